// Round 4
// baseline (966.429 us; speedup 1.0000x reference)
//
#include <hip/hip_runtime.h>
#include <cstdint>
#include <cstddef>

// ---------------------------------------------------------------------------
// AutoformerEncodeBlock R9:
//  - GEMM: software-pipelined phases — phase p issues ds_reads for phase p+1
//    (alternating A-frag sets), MFMA(p) consumes frags loaded in p-1, so LDS
//    latency hides under the MFMA cluster. 2 K-tiles per loop iteration with
//    fully static LDS buffer pointers; 1 barrier/phase (4/K-tile); counted
//    vmcnt(2) gates at end-ph0 (this tile's A1/A3) and end-ph2 (next tile's
//    B+A0/A2); kk-outer MFMA order (no back-to-back same-acc).
//  - corr_fft: register radix-8 FFT (R6)
//  - v-GEMM eliminated via Wvo = Wo*Wv fold; q,k fused GEMM; FFN sliced.
// ---------------------------------------------------------------------------

typedef _Float16 half8 __attribute__((ext_vector_type(8)));
typedef _Float16 half4 __attribute__((ext_vector_type(4)));
typedef float floatx4 __attribute__((ext_vector_type(4)));

#define PI_F 3.14159265358979323846f
#define ZP32(i) ((i) + ((i) >> 5))  // pad every 32 float2 elements

__device__ __forceinline__ void load_lds16(const void* g, void* l) {
  __builtin_amdgcn_global_load_lds((__attribute__((address_space(1))) void*)g,
                                   (__attribute__((address_space(3))) void*)l,
                                   16, 0, 0);
}

// ---------------------------- small utility kernels ------------------------

__global__ __launch_bounds__(256) void cvt_f16_kernel(const float* __restrict__ src,
                                                      _Float16* __restrict__ dst, int n4) {
  int i = blockIdx.x * 256 + threadIdx.x;
  if (i >= n4) return;
  float4 v = ((const float4*)src)[i];
  half4 h = {(_Float16)v.x, (_Float16)v.y, (_Float16)v.z, (_Float16)v.w};
  ((half4*)dst)[i] = h;
}

// dst[c, j] = src[j, c]  (n x n, fp32 -> fp16), 64x64 LDS tiles
__global__ __launch_bounds__(256) void transpose_f16_kernel(const float* __restrict__ src,
                                                            _Float16* __restrict__ dst, int n) {
  __shared__ float tile[64][65];
  int j0 = blockIdx.y * 64, c0 = blockIdx.x * 64;
  int tr = threadIdx.x >> 4;
  int tc = threadIdx.x & 15;
#pragma unroll
  for (int rr = 0; rr < 64; rr += 16) {
    float4 v = *(const float4*)(src + (size_t)(j0 + tr + rr) * n + c0 + tc * 4);
    tile[tr + rr][tc * 4 + 0] = v.x;
    tile[tr + rr][tc * 4 + 1] = v.y;
    tile[tr + rr][tc * 4 + 2] = v.z;
    tile[tr + rr][tc * 4 + 3] = v.w;
  }
  __syncthreads();
#pragma unroll
  for (int rr = 0; rr < 64; rr += 16) {
    int c = tr + rr;
    half4 h = {(_Float16)tile[tc * 4 + 0][c], (_Float16)tile[tc * 4 + 1][c],
               (_Float16)tile[tc * 4 + 2][c], (_Float16)tile[tc * 4 + 3][c]};
    *(half4*)(dst + (size_t)(c0 + c) * n + j0 + tc * 4) = h;
  }
}

// --------------------------------- LayerNorm -------------------------------
__global__ __launch_bounds__(256) void ln_kernel(const float* __restrict__ x,
                                                 const float* __restrict__ g,
                                                 const float* __restrict__ b,
                                                 _Float16* __restrict__ xn, int C) {
  int row = blockIdx.x;
  int t = threadIdx.x;
  const float4* xr = (const float4*)(x + (size_t)row * C);
  float4 v = xr[t];
  float s = v.x + v.y + v.z + v.w;
  float s2 = v.x * v.x + v.y * v.y + v.z * v.z + v.w * v.w;
  for (int o = 32; o > 0; o >>= 1) {
    s += __shfl_down(s, o, 64);
    s2 += __shfl_down(s2, o, 64);
  }
  __shared__ float red[8];
  int wave = t >> 6, lane = t & 63;
  if (lane == 0) { red[wave] = s; red[4 + wave] = s2; }
  __syncthreads();
  __shared__ float stats[2];
  if (t == 0) {
    float ts = red[0] + red[1] + red[2] + red[3];
    float ts2 = red[4] + red[5] + red[6] + red[7];
    float mu = ts / (float)C;
    float var = ts2 / (float)C - mu * mu;
    stats[0] = mu;
    stats[1] = 1.0f / sqrtf(var + 1e-5f);
  }
  __syncthreads();
  float mu = stats[0], rs = stats[1];
  float4 gv = ((const float4*)g)[t];
  float4 bv = ((const float4*)b)[t];
  half4 h = {(_Float16)((v.x - mu) * rs * gv.x + bv.x),
             (_Float16)((v.y - mu) * rs * gv.y + bv.y),
             (_Float16)((v.z - mu) * rs * gv.z + bv.z),
             (_Float16)((v.w - mu) * rs * gv.w + bv.w)};
  ((half4*)(xn + (size_t)row * C))[t] = h;
}

// ----------------------------------- GEMM ----------------------------------
// C[M,N] = A[M,K] * Bw[N,K]^T (fp16). 256x256 tile, BK=64, 8 waves (2x4),
// per-wave 128x64 output (acc[8][4]). 2-K-tile LDS double buffer with STATIC
// buffer pointers (loop unrolled 2 tiles/iter). Software-pipelined phases:
//   ph0: read bf(t)+A(2,3); stage B0,B1(t+1); MFMA mi0,1 (A(0,1) from ph3)
//        -> vmcnt(2) [A1,A3(t)]
//   ph1: read A(4,5); stage B2,B3,A0,A2(t+1); MFMA mi2,3
//   ph2: read A(6,7); stage A1,A3(t+1); MFMA mi4,5 -> vmcnt(2) [B+A0,A2(t+1)]
//   ph3: read A(0,1)(t+1) from other buf; MFMA mi6,7
// One s_barrier per phase; setprio around MFMA; kk-outer MFMA order.
// XOR-granule swizzle: source pre-swizzled (l7^l3), ds_read granule^(row&7).
// EPI: 1 = +bias[col]+res fp32, 2 = GELU -> fp16, 3 = +res fp32 (RMW ok),
//      4 = plain fp16, 5 = fp16 transposed [B, N, L] (L=2048)
template <int EPI>
__global__ __launch_bounds__(512, 2) void gemm256_kernel(
    const _Float16* __restrict__ A, const _Float16* __restrict__ Bw,
    int M, int N, int K, int lda, int ldb,
    float* __restrict__ outf, _Float16* __restrict__ outh,
    const float* __restrict__ bias, const float* __restrict__ res) {
  __shared__ _Float16 lds[2][2][256 * 64];  // [buf][A=0/B=1][256 rows x 64 halfs]

  int tid = threadIdx.x;
  int lane = tid & 63;
  int wave = tid >> 6;          // 0..7
  int wm = wave >> 2;           // 0..1  (M half)
  int wn = wave & 3;            // 0..3  (N quarter)
  int ln15 = lane & 15, q4 = lane >> 4;
  int l3 = lane >> 3, l7 = lane & 7;

  int nwg = gridDim.x, orig = blockIdx.x;
  int wg = ((nwg & 7) == 0) ? ((orig & 7) * (nwg >> 3) + (orig >> 3)) : orig;
  int nbn = N >> 8;
  size_t m0 = (size_t)(wg / nbn) << 8;
  size_t n0 = (size_t)(wg % nbn) << 8;

  // swizzled ds_read granule offsets (halfs)
  int sg0 = (q4 ^ l7) << 3;         // kk=0
  int sg1 = ((q4 + 4) ^ l7) << 3;   // kk=32

  floatx4 acc[8][4] = {};

  // staging: lane covers row (8*wave + l3) of each 64-row chunk, global
  // granule pre-swizzled to l7^l3 so linear LDS dest == swizzled layout.
  const _Float16* srcA = A + (m0 + 8 * wave + l3) * (size_t)lda + (size_t)((l7 ^ l3) * 8);
  const _Float16* srcB = Bw + (n0 + 8 * wave + l3) * (size_t)ldb + (size_t)((l7 ^ l3) * 8);
  // static buffer pointers
  const _Float16* cA0 = &lds[0][0][0];
  const _Float16* cB0 = &lds[0][1][0];
  const _Float16* cA1 = &lds[1][0][0];
  const _Float16* cB1 = &lds[1][1][0];
  char* stA0 = (char*)&lds[0][0][0] + wave * 1024;
  char* stB0 = (char*)&lds[0][1][0] + wave * 1024;
  char* stA1 = (char*)&lds[1][0][0] + wave * 1024;
  char* stB1 = (char*)&lds[1][1][0] + wave * 1024;

  int nk = K >> 6;   // even for all uses (K=1024)
  int nkh = nk >> 1;

  half8 bf[4][2];      // B frags, current K-tile
  half8 aS[2][2][2];   // [set][mi-pair slot][kk] A frags, alternating sets

#define RD_B4(base) _Pragma("unroll") for (int ni = 0; ni < 4; ++ni) {         \
    const _Float16* pb_ = (base) + ((wn * 64 + ni * 16 + ln15) << 6);          \
    bf[ni][0] = *(const half8*)(pb_ + sg0);                                    \
    bf[ni][1] = *(const half8*)(pb_ + sg1); }
#define RD_A2(s, mb, base) {                                                   \
    const _Float16* pa0_ = (base) + ((wm * 128 + (mb) * 16 + ln15) << 6);      \
    const _Float16* pa1_ = (base) + ((wm * 128 + ((mb) + 1) * 16 + ln15) << 6);\
    aS[s][0][0] = *(const half8*)(pa0_ + sg0);                                 \
    aS[s][0][1] = *(const half8*)(pa0_ + sg1);                                 \
    aS[s][1][0] = *(const half8*)(pa1_ + sg0);                                 \
    aS[s][1][1] = *(const half8*)(pa1_ + sg1); }
#define MM8(s, mi0, mi1) _Pragma("unroll") for (int kk = 0; kk < 2; ++kk) {    \
    _Pragma("unroll") for (int ni = 0; ni < 4; ++ni)                           \
      acc[mi0][ni] = __builtin_amdgcn_mfma_f32_16x16x32_f16(aS[s][0][kk], bf[ni][kk], acc[mi0][ni], 0, 0, 0); \
    _Pragma("unroll") for (int ni = 0; ni < 4; ++ni)                           \
      acc[mi1][ni] = __builtin_amdgcn_mfma_f32_16x16x32_f16(aS[s][1][kk], bf[ni][kk], acc[mi1][ni], 0, 0, 0); }

#define BARF() { __builtin_amdgcn_s_barrier(); __builtin_amdgcn_sched_barrier(0); }
#define FENCE() __builtin_amdgcn_sched_barrier(0)
#define VMC2() asm volatile("s_waitcnt vmcnt(2)" ::: "memory")
#define VMC0() asm volatile("s_waitcnt vmcnt(0)" ::: "memory")

// One K-tile: cur bufs (cA,cB), next-tile A buf (nA), stage dsts (sA,sB).
// PF: 1 = steady (stage next tile, gate vmcnt(2)), 0 = last tile (vmcnt(0)).
#define TB(cA, cB, nA, sA, sB, PF)                                             \
  /* ---- ph0: MFMA mi0,1 ---- */                                              \
  BARF();                                                                      \
  RD_B4(cB);                                                                   \
  RD_A2(1, 2, cA);                                                             \
  if (PF) {                                                                    \
    load_lds16(Bs, sB);                                                        \
    load_lds16(Bs + (size_t)64 * ldb, sB + 1 * 8192);                          \
  }                                                                            \
  FENCE();                                                                     \
  __builtin_amdgcn_s_setprio(1);                                               \
  MM8(0, 0, 1);                                                                \
  __builtin_amdgcn_s_setprio(0);                                               \
  FENCE();                                                                     \
  if (PF) { VMC2(); } else { VMC0(); }                                         \
  /* ---- ph1: MFMA mi2,3 ---- */                                              \
  BARF();                                                                      \
  RD_A2(0, 4, cA);                                                             \
  if (PF) {                                                                    \
    load_lds16(Bs + (size_t)128 * ldb, sB + 2 * 8192);                         \
    load_lds16(Bs + (size_t)192 * ldb, sB + 3 * 8192);                         \
    load_lds16(As, sA);                                                        \
    load_lds16(As + (size_t)128 * lda, sA + 2 * 8192);                         \
  }                                                                            \
  FENCE();                                                                     \
  __builtin_amdgcn_s_setprio(1);                                               \
  MM8(1, 2, 3);                                                                \
  __builtin_amdgcn_s_setprio(0);                                               \
  FENCE();                                                                     \
  /* ---- ph2: MFMA mi4,5 ---- */                                              \
  BARF();                                                                      \
  RD_A2(1, 6, cA);                                                             \
  if (PF) {                                                                    \
    load_lds16(As + (size_t)64 * lda, sA + 1 * 8192);                          \
    load_lds16(As + (size_t)192 * lda, sA + 3 * 8192);                         \
  }                                                                            \
  FENCE();                                                                     \
  __builtin_amdgcn_s_setprio(1);                                               \
  MM8(0, 4, 5);                                                                \
  __builtin_amdgcn_s_setprio(0);                                               \
  FENCE();                                                                     \
  VMC2();                                                                      \
  /* ---- ph3: MFMA mi6,7 ---- */                                              \
  BARF();                                                                      \
  if (PF) { RD_A2(0, 0, nA); }                                                 \
  FENCE();                                                                     \
  __builtin_amdgcn_s_setprio(1);                                               \
  MM8(1, 6, 7);                                                                \
  __builtin_amdgcn_s_setprio(0);                                               \
  FENCE();

  // prologue: stage tile 0 (B0..B3, A0, A2, A1, A3) into buf0
  load_lds16(srcB, stB0);
  load_lds16(srcB + (size_t)64 * ldb, stB0 + 1 * 8192);
  load_lds16(srcB + (size_t)128 * ldb, stB0 + 2 * 8192);
  load_lds16(srcB + (size_t)192 * ldb, stB0 + 3 * 8192);
  load_lds16(srcA, stA0);
  load_lds16(srcA + (size_t)128 * lda, stA0 + 2 * 8192);
  load_lds16(srcA + (size_t)64 * lda, stA0 + 1 * 8192);
  load_lds16(srcA + (size_t)192 * lda, stA0 + 3 * 8192);
  VMC2();  // B0..B3, A0, A2 landed (A1, A3 may be outstanding)
  BARF();
  RD_A2(0, 0, cA0);  // A(0,1) of tile 0 (chunks A0/A2)
  FENCE();

  const _Float16 *As, *Bs;
  for (int it = 0; it < nkh - 1; ++it) {
    int t0 = 2 * it;
    As = srcA + ((size_t)(t0 + 1) << 6);
    Bs = srcB + ((size_t)(t0 + 1) << 6);
    TB(cA0, cB0, cA1, stA1, stB1, 1)
    As = srcA + ((size_t)(t0 + 2) << 6);
    Bs = srcB + ((size_t)(t0 + 2) << 6);
    TB(cA1, cB1, cA0, stA0, stB0, 1)
  }
  // final pair: even tile stages last odd tile; odd tile stages nothing
  As = srcA + ((size_t)(nk - 1) << 6);
  Bs = srcB + ((size_t)(nk - 1) << 6);
  TB(cA0, cB0, cA1, stA1, stB1, 1)
  TB(cA1, cB1, cA0, stA0, stB0, 0)

#undef RD_B4
#undef RD_A2
#undef MM8
#undef BARF
#undef FENCE
#undef VMC2
#undef VMC0
#undef TB

#pragma unroll
  for (int mi = 0; mi < 8; ++mi) {
#pragma unroll
    for (int ni = 0; ni < 4; ++ni) {
      floatx4 a4 = acc[mi][ni];
      size_t rowb = m0 + wm * 128 + mi * 16 + q4 * 4;
      size_t col = n0 + wn * 64 + ni * 16 + ln15;
      if (EPI == 5) {
        size_t b = rowb >> 11, l0 = rowb & 2047;
        half4 h = {(_Float16)a4[0], (_Float16)a4[1], (_Float16)a4[2], (_Float16)a4[3]};
        *(half4*)(outh + (((size_t)b * N + col) << 11) + l0) = h;
      } else {
#pragma unroll
        for (int r = 0; r < 4; ++r) {
          size_t idx = (rowb + r) * (size_t)N + col;
          float v = a4[r];
          if (EPI == 1) {
            outf[idx] = v + bias[col] + res[idx];
          } else if (EPI == 2) {
            float ge = 0.5f * v * (1.0f + erff(v * 0.70710678118654752f));
            outh[idx] = (_Float16)ge;
          } else if (EPI == 3) {
            outf[idx] = v + res[idx];
          } else {
            outh[idx] = (_Float16)v;
          }
        }
      }
    }
  }
}

// --------------------- autocorrelation: register radix-8 FFT ---------------
// qk fused transposed layout F[b, ch, l], ch<1024 = q, ch>=1024 = k.
// block = (b, 2 channel-pairs), 256 threads. z = q + i*k; 2048-pt radix-2
// DIF FFT where 3 stages at a time run in registers (thread t holds 8 pts),
// separated by pad-32 conflict-free LDS exchanges. Hermitian split; partial
// spectrum row per block (no atomics), reduced by spec_reduce_kernel.

#define CBFLY(ch, ia, ib, wr, wi) {                      \
    float ax_ = z[ch][ia].x, ay_ = z[ch][ia].y;          \
    float bx_ = z[ch][ib].x, by_ = z[ch][ib].y;          \
    float dx_ = ax_ - bx_, dy_ = ay_ - by_;              \
    z[ch][ia].x = ax_ + bx_; z[ch][ia].y = ay_ + by_;    \
    z[ch][ib].x = dx_ * (wr) - dy_ * (wi);               \
    z[ch][ib].y = dx_ * (wi) + dy_ * (wr); }
#define BFLY2(ia, ib, m) { float2 w_ = twl[ZP32(m)];     \
    CBFLY(0, ia, ib, w_.x, w_.y) CBFLY(1, ia, ib, w_.x, w_.y) }

__global__ __launch_bounds__(256) void corr_fft_kernel(const _Float16* __restrict__ F,
                                                       float* __restrict__ S) {
  __shared__ float2 Zs[2][2112];   // 2048 + pad every 32
  __shared__ float2 twl[1056];     // 1024 twiddles, padded
  int tid = threadIdx.x;
  int b = blockIdx.x >> 9;
  int c0 = (blockIdx.x & 511) << 1;
  const _Float16* qb = F + ((size_t)(b * 2048 + c0) << 11);
  const _Float16* kb = F + ((size_t)(b * 2048 + 1024 + c0) << 11);

  // load 8 points per channel per thread: positions t + 256*j
  float2 z[2][8];
#pragma unroll
  for (int j = 0; j < 8; ++j) {
    int p = tid + 256 * j;
    z[0][j] = make_float2((float)qb[p], (float)kb[p]);
    z[1][j] = make_float2((float)qb[2048 + p], (float)kb[2048 + p]);
  }
  // twiddle table: twl[m] = exp(-2*pi*i*m/2048)
  for (int m = tid; m < 1024; m += 256) {
    float sn, cs;
    __sincosf(-PI_F * (float)m / 1024.0f, &sn, &cs);
    twl[ZP32(m)] = make_float2(cs, sn);
  }
  __syncthreads();

  // ---- round 1: stages sh=10,9,8  (positions t + 256j) ----
  BFLY2(0, 4, tid)
  BFLY2(1, 5, tid + 256)
  BFLY2(2, 6, tid + 512)
  BFLY2(3, 7, tid + 768)
  { float2 wA = twl[ZP32(tid << 1)], wB = twl[ZP32((tid + 256) << 1)];
    CBFLY(0, 0, 2, wA.x, wA.y) CBFLY(1, 0, 2, wA.x, wA.y)
    CBFLY(0, 1, 3, wB.x, wB.y) CBFLY(1, 1, 3, wB.x, wB.y)
    CBFLY(0, 4, 6, wA.x, wA.y) CBFLY(1, 4, 6, wA.x, wA.y)
    CBFLY(0, 5, 7, wB.x, wB.y) CBFLY(1, 5, 7, wB.x, wB.y) }
  { float2 wA = twl[ZP32(tid << 2)];
    CBFLY(0, 0, 1, wA.x, wA.y) CBFLY(1, 0, 1, wA.x, wA.y)
    CBFLY(0, 2, 3, wA.x, wA.y) CBFLY(1, 2, 3, wA.x, wA.y)
    CBFLY(0, 4, 5, wA.x, wA.y) CBFLY(1, 4, 5, wA.x, wA.y)
    CBFLY(0, 6, 7, wA.x, wA.y) CBFLY(1, 6, 7, wA.x, wA.y) }

  // ---- exchange 1: write t+256j, read (t>>5)*256 + (t&31) + 32j ----
#pragma unroll
  for (int j = 0; j < 8; ++j) {
    int p = tid + 256 * j;
    Zs[0][ZP32(p)] = z[0][j];
    Zs[1][ZP32(p)] = z[1][j];
  }
  __syncthreads();
  int t5 = tid & 31, hi1 = (tid >> 5) << 8;
#pragma unroll
  for (int j = 0; j < 8; ++j) {
    int p = hi1 + t5 + 32 * j;
    z[0][j] = Zs[0][ZP32(p)];
    z[1][j] = Zs[1][ZP32(p)];
  }

  // ---- round 2: stages sh=7,6,5 ----
  BFLY2(0, 4, t5 << 3)
  BFLY2(1, 5, (t5 + 32) << 3)
  BFLY2(2, 6, (t5 + 64) << 3)
  BFLY2(3, 7, (t5 + 96) << 3)
  { float2 wA = twl[ZP32(t5 << 4)], wB = twl[ZP32((t5 + 32) << 4)];
    CBFLY(0, 0, 2, wA.x, wA.y) CBFLY(1, 0, 2, wA.x, wA.y)
    CBFLY(0, 1, 3, wB.x, wB.y) CBFLY(1, 1, 3, wB.x, wB.y)
    CBFLY(0, 4, 6, wA.x, wA.y) CBFLY(1, 4, 6, wA.x, wA.y)
    CBFLY(0, 5, 7, wB.x, wB.y) CBFLY(1, 5, 7, wB.x, wB.y) }
  { float2 wA = twl[ZP32(t5 << 5)];
    CBFLY(0, 0, 1, wA.x, wA.y) CBFLY(1, 0, 1, wA.x, wA.y)
    CBFLY(0, 2, 3, wA.x, wA.y) CBFLY(1, 2, 3, wA.x, wA.y)
    CBFLY(0, 4, 5, wA.x, wA.y) CBFLY(1, 4, 5, wA.x, wA.y)
    CBFLY(0, 6, 7, wA.x, wA.y) CBFLY(1, 6, 7, wA.x, wA.y) }

  // ---- exchange 2: write back same slots, read (t>>2)*32 + (t&3) + 4j ----
  // (each slot was read only by this thread -> no barrier before write)
#pragma unroll
  for (int j = 0; j < 8; ++j) {
    int p = hi1 + t5 + 32 * j;
    Zs[0][ZP32(p)] = z[0][j];
    Zs[1][ZP32(p)] = z[1][j];
  }
  __syncthreads();
  int t3 = tid & 3, hi2 = (tid >> 2) << 5;
#pragma unroll
  for (int j = 0; j < 8; ++j) {
    int p = hi2 + t3 + 4 * j;
    z[0][j] = Zs[0][ZP32(p)];
    z[1][j] = Zs[1][ZP32(p)];
  }

  // ---- round 3: stages sh=4,3,2 ----
  BFLY2(0, 4, t3 << 6)
  BFLY2(1, 5, (t3 + 4) << 6)
  BFLY2(2, 6, (t3 + 8) << 6)
  BFLY2(3, 7, (t3 + 12) << 6)
  { float2 wA = twl[ZP32(t3 << 7)], wB = twl[ZP32((t3 + 4) << 7)];
    CBFLY(0, 0, 2, wA.x, wA.y) CBFLY(1, 0, 2, wA.x, wA.y)
    CBFLY(0, 1, 3, wB.x, wB.y) CBFLY(1, 1, 3, wB.x, wB.y)
    CBFLY(0, 4, 6, wA.x, wA.y) CBFLY(1, 4, 6, wA.x, wA.y)
    CBFLY(0, 5, 7, wB.x, wB.y) CBFLY(1, 5, 7, wB.x, wB.y) }
  { float2 wA = twl[ZP32(t3 << 8)];
    CBFLY(0, 0, 1, wA.x, wA.y) CBFLY(1, 0, 1, wA.x, wA.y)
    CBFLY(0, 2, 3, wA.x, wA.y) CBFLY(1, 2, 3, wA.x, wA.y)
    CBFLY(0, 4, 5, wA.x, wA.y) CBFLY(1, 4, 5, wA.x, wA.y)
    CBFLY(0, 6, 7, wA.x, wA.y) CBFLY(1, 6, 7, wA.x, wA.y) }

  // ---- exchange 3: write back same slots, read 8t + j ----
#pragma unroll
  for (int j = 0; j < 8; ++j) {
    int p = hi2 + t3 + 4 * j;
    Zs[0][ZP32(p)] = z[0][j];
    Zs[1][ZP32(p)] = z[1][j];
  }
  __syncthreads();
#pragma unroll
  for (int j = 0; j < 8; ++j) {
    int p = (tid << 3) + j;
    z[0][j] = Zs[0][ZP32(p)];
    z[1][j] = Zs[1][ZP32(p)];
  }

  // ---- round 4: stages sh=1 (w = 1 or -i), sh=0 (w = 1) ----
  CBFLY(0, 0, 2, 1.0f, 0.0f) CBFLY(1, 0, 2, 1.0f, 0.0f)
  CBFLY(0, 1, 3, 0.0f, -1.0f) CBFLY(1, 1, 3, 0.0f, -1.0f)
  CBFLY(0, 4, 6, 1.0f, 0.0f) CBFLY(1, 4, 6, 1.0f, 0.0f)
  CBFLY(0, 5, 7, 0.0f, -1.0f) CBFLY(1, 5, 7, 0.0f, -1.0f)
  CBFLY(0, 0, 1, 1.0f, 0.0f) CBFLY(1, 0, 1, 1.0f, 0.0f)
  CBFLY(0, 2, 3, 1.0f, 0.0f) CBFLY(1, 2, 3, 1.0f, 0.0f)
  CBFLY(0, 4, 5, 1.0f, 0.0f) CBFLY(1, 4, 5, 1.0f, 0.0f)
  CBFLY(0, 6, 7, 1.0f, 0.0f) CBFLY(1, 6, 7, 1.0f, 0.0f)

  // ---- final write (same slots as last read) + spectrum ----
#pragma unroll
  for (int j = 0; j < 8; ++j) {
    int p = (tid << 3) + j;
    Zs[0][ZP32(p)] = z[0][j];
    Zs[1][ZP32(p)] = z[1][j];
  }
  __syncthreads();
  float* Sb = S + (size_t)blockIdx.x * 2050;  // row = b*512 + channel-group
  for (int f = tid; f <= 1024; f += 256) {
    int rf = __brev((unsigned)f) >> 21;
    int rmf = __brev((unsigned)((2048 - f) & 2047)) >> 21;
    float pr = 0.f, pim = 0.f;
#pragma unroll
    for (int ch = 0; ch < 2; ++ch) {
      float2 zf = Zs[ch][ZP32(rf)], zm = Zs[ch][ZP32(rmf)];
      float Qr = 0.5f * (zf.x + zm.x), Qi = 0.5f * (zf.y - zm.y);
      float Kr = 0.5f * (zf.y + zm.y), Ki = -0.5f * (zf.x - zm.x);
      pr += Qr * Kr + Qi * Ki;
      pim += Qi * Kr - Qr * Ki;
    }
    Sb[2 * f] = pr;
    Sb[2 * f + 1] = pim;
  }
}

// ------------- reduce 512 partial spectrum rows -> 8-way S8 format ---------
__global__ __launch_bounds__(256) void spec_reduce_kernel(const float* __restrict__ Sbig,
                                                          float* __restrict__ S8) {
  int f = blockIdx.x * 256 + threadIdx.x;  // 0..2303, guard
  int sc = blockIdx.y;                     // 0..7 (64-row chunk)
  int b = blockIdx.z;                      // 0..7
  if (f >= 2050) return;
  const float* src = Sbig + ((size_t)b * 512 + (size_t)sc * 64) * 2050 + f;
  float s = 0.f;
  for (int i = 0; i < 64; ++i) s += src[(size_t)i * 2050];
  S8[((size_t)b * 8 + sc) * 2050 + f] = s;
}

// --------------- per-batch: inverse FFT -> mean_corr -> top-7 + softmax ----
__global__ __launch_bounds__(256) void corr_topk_kernel(const float* __restrict__ S,
                                                        int* __restrict__ delays,
                                                        float* __restrict__ alphas,
                                                        int C, int L) {
  __shared__ float2 W[2048];
  __shared__ float mc[2048];
  __shared__ float rv[4];
  __shared__ int ri[4];
  __shared__ float swv[7];
  __shared__ int sdi[7];
  int b = blockIdx.x, tid = threadIdx.x;
  const float* Sb = S + (size_t)b * 8 * 2050;
  for (int f = tid; f < 2048; f += 256) {
    int ff = f <= 1024 ? f : 2048 - f;
    float re = 0.f, im = 0.f;
    for (int s = 0; s < 8; ++s) {
      re += Sb[s * 2050 + 2 * ff];
      im += Sb[s * 2050 + 2 * ff + 1];
    }
    W[f] = make_float2(re, f <= 1024 ? -im : im);
  }
  __syncthreads();
  for (int sh = 10; sh >= 0; --sh) {
    int s = 1 << sh;
    for (int j = tid; j < 1024; j += 256) {
      int t = j & (s - 1);
      int i0 = ((j >> sh) << (sh + 1)) | t;
      int i1 = i0 + s;
      float2 a = W[i0], bb = W[i1];
      float ang = -PI_F * (float)t / (float)s;
      float sn, cs;
      __sincosf(ang, &sn, &cs);
      float2 d = make_float2(a.x - bb.x, a.y - bb.y);
      W[i0] = make_float2(a.x + bb.x, a.y + bb.y);
      W[i1] = make_float2(d.x * cs - d.y * sn, d.x * sn + d.y * cs);
    }
    __syncthreads();
  }
  float inv = 1.0f / ((float)C * (float)L);
  for (int t = tid; t < 2048; t += 256) mc[t] = W[__brev((unsigned)t) >> 21].x * inv;
  __syncthreads();
  int wv = tid >> 6, lane = tid & 63;
  for (int it = 0; it < 7; ++it) {
    float bvv = -1e30f;
    int bi = 0;
    for (int e = tid * 8; e < tid * 8 + 8; ++e) {
      float v = mc[e];
      if (v > bvv) { bvv = v; bi = e; }
    }
    for (int o = 32; o > 0; o >>= 1) {
      float ov = __shfl_down(bvv, o, 64);
      int oi = __shfl_down(bi, o, 64);
      if (ov > bvv || (ov == bvv && oi < bi)) { bvv = ov; bi = oi; }
    }
    if (lane == 0) { rv[wv] = bvv; ri[wv] = bi; }
    __syncthreads();
    if (tid == 0) {
      float fv = rv[0];
      int fi = ri[0];
      for (int w2 = 1; w2 < 4; ++w2)
        if (rv[w2] > fv || (rv[w2] == fv && ri[w2] < fi)) { fv = rv[w2]; fi = ri[w2]; }
      swv[it] = fv;
      sdi[it] = fi;
      mc[fi] = -1e30f;
    }
    __syncthreads();
  }
  if (tid == 0) {
    float mx = swv[0];
    for (int i = 1; i < 7; ++i) mx = fmaxf(mx, swv[i]);
    float e[7], s = 0.f;
    for (int i = 0; i < 7; ++i) { e[i] = expf(swv[i] - mx); s += e[i]; }
    for (int i = 0; i < 7; ++i) {
      alphas[b * 7 + i] = e[i] / s;
      delays[b * 7 + i] = sdi[i];
    }
  }
}

// ------------------- lag aggregation on xn (commuted past Wv) --------------
__global__ __launch_bounds__(256) void agg_kernel(const _Float16* __restrict__ v,
                                                  const int* __restrict__ delays,
                                                  const float* __restrict__ alphas,
                                                  _Float16* __restrict__ agg,
                                                  int L, int C) {
  int bt = blockIdx.x;
  int b = bt >> 11, t = bt & 2047;
  int tid = threadIdx.x;
  const _Float16* vb = v + (size_t)b * L * C;
  float ax = 0.f, ay = 0.f, az = 0.f, aw = 0.f;
#pragma unroll
  for (int i = 0; i < 7; ++i) {
    int d = delays[b * 7 + i];
    float a = alphas[b * 7 + i];
    int src = t + d;
    if (src >= L) src -= L;
    half4 x = ((const half4*)(vb + (size_t)src * C))[tid];
    ax += a * (float)x.x; ay += a * (float)x.y;
    az += a * (float)x.z; aw += a * (float)x.w;
  }
  half4 h = {(_Float16)ax, (_Float16)ay, (_Float16)az, (_Float16)aw};
  ((half4*)(agg + (size_t)bt * C))[tid] = h;
}

// ----------------- series decomposition: out = x - movavg25(x) -------------
template <int WRITE_H>
__global__ __launch_bounds__(256) void decomp_kernel(const float* __restrict__ xin,
                                                     float* __restrict__ xout,
                                                     _Float16* __restrict__ xh,
                                                     int L, int C) {
  int c = blockIdx.x * 256 + threadIdx.x;
  int t0 = blockIdx.y * 128;
  int b = blockIdx.z;
  const float* xb = xin + (size_t)b * L * C + c;
  float sum = 0.f;
  for (int j = t0 - 12; j <= t0 + 12; ++j) {
    int jc = j < 0 ? 0 : (j > L - 1 ? L - 1 : j);
    sum += xb[(size_t)jc * C];
  }
  for (int t = t0; t < t0 + 128; ++t) {
    float xv = xb[(size_t)t * C];
    float o = xv - sum * (1.0f / 25.0f);
    size_t oidx = ((size_t)b * L + t) * C + c;
    xout[oidx] = o;
    if (WRITE_H) xh[oidx] = (_Float16)o;
    int nj = t + 13; if (nj > L - 1) nj = L - 1;
    int oj = t - 12; if (oj < 0) oj = 0;
    sum += xb[(size_t)nj * C] - xb[(size_t)oj * C];
  }
}

// ------------------------------- launcher ----------------------------------
extern "C" void kernel_launch(void* const* d_in, const int* in_sizes, int n_in,
                              void* d_out, int out_size, void* d_ws, size_t ws_size,
                              hipStream_t stream) {
  const float* x = (const float*)d_in[0];
  const float* Wq = (const float*)d_in[1];
  const float* Wk = (const float*)d_in[2];
  const float* Wv = (const float*)d_in[3];
  const float* Wo = (const float*)d_in[4];
  const float* bo = (const float*)d_in[5];
  const float* lng = (const float*)d_in[6];
  const float* lnb = (const float*)d_in[7];
  const float* W1 = (const float*)d_in[8];
  const float* W2 = (const float*)d_in[9];
  float* out = (float*)d_out;

  const int B = 8, L = 2048, C = 1024, HD = 4096;
  const int M = B * L;  // 16384

  char* ws = (char*)d_ws;
  size_t off = 0;
  auto alloc = [&](size_t bytes) -> void* {
    void* p = ws + off;
    off = (off + bytes + 255) & ~(size_t)255;
    return p;
  };
  // ~150.6 MiB total (under the 152.1 MiB proven previously)
  _Float16* wqkh = (_Float16*)alloc((size_t)2 * C * C * 2); // 4 MB (q rows, then k rows)
  _Float16* wvoh = (_Float16*)alloc((size_t)C * C * 2);     // 2 MB (Wo*Wv)
  _Float16* w1h = (_Float16*)alloc((size_t)HD * C * 2);     // 8 MB
  _Float16* w2h = (_Float16*)alloc((size_t)C * HD * 2);     // 8 MB
  float* S8 = (float*)alloc((size_t)B * 8 * 2050 * 4);      // 512 KB (reduced spectrum)
  int* dl = (int*)alloc(B * 7 * 4);
  float* al = (float*)alloc(B * 7 * 4);
  _Float16* xn = (_Float16*)alloc((size_t)M * C * 2);       // 32 MB; later x2h
  _Float16* qkh = (_Float16*)alloc((size_t)M * 2 * C * 2);  // 64 MB [B,2C,L]; later x1/x3
  _Float16* vh = (_Float16*)alloc((size_t)4096 * 2050 * 4); // 33.6 MB: Sbig/wvT/woh, aggh, hid
  (void)ws_size; (void)in_sizes; (void)n_in; (void)out_size;

  _Float16* wvT = vh;                        // setup-only (dead before corr_fft)
  _Float16* woh = vh + (size_t)C * C;        // setup-only (dead before corr_fft)
  float* Sbig = (float*)vh;       // partial spectra (steps 5-6), dead before agg
  _Float16* aggh = vh;            // agg of xn (from step 8)
  float* x1 = (float*)qkh;        // q,k dead after corr_fft (64 MB)
  _Float16* x2h = xn;             // xn dead after agg
  float* x2 = out;                // d_out doubles as x2 scratch
  float* x3 = (float*)qkh;        // x1 dead after decomp1
  _Float16* hidc = vh;            // Sbig/aggh dead after attn GEMM (32 MB slice)

  // 1. weights -> fp16 (+ Wv transpose)
  cvt_f16_kernel<<<(C * C / 4 + 255) / 256, 256, 0, stream>>>(Wq, wqkh, C * C / 4);
  cvt_f16_kernel<<<(C * C / 4 + 255) / 256, 256, 0, stream>>>(Wk, wqkh + (size_t)C * C, C * C / 4);
  cvt_f16_kernel<<<(C * C / 4 + 255) / 256, 256, 0, stream>>>(Wo, woh, C * C / 4);
  transpose_f16_kernel<<<dim3(16, 16), 256, 0, stream>>>(Wv, wvT, C);
  cvt_f16_kernel<<<(HD * C / 4 + 255) / 256, 256, 0, stream>>>(W1, w1h, HD * C / 4);
  cvt_f16_kernel<<<(HD * C / 4 + 255) / 256, 256, 0, stream>>>(W2, w2h, HD * C / 4);
  // 2. Wvo[o,c] = sum_j Wo[o,j]*Wv[j,c]
  gemm256_kernel<4><<<16, 512, 0, stream>>>(woh, wvT, C, C, C, C, C,
                                            nullptr, wvoh, nullptr, nullptr);
  // 3. LayerNorm -> fp16
  ln_kernel<<<M, 256, 0, stream>>>(x, lng, lnb, xn, C);
  // 4. fused q,k GEMM -> transposed [B, 2C, L]
  gemm256_kernel<5><<<(M / 256) * (2 * C / 256), 512, 0, stream>>>(
      xn, wqkh, M, 2 * C, C, C, C, nullptr, qkh, nullptr, nullptr);
  // 5. channel FFTs -> per-block partial spectrum rows (no atomics)
  corr_fft_kernel<<<B * (C / 2), 256, 0, stream>>>(qkh, Sbig);
  // 6. reduce 512 partial rows -> 8-way S8
  spec_reduce_kernel<<<dim3(9, 8, 8), 256, 0, stream>>>(Sbig, S8);
  // 7. inverse FFT + top-7 + softmax
  corr_topk_kernel<<<B, 256, 0, stream>>>(S8, dl, al, C, L);
  // 8. lag aggregation on xn (commuted) -> aggh
  agg_kernel<<<B * L, 256, 0, stream>>>(xn, dl, al, aggh, L, C);
  // 9. attn = aggh * Wvo^T + bo + x -> x1 (fp32)
  gemm256_kernel<1><<<(M / 256) * (C / 256), 512, 0, stream>>>(
      aggh, wvoh, M, C, C, C, C, x1, nullptr, bo, x);
  // 10. decomp1: x2 = x1 - movavg(x1) -> d_out + fp16 copy (xn region)
  decomp_kernel<1><<<dim3(C / 256, L / 128, B), 256, 0, stream>>>(x1, x2, x2h, L, C);
  // 11. FFN: N-sliced FFN1, K-partial FFN2 (256-block dispatches)
  for (int ci = 0; ci < 4; ++ci) {
    gemm256_kernel<2><<<(M / 256) * (1024 / 256), 512, 0, stream>>>(
        x2h, w1h + (size_t)ci * 1024 * C, M, 1024, C, C, C,
        nullptr, hidc, nullptr, nullptr);
    gemm256_kernel<3><<<(M / 256) * (C / 256), 512, 0, stream>>>(
        hidc, w2h + (size_t)ci * 1024, M, C, 1024, 1024, HD,
        x3, nullptr, nullptr, ci == 0 ? x2 : x3);
  }
  // 12. decomp2 -> out
  decomp_kernel<0><<<dim3(C / 256, L / 128, B), 256, 0, stream>>>(x3, out, nullptr, L, C);
}

// Round 5
// 886.675 us; speedup vs baseline: 1.0899x; 1.0899x over previous
//
#include <hip/hip_runtime.h>
#include <cstdint>
#include <cstddef>

// ---------------------------------------------------------------------------
// AutoformerEncodeBlock R10:
//  - GEMM K-loop: R8 dual-barrier phase skeleton (best measured total).
//  - FFN restructured: HD sliced in 2 halves (not 4 quarters). hid half
//    (M x 2048 fp16, 64 MB) lives in dead x1/qkh region; x3 becomes fp16 in
//    dead vh region. FFN2 pass0: x3h = acc + x2 (fp32 res); pass1: fp16 RMW.
//    Epilogue traffic 512 MB -> 160 MB; FFN2 K=2048 (nk=32).
//  - decomp2 reads fp16 x3h (new decomp_h_kernel).
//  - corr_fft: register radix-8 FFT (R6); Wvo fold; fused qk GEMM.
// ---------------------------------------------------------------------------

typedef _Float16 half8 __attribute__((ext_vector_type(8)));
typedef _Float16 half4 __attribute__((ext_vector_type(4)));
typedef float floatx4 __attribute__((ext_vector_type(4)));

#define PI_F 3.14159265358979323846f
#define ZP32(i) ((i) + ((i) >> 5))  // pad every 32 float2 elements

__device__ __forceinline__ void load_lds16(const void* g, void* l) {
  __builtin_amdgcn_global_load_lds((__attribute__((address_space(1))) void*)g,
                                   (__attribute__((address_space(3))) void*)l,
                                   16, 0, 0);
}

// ---------------------------- small utility kernels ------------------------

__global__ __launch_bounds__(256) void cvt_f16_kernel(const float* __restrict__ src,
                                                      _Float16* __restrict__ dst, int n4) {
  int i = blockIdx.x * 256 + threadIdx.x;
  if (i >= n4) return;
  float4 v = ((const float4*)src)[i];
  half4 h = {(_Float16)v.x, (_Float16)v.y, (_Float16)v.z, (_Float16)v.w};
  ((half4*)dst)[i] = h;
}

// dst[c, j] = src[j, c]  (n x n, fp32 -> fp16), 64x64 LDS tiles
__global__ __launch_bounds__(256) void transpose_f16_kernel(const float* __restrict__ src,
                                                            _Float16* __restrict__ dst, int n) {
  __shared__ float tile[64][65];
  int j0 = blockIdx.y * 64, c0 = blockIdx.x * 64;
  int tr = threadIdx.x >> 4;
  int tc = threadIdx.x & 15;
#pragma unroll
  for (int rr = 0; rr < 64; rr += 16) {
    float4 v = *(const float4*)(src + (size_t)(j0 + tr + rr) * n + c0 + tc * 4);
    tile[tr + rr][tc * 4 + 0] = v.x;
    tile[tr + rr][tc * 4 + 1] = v.y;
    tile[tr + rr][tc * 4 + 2] = v.z;
    tile[tr + rr][tc * 4 + 3] = v.w;
  }
  __syncthreads();
#pragma unroll
  for (int rr = 0; rr < 64; rr += 16) {
    int c = tr + rr;
    half4 h = {(_Float16)tile[tc * 4 + 0][c], (_Float16)tile[tc * 4 + 1][c],
               (_Float16)tile[tc * 4 + 2][c], (_Float16)tile[tc * 4 + 3][c]};
    *(half4*)(dst + (size_t)(c0 + c) * n + j0 + tc * 4) = h;
  }
}

// --------------------------------- LayerNorm -------------------------------
__global__ __launch_bounds__(256) void ln_kernel(const float* __restrict__ x,
                                                 const float* __restrict__ g,
                                                 const float* __restrict__ b,
                                                 _Float16* __restrict__ xn, int C) {
  int row = blockIdx.x;
  int t = threadIdx.x;
  const float4* xr = (const float4*)(x + (size_t)row * C);
  float4 v = xr[t];
  float s = v.x + v.y + v.z + v.w;
  float s2 = v.x * v.x + v.y * v.y + v.z * v.z + v.w * v.w;
  for (int o = 32; o > 0; o >>= 1) {
    s += __shfl_down(s, o, 64);
    s2 += __shfl_down(s2, o, 64);
  }
  __shared__ float red[8];
  int wave = t >> 6, lane = t & 63;
  if (lane == 0) { red[wave] = s; red[4 + wave] = s2; }
  __syncthreads();
  __shared__ float stats[2];
  if (t == 0) {
    float ts = red[0] + red[1] + red[2] + red[3];
    float ts2 = red[4] + red[5] + red[6] + red[7];
    float mu = ts / (float)C;
    float var = ts2 / (float)C - mu * mu;
    stats[0] = mu;
    stats[1] = 1.0f / sqrtf(var + 1e-5f);
  }
  __syncthreads();
  float mu = stats[0], rs = stats[1];
  float4 gv = ((const float4*)g)[t];
  float4 bv = ((const float4*)b)[t];
  half4 h = {(_Float16)((v.x - mu) * rs * gv.x + bv.x),
             (_Float16)((v.y - mu) * rs * gv.y + bv.y),
             (_Float16)((v.z - mu) * rs * gv.z + bv.z),
             (_Float16)((v.w - mu) * rs * gv.w + bv.w)};
  ((half4*)(xn + (size_t)row * C))[t] = h;
}

// ----------------------------------- GEMM ----------------------------------
// C[M,N] = A[M,K] * Bw[N,K]^T (fp16). 256x256 tile, BK=64, 8 waves (2x4),
// per-wave 128x64 output (acc[8][4]). 2-K-tile LDS double buffer; 8 staging
// chunks/K-tile spread 3|3|1|1 across phases (B0,B1,B2 | B3,A0,A2 | A1 | A3);
// counted vmcnt: end-ph1 vmcnt(6) guards this tile's A1/A3, end-ph3 vmcnt(2)
// guards next tile's B*+A0/A2. Per phase (m201 skeleton): ds_reads ->
// stage-issue -> s_barrier -> lgkmcnt(0) -> setprio(1) 16xMFMA setprio(0) ->
// [vmcnt] -> s_barrier. XOR-granule swizzle: source pre-swizzled (l7^l3),
// ds_read applies granule^(row&7). Zero bank conflicts (verified R7).
// EPI: 1 = +bias[col]+res fp32, 2 = GELU -> fp16, 4 = plain fp16,
//      5 = fp16 transposed [B, N, L] (L=2048),
//      6 = fp16 out = acc + res(fp32), 7 = fp16 RMW out += acc
template <int EPI>
__global__ __launch_bounds__(512, 2) void gemm256_kernel(
    const _Float16* __restrict__ A, const _Float16* __restrict__ Bw,
    int M, int N, int K, int lda, int ldb,
    float* __restrict__ outf, _Float16* __restrict__ outh,
    const float* __restrict__ bias, const float* __restrict__ res) {
  __shared__ _Float16 lds[2][2][256 * 64];  // [buf][A=0/B=1][256 rows x 64 halfs]

  int tid = threadIdx.x;
  int lane = tid & 63;
  int wave = tid >> 6;          // 0..7
  int wm = wave >> 2;           // 0..1  (M half)
  int wn = wave & 3;            // 0..3  (N quarter)
  int ln15 = lane & 15, q4 = lane >> 4;
  int l3 = lane >> 3, l7 = lane & 7;

  int nwg = gridDim.x, orig = blockIdx.x;
  int wg = ((nwg & 7) == 0) ? ((orig & 7) * (nwg >> 3) + (orig >> 3)) : orig;
  int nbn = N >> 8;
  size_t m0 = (size_t)(wg / nbn) << 8;
  size_t n0 = (size_t)(wg % nbn) << 8;

  // swizzled ds_read granule offsets (halfs)
  int sg0 = (q4 ^ l7) << 3;         // kk=0
  int sg1 = ((q4 + 4) ^ l7) << 3;   // kk=32

  floatx4 acc[8][4] = {};

  // staging: lane covers row (8*wave + l3) of each 64-row chunk, global
  // granule pre-swizzled to l7^l3 so linear LDS dest == swizzled layout.
  const _Float16* srcA = A + (m0 + 8 * wave + l3) * (size_t)lda + (size_t)((l7 ^ l3) * 8);
  const _Float16* srcB = Bw + (n0 + 8 * wave + l3) * (size_t)ldb + (size_t)((l7 ^ l3) * 8);
  char* ldsA0 = (char*)&lds[0][0][0] + wave * 1024;
  char* ldsB0 = (char*)&lds[0][1][0] + wave * 1024;

  // prologue: stage tile 0 (order B0,B1,B2,B3,A0,A2,A1,A3) into buf 0
  load_lds16(srcB, ldsB0);
  load_lds16(srcB + (size_t)64 * ldb, ldsB0 + 1 * 8192);
  load_lds16(srcB + (size_t)128 * ldb, ldsB0 + 2 * 8192);
  load_lds16(srcB + (size_t)192 * ldb, ldsB0 + 3 * 8192);
  load_lds16(srcA, ldsA0);
  load_lds16(srcA + (size_t)128 * lda, ldsA0 + 2 * 8192);
  load_lds16(srcA + (size_t)64 * lda, ldsA0 + 1 * 8192);
  load_lds16(srcA + (size_t)192 * lda, ldsA0 + 3 * 8192);
  // guard tile-0 reads (A1,A3 may stay outstanding)
  asm volatile("s_waitcnt vmcnt(2)" ::: "memory");
  __builtin_amdgcn_s_barrier();
  __builtin_amdgcn_sched_barrier(0);

  int nk = K >> 6;
  half8 bf[4][2], aA[2][2];

#define RD_B() _Pragma("unroll") for (int ni = 0; ni < 4; ++ni) {      \
    const _Float16* p_ = cB + ((wn * 64 + ni * 16 + ln15) << 6);       \
    bf[ni][0] = *(const half8*)(p_ + sg0);                             \
    bf[ni][1] = *(const half8*)(p_ + sg1); }
#define RD_A(mi) { const _Float16* p_ = cA + ((wm * 128 + (mi) * 16 + ln15) << 6); \
    aA[(mi) & 1][0] = *(const half8*)(p_ + sg0);                                   \
    aA[(mi) & 1][1] = *(const half8*)(p_ + sg1); }
#define MM(mi) _Pragma("unroll") for (int ni = 0; ni < 4; ++ni) {      \
    acc[mi][ni] = __builtin_amdgcn_mfma_f32_16x16x32_f16(aA[(mi) & 1][0], bf[ni][0], acc[mi][ni], 0, 0, 0); \
    acc[mi][ni] = __builtin_amdgcn_mfma_f32_16x16x32_f16(aA[(mi) & 1][1], bf[ni][1], acc[mi][ni], 0, 0, 0); }

#define PH_MID()                                            \
    __builtin_amdgcn_s_barrier();                           \
    asm volatile("s_waitcnt lgkmcnt(0)" ::: "memory");      \
    __builtin_amdgcn_sched_barrier(0);                      \
    __builtin_amdgcn_s_setprio(1);
#define PH_END()                                            \
    __builtin_amdgcn_s_setprio(0);                          \
    __builtin_amdgcn_s_barrier();                           \
    __builtin_amdgcn_sched_barrier(0);

  for (int t = 0; t < nk; ++t) {
    int cur = t & 1;
    const _Float16* cA = &lds[cur][0][0];
    const _Float16* cB = &lds[cur][1][0];
    const _Float16* As = srcA + (size_t)(t + 1) * 64;
    const _Float16* Bs = srcB + (size_t)(t + 1) * 64;
    char* stA = ldsA0 + (cur ^ 1) * 65536;
    char* stB = ldsB0 + (cur ^ 1) * 65536;
    bool pf = (t + 1 < nk);

    // ---- phase 0: MFMA mi=0,1 ----
    RD_B();
    RD_A(0); RD_A(1);
    if (pf) {
      load_lds16(Bs, stB);
      load_lds16(Bs + (size_t)64 * ldb, stB + 1 * 8192);
      load_lds16(Bs + (size_t)128 * ldb, stB + 2 * 8192);
    }
    PH_MID();
    MM(0); MM(1);
    PH_END();
    // ---- phase 1: MFMA mi=2,3; end-wait guards this tile's A1,A3 ----
    RD_A(2); RD_A(3);
    if (pf) {
      load_lds16(Bs + (size_t)192 * ldb, stB + 3 * 8192);
      load_lds16(As, stA);
      load_lds16(As + (size_t)128 * lda, stA + 2 * 8192);
    }
    PH_MID();
    MM(2); MM(3);
    __builtin_amdgcn_s_setprio(0);
    if (pf) {
      asm volatile("s_waitcnt vmcnt(6)" ::: "memory");
    } else {
      asm volatile("s_waitcnt vmcnt(0)" ::: "memory");
    }
    __builtin_amdgcn_s_barrier();
    __builtin_amdgcn_sched_barrier(0);
    // ---- phase 2: MFMA mi=4,5 ----
    RD_A(4); RD_A(5);
    if (pf) {
      load_lds16(As + (size_t)64 * lda, stA + 1 * 8192);
    }
    PH_MID();
    MM(4); MM(5);
    PH_END();
    // ---- phase 3: MFMA mi=6,7; end-wait guards next tile's B*,A0,A2 ----
    RD_A(6); RD_A(7);
    if (pf) {
      load_lds16(As + (size_t)192 * lda, stA + 3 * 8192);
    }
    PH_MID();
    MM(6); MM(7);
    __builtin_amdgcn_s_setprio(0);
    asm volatile("s_waitcnt vmcnt(2)" ::: "memory");
    __builtin_amdgcn_s_barrier();
    __builtin_amdgcn_sched_barrier(0);
  }
#undef RD_B
#undef RD_A
#undef MM
#undef PH_MID
#undef PH_END

#pragma unroll
  for (int mi = 0; mi < 8; ++mi) {
#pragma unroll
    for (int ni = 0; ni < 4; ++ni) {
      floatx4 a4 = acc[mi][ni];
      size_t rowb = m0 + wm * 128 + mi * 16 + q4 * 4;
      size_t col = n0 + wn * 64 + ni * 16 + ln15;
      if (EPI == 5) {
        size_t b = rowb >> 11, l0 = rowb & 2047;
        half4 h = {(_Float16)a4[0], (_Float16)a4[1], (_Float16)a4[2], (_Float16)a4[3]};
        *(half4*)(outh + (((size_t)b * N + col) << 11) + l0) = h;
      } else {
#pragma unroll
        for (int r = 0; r < 4; ++r) {
          size_t idx = (rowb + r) * (size_t)N + col;
          float v = a4[r];
          if (EPI == 1) {
            outf[idx] = v + bias[col] + res[idx];
          } else if (EPI == 2) {
            float ge = 0.5f * v * (1.0f + erff(v * 0.70710678118654752f));
            outh[idx] = (_Float16)ge;
          } else if (EPI == 6) {
            outh[idx] = (_Float16)(v + res[idx]);
          } else if (EPI == 7) {
            float prev = (float)outh[idx];
            outh[idx] = (_Float16)(v + prev);
          } else {
            outh[idx] = (_Float16)v;
          }
        }
      }
    }
  }
}

// --------------------- autocorrelation: register radix-8 FFT ---------------
// qk fused transposed layout F[b, ch, l], ch<1024 = q, ch>=1024 = k.
// block = (b, 2 channel-pairs), 256 threads. z = q + i*k; 2048-pt radix-2
// DIF FFT where 3 stages at a time run in registers (thread t holds 8 pts),
// separated by pad-32 conflict-free LDS exchanges. Hermitian split; partial
// spectrum row per block (no atomics), reduced by spec_reduce_kernel.

#define CBFLY(ch, ia, ib, wr, wi) {                      \
    float ax_ = z[ch][ia].x, ay_ = z[ch][ia].y;          \
    float bx_ = z[ch][ib].x, by_ = z[ch][ib].y;          \
    float dx_ = ax_ - bx_, dy_ = ay_ - by_;              \
    z[ch][ia].x = ax_ + bx_; z[ch][ia].y = ay_ + by_;    \
    z[ch][ib].x = dx_ * (wr) - dy_ * (wi);               \
    z[ch][ib].y = dx_ * (wi) + dy_ * (wr); }
#define BFLY2(ia, ib, m) { float2 w_ = twl[ZP32(m)];     \
    CBFLY(0, ia, ib, w_.x, w_.y) CBFLY(1, ia, ib, w_.x, w_.y) }

__global__ __launch_bounds__(256) void corr_fft_kernel(const _Float16* __restrict__ F,
                                                       float* __restrict__ S) {
  __shared__ float2 Zs[2][2112];   // 2048 + pad every 32
  __shared__ float2 twl[1056];     // 1024 twiddles, padded
  int tid = threadIdx.x;
  int b = blockIdx.x >> 9;
  int c0 = (blockIdx.x & 511) << 1;
  const _Float16* qb = F + ((size_t)(b * 2048 + c0) << 11);
  const _Float16* kb = F + ((size_t)(b * 2048 + 1024 + c0) << 11);

  // load 8 points per channel per thread: positions t + 256*j
  float2 z[2][8];
#pragma unroll
  for (int j = 0; j < 8; ++j) {
    int p = tid + 256 * j;
    z[0][j] = make_float2((float)qb[p], (float)kb[p]);
    z[1][j] = make_float2((float)qb[2048 + p], (float)kb[2048 + p]);
  }
  // twiddle table: twl[m] = exp(-2*pi*i*m/2048)
  for (int m = tid; m < 1024; m += 256) {
    float sn, cs;
    __sincosf(-PI_F * (float)m / 1024.0f, &sn, &cs);
    twl[ZP32(m)] = make_float2(cs, sn);
  }
  __syncthreads();

  // ---- round 1: stages sh=10,9,8  (positions t + 256j) ----
  BFLY2(0, 4, tid)
  BFLY2(1, 5, tid + 256)
  BFLY2(2, 6, tid + 512)
  BFLY2(3, 7, tid + 768)
  { float2 wA = twl[ZP32(tid << 1)], wB = twl[ZP32((tid + 256) << 1)];
    CBFLY(0, 0, 2, wA.x, wA.y) CBFLY(1, 0, 2, wA.x, wA.y)
    CBFLY(0, 1, 3, wB.x, wB.y) CBFLY(1, 1, 3, wB.x, wB.y)
    CBFLY(0, 4, 6, wA.x, wA.y) CBFLY(1, 4, 6, wA.x, wA.y)
    CBFLY(0, 5, 7, wB.x, wB.y) CBFLY(1, 5, 7, wB.x, wB.y) }
  { float2 wA = twl[ZP32(tid << 2)];
    CBFLY(0, 0, 1, wA.x, wA.y) CBFLY(1, 0, 1, wA.x, wA.y)
    CBFLY(0, 2, 3, wA.x, wA.y) CBFLY(1, 2, 3, wA.x, wA.y)
    CBFLY(0, 4, 5, wA.x, wA.y) CBFLY(1, 4, 5, wA.x, wA.y)
    CBFLY(0, 6, 7, wA.x, wA.y) CBFLY(1, 6, 7, wA.x, wA.y) }

  // ---- exchange 1: write t+256j, read (t>>5)*256 + (t&31) + 32j ----
#pragma unroll
  for (int j = 0; j < 8; ++j) {
    int p = tid + 256 * j;
    Zs[0][ZP32(p)] = z[0][j];
    Zs[1][ZP32(p)] = z[1][j];
  }
  __syncthreads();
  int t5 = tid & 31, hi1 = (tid >> 5) << 8;
#pragma unroll
  for (int j = 0; j < 8; ++j) {
    int p = hi1 + t5 + 32 * j;
    z[0][j] = Zs[0][ZP32(p)];
    z[1][j] = Zs[1][ZP32(p)];
  }

  // ---- round 2: stages sh=7,6,5 ----
  BFLY2(0, 4, t5 << 3)
  BFLY2(1, 5, (t5 + 32) << 3)
  BFLY2(2, 6, (t5 + 64) << 3)
  BFLY2(3, 7, (t5 + 96) << 3)
  { float2 wA = twl[ZP32(t5 << 4)], wB = twl[ZP32((t5 + 32) << 4)];
    CBFLY(0, 0, 2, wA.x, wA.y) CBFLY(1, 0, 2, wA.x, wA.y)
    CBFLY(0, 1, 3, wB.x, wB.y) CBFLY(1, 1, 3, wB.x, wB.y)
    CBFLY(0, 4, 6, wA.x, wA.y) CBFLY(1, 4, 6, wA.x, wA.y)
    CBFLY(0, 5, 7, wB.x, wB.y) CBFLY(1, 5, 7, wB.x, wB.y) }
  { float2 wA = twl[ZP32(t5 << 5)];
    CBFLY(0, 0, 1, wA.x, wA.y) CBFLY(1, 0, 1, wA.x, wA.y)
    CBFLY(0, 2, 3, wA.x, wA.y) CBFLY(1, 2, 3, wA.x, wA.y)
    CBFLY(0, 4, 5, wA.x, wA.y) CBFLY(1, 4, 5, wA.x, wA.y)
    CBFLY(0, 6, 7, wA.x, wA.y) CBFLY(1, 6, 7, wA.x, wA.y) }

  // ---- exchange 2: write back same slots, read (t>>2)*32 + (t&3) + 4j ----
  // (each slot was read only by this thread -> no barrier before write)
#pragma unroll
  for (int j = 0; j < 8; ++j) {
    int p = hi1 + t5 + 32 * j;
    Zs[0][ZP32(p)] = z[0][j];
    Zs[1][ZP32(p)] = z[1][j];
  }
  __syncthreads();
  int t3 = tid & 3, hi2 = (tid >> 2) << 5;
#pragma unroll
  for (int j = 0; j < 8; ++j) {
    int p = hi2 + t3 + 4 * j;
    z[0][j] = Zs[0][ZP32(p)];
    z[1][j] = Zs[1][ZP32(p)];
  }

  // ---- round 3: stages sh=4,3,2 ----
  BFLY2(0, 4, t3 << 6)
  BFLY2(1, 5, (t3 + 4) << 6)
  BFLY2(2, 6, (t3 + 8) << 6)
  BFLY2(3, 7, (t3 + 12) << 6)
  { float2 wA = twl[ZP32(t3 << 7)], wB = twl[ZP32((t3 + 4) << 7)];
    CBFLY(0, 0, 2, wA.x, wA.y) CBFLY(1, 0, 2, wA.x, wA.y)
    CBFLY(0, 1, 3, wB.x, wB.y) CBFLY(1, 1, 3, wB.x, wB.y)
    CBFLY(0, 4, 6, wA.x, wA.y) CBFLY(1, 4, 6, wA.x, wA.y)
    CBFLY(0, 5, 7, wB.x, wB.y) CBFLY(1, 5, 7, wB.x, wB.y) }
  { float2 wA = twl[ZP32(t3 << 8)];
    CBFLY(0, 0, 1, wA.x, wA.y) CBFLY(1, 0, 1, wA.x, wA.y)
    CBFLY(0, 2, 3, wA.x, wA.y) CBFLY(1, 2, 3, wA.x, wA.y)
    CBFLY(0, 4, 5, wA.x, wA.y) CBFLY(1, 4, 5, wA.x, wA.y)
    CBFLY(0, 6, 7, wA.x, wA.y) CBFLY(1, 6, 7, wA.x, wA.y) }

  // ---- exchange 3: write back same slots, read 8t + j ----
#pragma unroll
  for (int j = 0; j < 8; ++j) {
    int p = hi2 + t3 + 4 * j;
    Zs[0][ZP32(p)] = z[0][j];
    Zs[1][ZP32(p)] = z[1][j];
  }
  __syncthreads();
#pragma unroll
  for (int j = 0; j < 8; ++j) {
    int p = (tid << 3) + j;
    z[0][j] = Zs[0][ZP32(p)];
    z[1][j] = Zs[1][ZP32(p)];
  }

  // ---- round 4: stages sh=1 (w = 1 or -i), sh=0 (w = 1) ----
  CBFLY(0, 0, 2, 1.0f, 0.0f) CBFLY(1, 0, 2, 1.0f, 0.0f)
  CBFLY(0, 1, 3, 0.0f, -1.0f) CBFLY(1, 1, 3, 0.0f, -1.0f)
  CBFLY(0, 4, 6, 1.0f, 0.0f) CBFLY(1, 4, 6, 1.0f, 0.0f)
  CBFLY(0, 5, 7, 0.0f, -1.0f) CBFLY(1, 5, 7, 0.0f, -1.0f)
  CBFLY(0, 0, 1, 1.0f, 0.0f) CBFLY(1, 0, 1, 1.0f, 0.0f)
  CBFLY(0, 2, 3, 1.0f, 0.0f) CBFLY(1, 2, 3, 1.0f, 0.0f)
  CBFLY(0, 4, 5, 1.0f, 0.0f) CBFLY(1, 4, 5, 1.0f, 0.0f)
  CBFLY(0, 6, 7, 1.0f, 0.0f) CBFLY(1, 6, 7, 1.0f, 0.0f)

  // ---- final write (same slots as last read) + spectrum ----
#pragma unroll
  for (int j = 0; j < 8; ++j) {
    int p = (tid << 3) + j;
    Zs[0][ZP32(p)] = z[0][j];
    Zs[1][ZP32(p)] = z[1][j];
  }
  __syncthreads();
  float* Sb = S + (size_t)blockIdx.x * 2050;  // row = b*512 + channel-group
  for (int f = tid; f <= 1024; f += 256) {
    int rf = __brev((unsigned)f) >> 21;
    int rmf = __brev((unsigned)((2048 - f) & 2047)) >> 21;
    float pr = 0.f, pim = 0.f;
#pragma unroll
    for (int ch = 0; ch < 2; ++ch) {
      float2 zf = Zs[ch][ZP32(rf)], zm = Zs[ch][ZP32(rmf)];
      float Qr = 0.5f * (zf.x + zm.x), Qi = 0.5f * (zf.y - zm.y);
      float Kr = 0.5f * (zf.y + zm.y), Ki = -0.5f * (zf.x - zm.x);
      pr += Qr * Kr + Qi * Ki;
      pim += Qi * Kr - Qr * Ki;
    }
    Sb[2 * f] = pr;
    Sb[2 * f + 1] = pim;
  }
}

// ------------- reduce 512 partial spectrum rows -> 8-way S8 format ---------
__global__ __launch_bounds__(256) void spec_reduce_kernel(const float* __restrict__ Sbig,
                                                          float* __restrict__ S8) {
  int f = blockIdx.x * 256 + threadIdx.x;  // 0..2303, guard
  int sc = blockIdx.y;                     // 0..7 (64-row chunk)
  int b = blockIdx.z;                      // 0..7
  if (f >= 2050) return;
  const float* src = Sbig + ((size_t)b * 512 + (size_t)sc * 64) * 2050 + f;
  float s = 0.f;
  for (int i = 0; i < 64; ++i) s += src[(size_t)i * 2050];
  S8[((size_t)b * 8 + sc) * 2050 + f] = s;
}

// --------------- per-batch: inverse FFT -> mean_corr -> top-7 + softmax ----
__global__ __launch_bounds__(256) void corr_topk_kernel(const float* __restrict__ S,
                                                        int* __restrict__ delays,
                                                        float* __restrict__ alphas,
                                                        int C, int L) {
  __shared__ float2 W[2048];
  __shared__ float mc[2048];
  __shared__ float rv[4];
  __shared__ int ri[4];
  __shared__ float swv[7];
  __shared__ int sdi[7];
  int b = blockIdx.x, tid = threadIdx.x;
  const float* Sb = S + (size_t)b * 8 * 2050;
  for (int f = tid; f < 2048; f += 256) {
    int ff = f <= 1024 ? f : 2048 - f;
    float re = 0.f, im = 0.f;
    for (int s = 0; s < 8; ++s) {
      re += Sb[s * 2050 + 2 * ff];
      im += Sb[s * 2050 + 2 * ff + 1];
    }
    W[f] = make_float2(re, f <= 1024 ? -im : im);
  }
  __syncthreads();
  for (int sh = 10; sh >= 0; --sh) {
    int s = 1 << sh;
    for (int j = tid; j < 1024; j += 256) {
      int t = j & (s - 1);
      int i0 = ((j >> sh) << (sh + 1)) | t;
      int i1 = i0 + s;
      float2 a = W[i0], bb = W[i1];
      float ang = -PI_F * (float)t / (float)s;
      float sn, cs;
      __sincosf(ang, &sn, &cs);
      float2 d = make_float2(a.x - bb.x, a.y - bb.y);
      W[i0] = make_float2(a.x + bb.x, a.y + bb.y);
      W[i1] = make_float2(d.x * cs - d.y * sn, d.x * sn + d.y * cs);
    }
    __syncthreads();
  }
  float inv = 1.0f / ((float)C * (float)L);
  for (int t = tid; t < 2048; t += 256) mc[t] = W[__brev((unsigned)t) >> 21].x * inv;
  __syncthreads();
  int wv = tid >> 6, lane = tid & 63;
  for (int it = 0; it < 7; ++it) {
    float bvv = -1e30f;
    int bi = 0;
    for (int e = tid * 8; e < tid * 8 + 8; ++e) {
      float v = mc[e];
      if (v > bvv) { bvv = v; bi = e; }
    }
    for (int o = 32; o > 0; o >>= 1) {
      float ov = __shfl_down(bvv, o, 64);
      int oi = __shfl_down(bi, o, 64);
      if (ov > bvv || (ov == bvv && oi < bi)) { bvv = ov; bi = oi; }
    }
    if (lane == 0) { rv[wv] = bvv; ri[wv] = bi; }
    __syncthreads();
    if (tid == 0) {
      float fv = rv[0];
      int fi = ri[0];
      for (int w2 = 1; w2 < 4; ++w2)
        if (rv[w2] > fv || (rv[w2] == fv && ri[w2] < fi)) { fv = rv[w2]; fi = ri[w2]; }
      swv[it] = fv;
      sdi[it] = fi;
      mc[fi] = -1e30f;
    }
    __syncthreads();
  }
  if (tid == 0) {
    float mx = swv[0];
    for (int i = 1; i < 7; ++i) mx = fmaxf(mx, swv[i]);
    float e[7], s = 0.f;
    for (int i = 0; i < 7; ++i) { e[i] = expf(swv[i] - mx); s += e[i]; }
    for (int i = 0; i < 7; ++i) {
      alphas[b * 7 + i] = e[i] / s;
      delays[b * 7 + i] = sdi[i];
    }
  }
}

// ------------------- lag aggregation on xn (commuted past Wv) --------------
__global__ __launch_bounds__(256) void agg_kernel(const _Float16* __restrict__ v,
                                                  const int* __restrict__ delays,
                                                  const float* __restrict__ alphas,
                                                  _Float16* __restrict__ agg,
                                                  int L, int C) {
  int bt = blockIdx.x;
  int b = bt >> 11, t = bt & 2047;
  int tid = threadIdx.x;
  const _Float16* vb = v + (size_t)b * L * C;
  float ax = 0.f, ay = 0.f, az = 0.f, aw = 0.f;
#pragma unroll
  for (int i = 0; i < 7; ++i) {
    int d = delays[b * 7 + i];
    float a = alphas[b * 7 + i];
    int src = t + d;
    if (src >= L) src -= L;
    half4 x = ((const half4*)(vb + (size_t)src * C))[tid];
    ax += a * (float)x.x; ay += a * (float)x.y;
    az += a * (float)x.z; aw += a * (float)x.w;
  }
  half4 h = {(_Float16)ax, (_Float16)ay, (_Float16)az, (_Float16)aw};
  ((half4*)(agg + (size_t)bt * C))[tid] = h;
}

// ----------------- series decomposition: out = x - movavg25(x) -------------
template <int WRITE_H>
__global__ __launch_bounds__(256) void decomp_kernel(const float* __restrict__ xin,
                                                     float* __restrict__ xout,
                                                     _Float16* __restrict__ xh,
                                                     int L, int C) {
  int c = blockIdx.x * 256 + threadIdx.x;
  int t0 = blockIdx.y * 128;
  int b = blockIdx.z;
  const float* xb = xin + (size_t)b * L * C + c;
  float sum = 0.f;
  for (int j = t0 - 12; j <= t0 + 12; ++j) {
    int jc = j < 0 ? 0 : (j > L - 1 ? L - 1 : j);
    sum += xb[(size_t)jc * C];
  }
  for (int t = t0; t < t0 + 128; ++t) {
    float xv = xb[(size_t)t * C];
    float o = xv - sum * (1.0f / 25.0f);
    size_t oidx = ((size_t)b * L + t) * C + c;
    xout[oidx] = o;
    if (WRITE_H) xh[oidx] = (_Float16)o;
    int nj = t + 13; if (nj > L - 1) nj = L - 1;
    int oj = t - 12; if (oj < 0) oj = 0;
    sum += xb[(size_t)nj * C] - xb[(size_t)oj * C];
  }
}

// ----------- series decomposition, fp16 input: out = x - movavg25(x) -------
__global__ __launch_bounds__(256) void decomp_h_kernel(const _Float16* __restrict__ xin,
                                                       float* __restrict__ xout,
                                                       int L, int C) {
  int c = blockIdx.x * 256 + threadIdx.x;
  int t0 = blockIdx.y * 128;
  int b = blockIdx.z;
  const _Float16* xb = xin + (size_t)b * L * C + c;
  float sum = 0.f;
  for (int j = t0 - 12; j <= t0 + 12; ++j) {
    int jc = j < 0 ? 0 : (j > L - 1 ? L - 1 : j);
    sum += (float)xb[(size_t)jc * C];
  }
  for (int t = t0; t < t0 + 128; ++t) {
    float xv = (float)xb[(size_t)t * C];
    float o = xv - sum * (1.0f / 25.0f);
    xout[((size_t)b * L + t) * C + c] = o;
    int nj = t + 13; if (nj > L - 1) nj = L - 1;
    int oj = t - 12; if (oj < 0) oj = 0;
    sum += (float)xb[(size_t)nj * C] - (float)xb[(size_t)oj * C];
  }
}

// ------------------------------- launcher ----------------------------------
extern "C" void kernel_launch(void* const* d_in, const int* in_sizes, int n_in,
                              void* d_out, int out_size, void* d_ws, size_t ws_size,
                              hipStream_t stream) {
  const float* x = (const float*)d_in[0];
  const float* Wq = (const float*)d_in[1];
  const float* Wk = (const float*)d_in[2];
  const float* Wv = (const float*)d_in[3];
  const float* Wo = (const float*)d_in[4];
  const float* bo = (const float*)d_in[5];
  const float* lng = (const float*)d_in[6];
  const float* lnb = (const float*)d_in[7];
  const float* W1 = (const float*)d_in[8];
  const float* W2 = (const float*)d_in[9];
  float* out = (float*)d_out;

  const int B = 8, L = 2048, C = 1024, HD = 4096;
  const int M = B * L;  // 16384

  char* ws = (char*)d_ws;
  size_t off = 0;
  auto alloc = [&](size_t bytes) -> void* {
    void* p = ws + off;
    off = (off + bytes + 255) & ~(size_t)255;
    return p;
  };
  // ~150.6 MiB total (under the 152.1 MiB proven previously)
  _Float16* wqkh = (_Float16*)alloc((size_t)2 * C * C * 2); // 4 MB (q rows, then k rows)
  _Float16* wvoh = (_Float16*)alloc((size_t)C * C * 2);     // 2 MB (Wo*Wv)
  _Float16* w1h = (_Float16*)alloc((size_t)HD * C * 2);     // 8 MB
  _Float16* w2h = (_Float16*)alloc((size_t)C * HD * 2);     // 8 MB
  float* S8 = (float*)alloc((size_t)B * 8 * 2050 * 4);      // 512 KB (reduced spectrum)
  int* dl = (int*)alloc(B * 7 * 4);
  float* al = (float*)alloc(B * 7 * 4);
  _Float16* xn = (_Float16*)alloc((size_t)M * C * 2);       // 32 MB; later x2h
  _Float16* qkh = (_Float16*)alloc((size_t)M * 2 * C * 2);  // 64 MB [B,2C,L]; later x1/hid
  _Float16* vh = (_Float16*)alloc((size_t)4096 * 2050 * 4); // 33.6 MB: Sbig/wvT/woh, aggh, x3h
  (void)ws_size; (void)in_sizes; (void)n_in; (void)out_size;

  _Float16* wvT = vh;                        // setup-only (dead before corr_fft)
  _Float16* woh = vh + (size_t)C * C;        // setup-only (dead before corr_fft)
  float* Sbig = (float*)vh;       // partial spectra (steps 5-6), dead before agg
  _Float16* aggh = vh;            // agg of xn (from step 8)
  float* x1 = (float*)qkh;        // q,k dead after corr_fft (64 MB)
  _Float16* x2h = xn;             // xn dead after agg
  float* x2 = out;                // d_out doubles as x2 scratch
  _Float16* hid2 = qkh;           // FFN hidden half (M x 2048 fp16 = 64 MB); x1 dead
  _Float16* x3h = vh;             // FFN output fp16 (32 MB); aggh dead after attn GEMM

  // 1. weights -> fp16 (+ Wv transpose)
  cvt_f16_kernel<<<(C * C / 4 + 255) / 256, 256, 0, stream>>>(Wq, wqkh, C * C / 4);
  cvt_f16_kernel<<<(C * C / 4 + 255) / 256, 256, 0, stream>>>(Wk, wqkh + (size_t)C * C, C * C / 4);
  cvt_f16_kernel<<<(C * C / 4 + 255) / 256, 256, 0, stream>>>(Wo, woh, C * C / 4);
  transpose_f16_kernel<<<dim3(16, 16), 256, 0, stream>>>(Wv, wvT, C);
  cvt_f16_kernel<<<(HD * C / 4 + 255) / 256, 256, 0, stream>>>(W1, w1h, HD * C / 4);
  cvt_f16_kernel<<<(HD * C / 4 + 255) / 256, 256, 0, stream>>>(W2, w2h, HD * C / 4);
  // 2. Wvo[o,c] = sum_j Wo[o,j]*Wv[j,c]
  gemm256_kernel<4><<<16, 512, 0, stream>>>(woh, wvT, C, C, C, C, C,
                                            nullptr, wvoh, nullptr, nullptr);
  // 3. LayerNorm -> fp16
  ln_kernel<<<M, 256, 0, stream>>>(x, lng, lnb, xn, C);
  // 4. fused q,k GEMM -> transposed [B, 2C, L]
  gemm256_kernel<5><<<(M / 256) * (2 * C / 256), 512, 0, stream>>>(
      xn, wqkh, M, 2 * C, C, C, C, nullptr, qkh, nullptr, nullptr);
  // 5. channel FFTs -> per-block partial spectrum rows (no atomics)
  corr_fft_kernel<<<B * (C / 2), 256, 0, stream>>>(qkh, Sbig);
  // 6. reduce 512 partial rows -> 8-way S8
  spec_reduce_kernel<<<dim3(9, 8, 8), 256, 0, stream>>>(Sbig, S8);
  // 7. inverse FFT + top-7 + softmax
  corr_topk_kernel<<<B, 256, 0, stream>>>(S8, dl, al, C, L);
  // 8. lag aggregation on xn (commuted) -> aggh
  agg_kernel<<<B * L, 256, 0, stream>>>(xn, dl, al, aggh, L, C);
  // 9. attn = aggh * Wvo^T + bo + x -> x1 (fp32, qkh region)
  gemm256_kernel<1><<<(M / 256) * (C / 256), 512, 0, stream>>>(
      aggh, wvoh, M, C, C, C, C, x1, nullptr, bo, x);
  // 10. decomp1: x2 = x1 - movavg(x1) -> d_out + fp16 copy (xn region)
  decomp_kernel<1><<<dim3(C / 256, L / 128, B), 256, 0, stream>>>(x1, x2, x2h, L, C);
  // 11. FFN in 2 HD-halves: FFN1 -> hid2 (qkh region), FFN2 -> x3h fp16 (vh)
  //     pass0: x3h = acc + x2 (fp32 res); pass1: x3h += acc (fp16 RMW)
  for (int ci = 0; ci < 2; ++ci) {
    gemm256_kernel<2><<<(M / 256) * (2048 / 256), 512, 0, stream>>>(
        x2h, w1h + (size_t)ci * 2048 * C, M, 2048, C, C, C,
        nullptr, hid2, nullptr, nullptr);
    if (ci == 0) {
      gemm256_kernel<6><<<(M / 256) * (C / 256), 512, 0, stream>>>(
          hid2, w2h, M, C, 2048, 2048, HD, nullptr, x3h, nullptr, x2);
    } else {
      gemm256_kernel<7><<<(M / 256) * (C / 256), 512, 0, stream>>>(
          hid2, w2h + 2048, M, C, 2048, 2048, HD, nullptr, x3h, nullptr, nullptr);
    }
  }
  // 12. decomp2 (fp16 input) -> out
  decomp_h_kernel<<<dim3(C / 256, L / 128, B), 256, 0, stream>>>(x3h, out, L, C);
}

// Round 6
// 833.179 us; speedup vs baseline: 1.1599x; 1.0642x over previous
//
#include <hip/hip_runtime.h>
#include <cstdint>
#include <cstddef>

// ---------------------------------------------------------------------------
// AutoformerEncodeBlock R11 (= R10 + fast-erf GELU epilogue):
//  - EPI=2 epilogue: libm erff (branchy, ~60 cyc) replaced by A&S 7.1.26
//    rational erf approx (~15 VALU ops, max err 1.5e-7) -> FFN1's 128
//    erf calls/thread stop dominating (VALUBusy 42% -> ~25%).
//  - GEMM K-loop: R8 dual-barrier phase skeleton.
//  - FFN: HD in 2 halves; hid fp16 in dead qkh region; x3 fp16 in vh.
//  - corr_fft: register radix-8 FFT; Wvo fold; fused qk GEMM.
// ---------------------------------------------------------------------------

typedef _Float16 half8 __attribute__((ext_vector_type(8)));
typedef _Float16 half4 __attribute__((ext_vector_type(4)));
typedef float floatx4 __attribute__((ext_vector_type(4)));

#define PI_F 3.14159265358979323846f
#define ZP32(i) ((i) + ((i) >> 5))  // pad every 32 float2 elements

__device__ __forceinline__ void load_lds16(const void* g, void* l) {
  __builtin_amdgcn_global_load_lds((__attribute__((address_space(1))) void*)g,
                                   (__attribute__((address_space(3))) void*)l,
                                   16, 0, 0);
}

// exact-GELU via A&S 7.1.26 erf approximation (max abs err ~1.5e-7 on erf)
__device__ __forceinline__ float fast_gelu(float v) {
  float u = v * 0.70710678118654752f;
  float au = fabsf(u);
  float t = __builtin_amdgcn_rcpf(1.0f + 0.3275911f * au);
  float poly = t * (0.254829592f +
               t * (-0.284496736f +
               t * (1.421413741f +
               t * (-1.453152027f +
               t * 1.061405429f))));
  float e = __expf(-u * u);
  float erf_abs = 1.0f - poly * e;
  float erfv = copysignf(erf_abs, u);
  return 0.5f * v * (1.0f + erfv);
}

// ---------------------------- small utility kernels ------------------------

__global__ __launch_bounds__(256) void cvt_f16_kernel(const float* __restrict__ src,
                                                      _Float16* __restrict__ dst, int n4) {
  int i = blockIdx.x * 256 + threadIdx.x;
  if (i >= n4) return;
  float4 v = ((const float4*)src)[i];
  half4 h = {(_Float16)v.x, (_Float16)v.y, (_Float16)v.z, (_Float16)v.w};
  ((half4*)dst)[i] = h;
}

// dst[c, j] = src[j, c]  (n x n, fp32 -> fp16), 64x64 LDS tiles
__global__ __launch_bounds__(256) void transpose_f16_kernel(const float* __restrict__ src,
                                                            _Float16* __restrict__ dst, int n) {
  __shared__ float tile[64][65];
  int j0 = blockIdx.y * 64, c0 = blockIdx.x * 64;
  int tr = threadIdx.x >> 4;
  int tc = threadIdx.x & 15;
#pragma unroll
  for (int rr = 0; rr < 64; rr += 16) {
    float4 v = *(const float4*)(src + (size_t)(j0 + tr + rr) * n + c0 + tc * 4);
    tile[tr + rr][tc * 4 + 0] = v.x;
    tile[tr + rr][tc * 4 + 1] = v.y;
    tile[tr + rr][tc * 4 + 2] = v.z;
    tile[tr + rr][tc * 4 + 3] = v.w;
  }
  __syncthreads();
#pragma unroll
  for (int rr = 0; rr < 64; rr += 16) {
    int c = tr + rr;
    half4 h = {(_Float16)tile[tc * 4 + 0][c], (_Float16)tile[tc * 4 + 1][c],
               (_Float16)tile[tc * 4 + 2][c], (_Float16)tile[tc * 4 + 3][c]};
    *(half4*)(dst + (size_t)(c0 + c) * n + j0 + tc * 4) = h;
  }
}

// --------------------------------- LayerNorm -------------------------------
__global__ __launch_bounds__(256) void ln_kernel(const float* __restrict__ x,
                                                 const float* __restrict__ g,
                                                 const float* __restrict__ b,
                                                 _Float16* __restrict__ xn, int C) {
  int row = blockIdx.x;
  int t = threadIdx.x;
  const float4* xr = (const float4*)(x + (size_t)row * C);
  float4 v = xr[t];
  float s = v.x + v.y + v.z + v.w;
  float s2 = v.x * v.x + v.y * v.y + v.z * v.z + v.w * v.w;
  for (int o = 32; o > 0; o >>= 1) {
    s += __shfl_down(s, o, 64);
    s2 += __shfl_down(s2, o, 64);
  }
  __shared__ float red[8];
  int wave = t >> 6, lane = t & 63;
  if (lane == 0) { red[wave] = s; red[4 + wave] = s2; }
  __syncthreads();
  __shared__ float stats[2];
  if (t == 0) {
    float ts = red[0] + red[1] + red[2] + red[3];
    float ts2 = red[4] + red[5] + red[6] + red[7];
    float mu = ts / (float)C;
    float var = ts2 / (float)C - mu * mu;
    stats[0] = mu;
    stats[1] = 1.0f / sqrtf(var + 1e-5f);
  }
  __syncthreads();
  float mu = stats[0], rs = stats[1];
  float4 gv = ((const float4*)g)[t];
  float4 bv = ((const float4*)b)[t];
  half4 h = {(_Float16)((v.x - mu) * rs * gv.x + bv.x),
             (_Float16)((v.y - mu) * rs * gv.y + bv.y),
             (_Float16)((v.z - mu) * rs * gv.z + bv.z),
             (_Float16)((v.w - mu) * rs * gv.w + bv.w)};
  ((half4*)(xn + (size_t)row * C))[t] = h;
}

// ----------------------------------- GEMM ----------------------------------
// C[M,N] = A[M,K] * Bw[N,K]^T (fp16). 256x256 tile, BK=64, 8 waves (2x4),
// per-wave 128x64 output (acc[8][4]). 2-K-tile LDS double buffer; 8 staging
// chunks/K-tile spread 3|3|1|1 across phases (B0,B1,B2 | B3,A0,A2 | A1 | A3);
// counted vmcnt: end-ph1 vmcnt(6) guards this tile's A1/A3, end-ph3 vmcnt(2)
// guards next tile's B*+A0/A2. Per phase (m201 skeleton): ds_reads ->
// stage-issue -> s_barrier -> lgkmcnt(0) -> setprio(1) 16xMFMA setprio(0) ->
// [vmcnt] -> s_barrier. XOR-granule swizzle: source pre-swizzled (l7^l3),
// ds_read applies granule^(row&7). Zero bank conflicts (verified R7).
// EPI: 1 = +bias[col]+res fp32, 2 = fast GELU -> fp16, 4 = plain fp16,
//      5 = fp16 transposed [B, N, L] (L=2048),
//      6 = fp16 out = acc + res(fp32), 7 = fp16 RMW out += acc
template <int EPI>
__global__ __launch_bounds__(512, 2) void gemm256_kernel(
    const _Float16* __restrict__ A, const _Float16* __restrict__ Bw,
    int M, int N, int K, int lda, int ldb,
    float* __restrict__ outf, _Float16* __restrict__ outh,
    const float* __restrict__ bias, const float* __restrict__ res) {
  __shared__ _Float16 lds[2][2][256 * 64];  // [buf][A=0/B=1][256 rows x 64 halfs]

  int tid = threadIdx.x;
  int lane = tid & 63;
  int wave = tid >> 6;          // 0..7
  int wm = wave >> 2;           // 0..1  (M half)
  int wn = wave & 3;            // 0..3  (N quarter)
  int ln15 = lane & 15, q4 = lane >> 4;
  int l3 = lane >> 3, l7 = lane & 7;

  int nwg = gridDim.x, orig = blockIdx.x;
  int wg = ((nwg & 7) == 0) ? ((orig & 7) * (nwg >> 3) + (orig >> 3)) : orig;
  int nbn = N >> 8;
  size_t m0 = (size_t)(wg / nbn) << 8;
  size_t n0 = (size_t)(wg % nbn) << 8;

  // swizzled ds_read granule offsets (halfs)
  int sg0 = (q4 ^ l7) << 3;         // kk=0
  int sg1 = ((q4 + 4) ^ l7) << 3;   // kk=32

  floatx4 acc[8][4] = {};

  // staging: lane covers row (8*wave + l3) of each 64-row chunk, global
  // granule pre-swizzled to l7^l3 so linear LDS dest == swizzled layout.
  const _Float16* srcA = A + (m0 + 8 * wave + l3) * (size_t)lda + (size_t)((l7 ^ l3) * 8);
  const _Float16* srcB = Bw + (n0 + 8 * wave + l3) * (size_t)ldb + (size_t)((l7 ^ l3) * 8);
  char* ldsA0 = (char*)&lds[0][0][0] + wave * 1024;
  char* ldsB0 = (char*)&lds[0][1][0] + wave * 1024;

  // prologue: stage tile 0 (order B0,B1,B2,B3,A0,A2,A1,A3) into buf 0
  load_lds16(srcB, ldsB0);
  load_lds16(srcB + (size_t)64 * ldb, ldsB0 + 1 * 8192);
  load_lds16(srcB + (size_t)128 * ldb, ldsB0 + 2 * 8192);
  load_lds16(srcB + (size_t)192 * ldb, ldsB0 + 3 * 8192);
  load_lds16(srcA, ldsA0);
  load_lds16(srcA + (size_t)128 * lda, ldsA0 + 2 * 8192);
  load_lds16(srcA + (size_t)64 * lda, ldsA0 + 1 * 8192);
  load_lds16(srcA + (size_t)192 * lda, ldsA0 + 3 * 8192);
  // guard tile-0 reads (A1,A3 may stay outstanding)
  asm volatile("s_waitcnt vmcnt(2)" ::: "memory");
  __builtin_amdgcn_s_barrier();
  __builtin_amdgcn_sched_barrier(0);

  int nk = K >> 6;
  half8 bf[4][2], aA[2][2];

#define RD_B() _Pragma("unroll") for (int ni = 0; ni < 4; ++ni) {      \
    const _Float16* p_ = cB + ((wn * 64 + ni * 16 + ln15) << 6);       \
    bf[ni][0] = *(const half8*)(p_ + sg0);                             \
    bf[ni][1] = *(const half8*)(p_ + sg1); }
#define RD_A(mi) { const _Float16* p_ = cA + ((wm * 128 + (mi) * 16 + ln15) << 6); \
    aA[(mi) & 1][0] = *(const half8*)(p_ + sg0);                                   \
    aA[(mi) & 1][1] = *(const half8*)(p_ + sg1); }
#define MM(mi) _Pragma("unroll") for (int ni = 0; ni < 4; ++ni) {      \
    acc[mi][ni] = __builtin_amdgcn_mfma_f32_16x16x32_f16(aA[(mi) & 1][0], bf[ni][0], acc[mi][ni], 0, 0, 0); \
    acc[mi][ni] = __builtin_amdgcn_mfma_f32_16x16x32_f16(aA[(mi) & 1][1], bf[ni][1], acc[mi][ni], 0, 0, 0); }

#define PH_MID()                                            \
    __builtin_amdgcn_s_barrier();                           \
    asm volatile("s_waitcnt lgkmcnt(0)" ::: "memory");      \
    __builtin_amdgcn_sched_barrier(0);                      \
    __builtin_amdgcn_s_setprio(1);
#define PH_END()                                            \
    __builtin_amdgcn_s_setprio(0);                          \
    __builtin_amdgcn_s_barrier();                           \
    __builtin_amdgcn_sched_barrier(0);

  for (int t = 0; t < nk; ++t) {
    int cur = t & 1;
    const _Float16* cA = &lds[cur][0][0];
    const _Float16* cB = &lds[cur][1][0];
    const _Float16* As = srcA + (size_t)(t + 1) * 64;
    const _Float16* Bs = srcB + (size_t)(t + 1) * 64;
    char* stA = ldsA0 + (cur ^ 1) * 65536;
    char* stB = ldsB0 + (cur ^ 1) * 65536;
    bool pf = (t + 1 < nk);

    // ---- phase 0: MFMA mi=0,1 ----
    RD_B();
    RD_A(0); RD_A(1);
    if (pf) {
      load_lds16(Bs, stB);
      load_lds16(Bs + (size_t)64 * ldb, stB + 1 * 8192);
      load_lds16(Bs + (size_t)128 * ldb, stB + 2 * 8192);
    }
    PH_MID();
    MM(0); MM(1);
    PH_END();
    // ---- phase 1: MFMA mi=2,3; end-wait guards this tile's A1,A3 ----
    RD_A(2); RD_A(3);
    if (pf) {
      load_lds16(Bs + (size_t)192 * ldb, stB + 3 * 8192);
      load_lds16(As, stA);
      load_lds16(As + (size_t)128 * lda, stA + 2 * 8192);
    }
    PH_MID();
    MM(2); MM(3);
    __builtin_amdgcn_s_setprio(0);
    if (pf) {
      asm volatile("s_waitcnt vmcnt(6)" ::: "memory");
    } else {
      asm volatile("s_waitcnt vmcnt(0)" ::: "memory");
    }
    __builtin_amdgcn_s_barrier();
    __builtin_amdgcn_sched_barrier(0);
    // ---- phase 2: MFMA mi=4,5 ----
    RD_A(4); RD_A(5);
    if (pf) {
      load_lds16(As + (size_t)64 * lda, stA + 1 * 8192);
    }
    PH_MID();
    MM(4); MM(5);
    PH_END();
    // ---- phase 3: MFMA mi=6,7; end-wait guards next tile's B*,A0,A2 ----
    RD_A(6); RD_A(7);
    if (pf) {
      load_lds16(As + (size_t)192 * lda, stA + 3 * 8192);
    }
    PH_MID();
    MM(6); MM(7);
    __builtin_amdgcn_s_setprio(0);
    asm volatile("s_waitcnt vmcnt(2)" ::: "memory");
    __builtin_amdgcn_s_barrier();
    __builtin_amdgcn_sched_barrier(0);
  }
#undef RD_B
#undef RD_A
#undef MM
#undef PH_MID
#undef PH_END

#pragma unroll
  for (int mi = 0; mi < 8; ++mi) {
#pragma unroll
    for (int ni = 0; ni < 4; ++ni) {
      floatx4 a4 = acc[mi][ni];
      size_t rowb = m0 + wm * 128 + mi * 16 + q4 * 4;
      size_t col = n0 + wn * 64 + ni * 16 + ln15;
      if (EPI == 5) {
        size_t b = rowb >> 11, l0 = rowb & 2047;
        half4 h = {(_Float16)a4[0], (_Float16)a4[1], (_Float16)a4[2], (_Float16)a4[3]};
        *(half4*)(outh + (((size_t)b * N + col) << 11) + l0) = h;
      } else {
#pragma unroll
        for (int r = 0; r < 4; ++r) {
          size_t idx = (rowb + r) * (size_t)N + col;
          float v = a4[r];
          if (EPI == 1) {
            outf[idx] = v + bias[col] + res[idx];
          } else if (EPI == 2) {
            outh[idx] = (_Float16)fast_gelu(v);
          } else if (EPI == 6) {
            outh[idx] = (_Float16)(v + res[idx]);
          } else if (EPI == 7) {
            float prev = (float)outh[idx];
            outh[idx] = (_Float16)(v + prev);
          } else {
            outh[idx] = (_Float16)v;
          }
        }
      }
    }
  }
}

// --------------------- autocorrelation: register radix-8 FFT ---------------
// qk fused transposed layout F[b, ch, l], ch<1024 = q, ch>=1024 = k.
// block = (b, 2 channel-pairs), 256 threads. z = q + i*k; 2048-pt radix-2
// DIF FFT where 3 stages at a time run in registers (thread t holds 8 pts),
// separated by pad-32 conflict-free LDS exchanges. Hermitian split; partial
// spectrum row per block (no atomics), reduced by spec_reduce_kernel.

#define CBFLY(ch, ia, ib, wr, wi) {                      \
    float ax_ = z[ch][ia].x, ay_ = z[ch][ia].y;          \
    float bx_ = z[ch][ib].x, by_ = z[ch][ib].y;          \
    float dx_ = ax_ - bx_, dy_ = ay_ - by_;              \
    z[ch][ia].x = ax_ + bx_; z[ch][ia].y = ay_ + by_;    \
    z[ch][ib].x = dx_ * (wr) - dy_ * (wi);               \
    z[ch][ib].y = dx_ * (wi) + dy_ * (wr); }
#define BFLY2(ia, ib, m) { float2 w_ = twl[ZP32(m)];     \
    CBFLY(0, ia, ib, w_.x, w_.y) CBFLY(1, ia, ib, w_.x, w_.y) }

__global__ __launch_bounds__(256) void corr_fft_kernel(const _Float16* __restrict__ F,
                                                       float* __restrict__ S) {
  __shared__ float2 Zs[2][2112];   // 2048 + pad every 32
  __shared__ float2 twl[1056];     // 1024 twiddles, padded
  int tid = threadIdx.x;
  int b = blockIdx.x >> 9;
  int c0 = (blockIdx.x & 511) << 1;
  const _Float16* qb = F + ((size_t)(b * 2048 + c0) << 11);
  const _Float16* kb = F + ((size_t)(b * 2048 + 1024 + c0) << 11);

  // load 8 points per channel per thread: positions t + 256*j
  float2 z[2][8];
#pragma unroll
  for (int j = 0; j < 8; ++j) {
    int p = tid + 256 * j;
    z[0][j] = make_float2((float)qb[p], (float)kb[p]);
    z[1][j] = make_float2((float)qb[2048 + p], (float)kb[2048 + p]);
  }
  // twiddle table: twl[m] = exp(-2*pi*i*m/2048)
  for (int m = tid; m < 1024; m += 256) {
    float sn, cs;
    __sincosf(-PI_F * (float)m / 1024.0f, &sn, &cs);
    twl[ZP32(m)] = make_float2(cs, sn);
  }
  __syncthreads();

  // ---- round 1: stages sh=10,9,8  (positions t + 256j) ----
  BFLY2(0, 4, tid)
  BFLY2(1, 5, tid + 256)
  BFLY2(2, 6, tid + 512)
  BFLY2(3, 7, tid + 768)
  { float2 wA = twl[ZP32(tid << 1)], wB = twl[ZP32((tid + 256) << 1)];
    CBFLY(0, 0, 2, wA.x, wA.y) CBFLY(1, 0, 2, wA.x, wA.y)
    CBFLY(0, 1, 3, wB.x, wB.y) CBFLY(1, 1, 3, wB.x, wB.y)
    CBFLY(0, 4, 6, wA.x, wA.y) CBFLY(1, 4, 6, wA.x, wA.y)
    CBFLY(0, 5, 7, wB.x, wB.y) CBFLY(1, 5, 7, wB.x, wB.y) }
  { float2 wA = twl[ZP32(tid << 2)];
    CBFLY(0, 0, 1, wA.x, wA.y) CBFLY(1, 0, 1, wA.x, wA.y)
    CBFLY(0, 2, 3, wA.x, wA.y) CBFLY(1, 2, 3, wA.x, wA.y)
    CBFLY(0, 4, 5, wA.x, wA.y) CBFLY(1, 4, 5, wA.x, wA.y)
    CBFLY(0, 6, 7, wA.x, wA.y) CBFLY(1, 6, 7, wA.x, wA.y) }

  // ---- exchange 1: write t+256j, read (t>>5)*256 + (t&31) + 32j ----
#pragma unroll
  for (int j = 0; j < 8; ++j) {
    int p = tid + 256 * j;
    Zs[0][ZP32(p)] = z[0][j];
    Zs[1][ZP32(p)] = z[1][j];
  }
  __syncthreads();
  int t5 = tid & 31, hi1 = (tid >> 5) << 8;
#pragma unroll
  for (int j = 0; j < 8; ++j) {
    int p = hi1 + t5 + 32 * j;
    z[0][j] = Zs[0][ZP32(p)];
    z[1][j] = Zs[1][ZP32(p)];
  }

  // ---- round 2: stages sh=7,6,5 ----
  BFLY2(0, 4, t5 << 3)
  BFLY2(1, 5, (t5 + 32) << 3)
  BFLY2(2, 6, (t5 + 64) << 3)
  BFLY2(3, 7, (t5 + 96) << 3)
  { float2 wA = twl[ZP32(t5 << 4)], wB = twl[ZP32((t5 + 32) << 4)];
    CBFLY(0, 0, 2, wA.x, wA.y) CBFLY(1, 0, 2, wA.x, wA.y)
    CBFLY(0, 1, 3, wB.x, wB.y) CBFLY(1, 1, 3, wB.x, wB.y)
    CBFLY(0, 4, 6, wA.x, wA.y) CBFLY(1, 4, 6, wA.x, wA.y)
    CBFLY(0, 5, 7, wB.x, wB.y) CBFLY(1, 5, 7, wB.x, wB.y) }
  { float2 wA = twl[ZP32(t5 << 5)];
    CBFLY(0, 0, 1, wA.x, wA.y) CBFLY(1, 0, 1, wA.x, wA.y)
    CBFLY(0, 2, 3, wA.x, wA.y) CBFLY(1, 2, 3, wA.x, wA.y)
    CBFLY(0, 4, 5, wA.x, wA.y) CBFLY(1, 4, 5, wA.x, wA.y)
    CBFLY(0, 6, 7, wA.x, wA.y) CBFLY(1, 6, 7, wA.x, wA.y) }

  // ---- exchange 2: write back same slots, read (t>>2)*32 + (t&3) + 4j ----
  // (each slot was read only by this thread -> no barrier before write)
#pragma unroll
  for (int j = 0; j < 8; ++j) {
    int p = hi1 + t5 + 32 * j;
    Zs[0][ZP32(p)] = z[0][j];
    Zs[1][ZP32(p)] = z[1][j];
  }
  __syncthreads();
  int t3 = tid & 3, hi2 = (tid >> 2) << 5;
#pragma unroll
  for (int j = 0; j < 8; ++j) {
    int p = hi2 + t3 + 4 * j;
    z[0][j] = Zs[0][ZP32(p)];
    z[1][j] = Zs[1][ZP32(p)];
  }

  // ---- round 3: stages sh=4,3,2 ----
  BFLY2(0, 4, t3 << 6)
  BFLY2(1, 5, (t3 + 4) << 6)
  BFLY2(2, 6, (t3 + 8) << 6)
  BFLY2(3, 7, (t3 + 12) << 6)
  { float2 wA = twl[ZP32(t3 << 7)], wB = twl[ZP32((t3 + 4) << 7)];
    CBFLY(0, 0, 2, wA.x, wA.y) CBFLY(1, 0, 2, wA.x, wA.y)
    CBFLY(0, 1, 3, wB.x, wB.y) CBFLY(1, 1, 3, wB.x, wB.y)
    CBFLY(0, 4, 6, wA.x, wA.y) CBFLY(1, 4, 6, wA.x, wA.y)
    CBFLY(0, 5, 7, wB.x, wB.y) CBFLY(1, 5, 7, wB.x, wB.y) }
  { float2 wA = twl[ZP32(t3 << 8)];
    CBFLY(0, 0, 1, wA.x, wA.y) CBFLY(1, 0, 1, wA.x, wA.y)
    CBFLY(0, 2, 3, wA.x, wA.y) CBFLY(1, 2, 3, wA.x, wA.y)
    CBFLY(0, 4, 5, wA.x, wA.y) CBFLY(1, 4, 5, wA.x, wA.y)
    CBFLY(0, 6, 7, wA.x, wA.y) CBFLY(1, 6, 7, wA.x, wA.y) }

  // ---- exchange 3: write back same slots, read 8t + j ----
#pragma unroll
  for (int j = 0; j < 8; ++j) {
    int p = hi2 + t3 + 4 * j;
    Zs[0][ZP32(p)] = z[0][j];
    Zs[1][ZP32(p)] = z[1][j];
  }
  __syncthreads();
#pragma unroll
  for (int j = 0; j < 8; ++j) {
    int p = (tid << 3) + j;
    z[0][j] = Zs[0][ZP32(p)];
    z[1][j] = Zs[1][ZP32(p)];
  }

  // ---- round 4: stages sh=1 (w = 1 or -i), sh=0 (w = 1) ----
  CBFLY(0, 0, 2, 1.0f, 0.0f) CBFLY(1, 0, 2, 1.0f, 0.0f)
  CBFLY(0, 1, 3, 0.0f, -1.0f) CBFLY(1, 1, 3, 0.0f, -1.0f)
  CBFLY(0, 4, 6, 1.0f, 0.0f) CBFLY(1, 4, 6, 1.0f, 0.0f)
  CBFLY(0, 5, 7, 0.0f, -1.0f) CBFLY(1, 5, 7, 0.0f, -1.0f)
  CBFLY(0, 0, 1, 1.0f, 0.0f) CBFLY(1, 0, 1, 1.0f, 0.0f)
  CBFLY(0, 2, 3, 1.0f, 0.0f) CBFLY(1, 2, 3, 1.0f, 0.0f)
  CBFLY(0, 4, 5, 1.0f, 0.0f) CBFLY(1, 4, 5, 1.0f, 0.0f)
  CBFLY(0, 6, 7, 1.0f, 0.0f) CBFLY(1, 6, 7, 1.0f, 0.0f)

  // ---- final write (same slots as last read) + spectrum ----
#pragma unroll
  for (int j = 0; j < 8; ++j) {
    int p = (tid << 3) + j;
    Zs[0][ZP32(p)] = z[0][j];
    Zs[1][ZP32(p)] = z[1][j];
  }
  __syncthreads();
  float* Sb = S + (size_t)blockIdx.x * 2050;  // row = b*512 + channel-group
  for (int f = tid; f <= 1024; f += 256) {
    int rf = __brev((unsigned)f) >> 21;
    int rmf = __brev((unsigned)((2048 - f) & 2047)) >> 21;
    float pr = 0.f, pim = 0.f;
#pragma unroll
    for (int ch = 0; ch < 2; ++ch) {
      float2 zf = Zs[ch][ZP32(rf)], zm = Zs[ch][ZP32(rmf)];
      float Qr = 0.5f * (zf.x + zm.x), Qi = 0.5f * (zf.y - zm.y);
      float Kr = 0.5f * (zf.y + zm.y), Ki = -0.5f * (zf.x - zm.x);
      pr += Qr * Kr + Qi * Ki;
      pim += Qi * Kr - Qr * Ki;
    }
    Sb[2 * f] = pr;
    Sb[2 * f + 1] = pim;
  }
}

// ------------- reduce 512 partial spectrum rows -> 8-way S8 format ---------
__global__ __launch_bounds__(256) void spec_reduce_kernel(const float* __restrict__ Sbig,
                                                          float* __restrict__ S8) {
  int f = blockIdx.x * 256 + threadIdx.x;  // 0..2303, guard
  int sc = blockIdx.y;                     // 0..7 (64-row chunk)
  int b = blockIdx.z;                      // 0..7
  if (f >= 2050) return;
  const float* src = Sbig + ((size_t)b * 512 + (size_t)sc * 64) * 2050 + f;
  float s = 0.f;
  for (int i = 0; i < 64; ++i) s += src[(size_t)i * 2050];
  S8[((size_t)b * 8 + sc) * 2050 + f] = s;
}

// --------------- per-batch: inverse FFT -> mean_corr -> top-7 + softmax ----
__global__ __launch_bounds__(256) void corr_topk_kernel(const float* __restrict__ S,
                                                        int* __restrict__ delays,
                                                        float* __restrict__ alphas,
                                                        int C, int L) {
  __shared__ float2 W[2048];
  __shared__ float mc[2048];
  __shared__ float rv[4];
  __shared__ int ri[4];
  __shared__ float swv[7];
  __shared__ int sdi[7];
  int b = blockIdx.x, tid = threadIdx.x;
  const float* Sb = S + (size_t)b * 8 * 2050;
  for (int f = tid; f < 2048; f += 256) {
    int ff = f <= 1024 ? f : 2048 - f;
    float re = 0.f, im = 0.f;
    for (int s = 0; s < 8; ++s) {
      re += Sb[s * 2050 + 2 * ff];
      im += Sb[s * 2050 + 2 * ff + 1];
    }
    W[f] = make_float2(re, f <= 1024 ? -im : im);
  }
  __syncthreads();
  for (int sh = 10; sh >= 0; --sh) {
    int s = 1 << sh;
    for (int j = tid; j < 1024; j += 256) {
      int t = j & (s - 1);
      int i0 = ((j >> sh) << (sh + 1)) | t;
      int i1 = i0 + s;
      float2 a = W[i0], bb = W[i1];
      float ang = -PI_F * (float)t / (float)s;
      float sn, cs;
      __sincosf(ang, &sn, &cs);
      float2 d = make_float2(a.x - bb.x, a.y - bb.y);
      W[i0] = make_float2(a.x + bb.x, a.y + bb.y);
      W[i1] = make_float2(d.x * cs - d.y * sn, d.x * sn + d.y * cs);
    }
    __syncthreads();
  }
  float inv = 1.0f / ((float)C * (float)L);
  for (int t = tid; t < 2048; t += 256) mc[t] = W[__brev((unsigned)t) >> 21].x * inv;
  __syncthreads();
  int wv = tid >> 6, lane = tid & 63;
  for (int it = 0; it < 7; ++it) {
    float bvv = -1e30f;
    int bi = 0;
    for (int e = tid * 8; e < tid * 8 + 8; ++e) {
      float v = mc[e];
      if (v > bvv) { bvv = v; bi = e; }
    }
    for (int o = 32; o > 0; o >>= 1) {
      float ov = __shfl_down(bvv, o, 64);
      int oi = __shfl_down(bi, o, 64);
      if (ov > bvv || (ov == bvv && oi < bi)) { bvv = ov; bi = oi; }
    }
    if (lane == 0) { rv[wv] = bvv; ri[wv] = bi; }
    __syncthreads();
    if (tid == 0) {
      float fv = rv[0];
      int fi = ri[0];
      for (int w2 = 1; w2 < 4; ++w2)
        if (rv[w2] > fv || (rv[w2] == fv && ri[w2] < fi)) { fv = rv[w2]; fi = ri[w2]; }
      swv[it] = fv;
      sdi[it] = fi;
      mc[fi] = -1e30f;
    }
    __syncthreads();
  }
  if (tid == 0) {
    float mx = swv[0];
    for (int i = 1; i < 7; ++i) mx = fmaxf(mx, swv[i]);
    float e[7], s = 0.f;
    for (int i = 0; i < 7; ++i) { e[i] = expf(swv[i] - mx); s += e[i]; }
    for (int i = 0; i < 7; ++i) {
      alphas[b * 7 + i] = e[i] / s;
      delays[b * 7 + i] = sdi[i];
    }
  }
}

// ------------------- lag aggregation on xn (commuted past Wv) --------------
__global__ __launch_bounds__(256) void agg_kernel(const _Float16* __restrict__ v,
                                                  const int* __restrict__ delays,
                                                  const float* __restrict__ alphas,
                                                  _Float16* __restrict__ agg,
                                                  int L, int C) {
  int bt = blockIdx.x;
  int b = bt >> 11, t = bt & 2047;
  int tid = threadIdx.x;
  const _Float16* vb = v + (size_t)b * L * C;
  float ax = 0.f, ay = 0.f, az = 0.f, aw = 0.f;
#pragma unroll
  for (int i = 0; i < 7; ++i) {
    int d = delays[b * 7 + i];
    float a = alphas[b * 7 + i];
    int src = t + d;
    if (src >= L) src -= L;
    half4 x = ((const half4*)(vb + (size_t)src * C))[tid];
    ax += a * (float)x.x; ay += a * (float)x.y;
    az += a * (float)x.z; aw += a * (float)x.w;
  }
  half4 h = {(_Float16)ax, (_Float16)ay, (_Float16)az, (_Float16)aw};
  ((half4*)(agg + (size_t)bt * C))[tid] = h;
}

// ----------------- series decomposition: out = x - movavg25(x) -------------
template <int WRITE_H>
__global__ __launch_bounds__(256) void decomp_kernel(const float* __restrict__ xin,
                                                     float* __restrict__ xout,
                                                     _Float16* __restrict__ xh,
                                                     int L, int C) {
  int c = blockIdx.x * 256 + threadIdx.x;
  int t0 = blockIdx.y * 128;
  int b = blockIdx.z;
  const float* xb = xin + (size_t)b * L * C + c;
  float sum = 0.f;
  for (int j = t0 - 12; j <= t0 + 12; ++j) {
    int jc = j < 0 ? 0 : (j > L - 1 ? L - 1 : j);
    sum += xb[(size_t)jc * C];
  }
  for (int t = t0; t < t0 + 128; ++t) {
    float xv = xb[(size_t)t * C];
    float o = xv - sum * (1.0f / 25.0f);
    size_t oidx = ((size_t)b * L + t) * C + c;
    xout[oidx] = o;
    if (WRITE_H) xh[oidx] = (_Float16)o;
    int nj = t + 13; if (nj > L - 1) nj = L - 1;
    int oj = t - 12; if (oj < 0) oj = 0;
    sum += xb[(size_t)nj * C] - xb[(size_t)oj * C];
  }
}

// ----------- series decomposition, fp16 input: out = x - movavg25(x) -------
__global__ __launch_bounds__(256) void decomp_h_kernel(const _Float16* __restrict__ xin,
                                                       float* __restrict__ xout,
                                                       int L, int C) {
  int c = blockIdx.x * 256 + threadIdx.x;
  int t0 = blockIdx.y * 128;
  int b = blockIdx.z;
  const _Float16* xb = xin + (size_t)b * L * C + c;
  float sum = 0.f;
  for (int j = t0 - 12; j <= t0 + 12; ++j) {
    int jc = j < 0 ? 0 : (j > L - 1 ? L - 1 : j);
    sum += (float)xb[(size_t)jc * C];
  }
  for (int t = t0; t < t0 + 128; ++t) {
    float xv = (float)xb[(size_t)t * C];
    float o = xv - sum * (1.0f / 25.0f);
    xout[((size_t)b * L + t) * C + c] = o;
    int nj = t + 13; if (nj > L - 1) nj = L - 1;
    int oj = t - 12; if (oj < 0) oj = 0;
    sum += (float)xb[(size_t)nj * C] - (float)xb[(size_t)oj * C];
  }
}

// ------------------------------- launcher ----------------------------------
extern "C" void kernel_launch(void* const* d_in, const int* in_sizes, int n_in,
                              void* d_out, int out_size, void* d_ws, size_t ws_size,
                              hipStream_t stream) {
  const float* x = (const float*)d_in[0];
  const float* Wq = (const float*)d_in[1];
  const float* Wk = (const float*)d_in[2];
  const float* Wv = (const float*)d_in[3];
  const float* Wo = (const float*)d_in[4];
  const float* bo = (const float*)d_in[5];
  const float* lng = (const float*)d_in[6];
  const float* lnb = (const float*)d_in[7];
  const float* W1 = (const float*)d_in[8];
  const float* W2 = (const float*)d_in[9];
  float* out = (float*)d_out;

  const int B = 8, L = 2048, C = 1024, HD = 4096;
  const int M = B * L;  // 16384

  char* ws = (char*)d_ws;
  size_t off = 0;
  auto alloc = [&](size_t bytes) -> void* {
    void* p = ws + off;
    off = (off + bytes + 255) & ~(size_t)255;
    return p;
  };
  // ~150.6 MiB total (under the 152.1 MiB proven previously)
  _Float16* wqkh = (_Float16*)alloc((size_t)2 * C * C * 2); // 4 MB (q rows, then k rows)
  _Float16* wvoh = (_Float16*)alloc((size_t)C * C * 2);     // 2 MB (Wo*Wv)
  _Float16* w1h = (_Float16*)alloc((size_t)HD * C * 2);     // 8 MB
  _Float16* w2h = (_Float16*)alloc((size_t)C * HD * 2);     // 8 MB
  float* S8 = (float*)alloc((size_t)B * 8 * 2050 * 4);      // 512 KB (reduced spectrum)
  int* dl = (int*)alloc(B * 7 * 4);
  float* al = (float*)alloc(B * 7 * 4);
  _Float16* xn = (_Float16*)alloc((size_t)M * C * 2);       // 32 MB; later x2h
  _Float16* qkh = (_Float16*)alloc((size_t)M * 2 * C * 2);  // 64 MB [B,2C,L]; later x1/hid
  _Float16* vh = (_Float16*)alloc((size_t)4096 * 2050 * 4); // 33.6 MB: Sbig/wvT/woh, aggh, x3h
  (void)ws_size; (void)in_sizes; (void)n_in; (void)out_size;

  _Float16* wvT = vh;                        // setup-only (dead before corr_fft)
  _Float16* woh = vh + (size_t)C * C;        // setup-only (dead before corr_fft)
  float* Sbig = (float*)vh;       // partial spectra (steps 5-6), dead before agg
  _Float16* aggh = vh;            // agg of xn (from step 8)
  float* x1 = (float*)qkh;        // q,k dead after corr_fft (64 MB)
  _Float16* x2h = xn;             // xn dead after agg
  float* x2 = out;                // d_out doubles as x2 scratch
  _Float16* hid2 = qkh;           // FFN hidden half (M x 2048 fp16 = 64 MB); x1 dead
  _Float16* x3h = vh;             // FFN output fp16 (32 MB); aggh dead after attn GEMM

  // 1. weights -> fp16 (+ Wv transpose)
  cvt_f16_kernel<<<(C * C / 4 + 255) / 256, 256, 0, stream>>>(Wq, wqkh, C * C / 4);
  cvt_f16_kernel<<<(C * C / 4 + 255) / 256, 256, 0, stream>>>(Wk, wqkh + (size_t)C * C, C * C / 4);
  cvt_f16_kernel<<<(C * C / 4 + 255) / 256, 256, 0, stream>>>(Wo, woh, C * C / 4);
  transpose_f16_kernel<<<dim3(16, 16), 256, 0, stream>>>(Wv, wvT, C);
  cvt_f16_kernel<<<(HD * C / 4 + 255) / 256, 256, 0, stream>>>(W1, w1h, HD * C / 4);
  cvt_f16_kernel<<<(HD * C / 4 + 255) / 256, 256, 0, stream>>>(W2, w2h, HD * C / 4);
  // 2. Wvo[o,c] = sum_j Wo[o,j]*Wv[j,c]
  gemm256_kernel<4><<<16, 512, 0, stream>>>(woh, wvT, C, C, C, C, C,
                                            nullptr, wvoh, nullptr, nullptr);
  // 3. LayerNorm -> fp16
  ln_kernel<<<M, 256, 0, stream>>>(x, lng, lnb, xn, C);
  // 4. fused q,k GEMM -> transposed [B, 2C, L]
  gemm256_kernel<5><<<(M / 256) * (2 * C / 256), 512, 0, stream>>>(
      xn, wqkh, M, 2 * C, C, C, C, nullptr, qkh, nullptr, nullptr);
  // 5. channel FFTs -> per-block partial spectrum rows (no atomics)
  corr_fft_kernel<<<B * (C / 2), 256, 0, stream>>>(qkh, Sbig);
  // 6. reduce 512 partial rows -> 8-way S8
  spec_reduce_kernel<<<dim3(9, 8, 8), 256, 0, stream>>>(Sbig, S8);
  // 7. inverse FFT + top-7 + softmax
  corr_topk_kernel<<<B, 256, 0, stream>>>(S8, dl, al, C, L);
  // 8. lag aggregation on xn (commuted) -> aggh
  agg_kernel<<<B * L, 256, 0, stream>>>(xn, dl, al, aggh, L, C);
  // 9. attn = aggh * Wvo^T + bo + x -> x1 (fp32, qkh region)
  gemm256_kernel<1><<<(M / 256) * (C / 256), 512, 0, stream>>>(
      aggh, wvoh, M, C, C, C, C, x1, nullptr, bo, x);
  // 10. decomp1: x2 = x1 - movavg(x1) -> d_out + fp16 copy (xn region)
  decomp_kernel<1><<<dim3(C / 256, L / 128, B), 256, 0, stream>>>(x1, x2, x2h, L, C);
  // 11. FFN in 2 HD-halves: FFN1 -> hid2 (qkh region), FFN2 -> x3h fp16 (vh)
  //     pass0: x3h = acc + x2 (fp32 res); pass1: x3h += acc (fp16 RMW)
  for (int ci = 0; ci < 2; ++ci) {
    gemm256_kernel<2><<<(M / 256) * (2048 / 256), 512, 0, stream>>>(
        x2h, w1h + (size_t)ci * 2048 * C, M, 2048, C, C, C,
        nullptr, hid2, nullptr, nullptr);
    if (ci == 0) {
      gemm256_kernel<6><<<(M / 256) * (C / 256), 512, 0, stream>>>(
          hid2, w2h, M, C, 2048, 2048, HD, nullptr, x3h, nullptr, x2);
    } else {
      gemm256_kernel<7><<<(M / 256) * (C / 256), 512, 0, stream>>>(
          hid2, w2h + 2048, M, C, 2048, 2048, HD, nullptr, x3h, nullptr, nullptr);
    }
  }
  // 12. decomp2 (fp16 input) -> out
  decomp_h_kernel<<<dim3(C / 256, L / 128, B), 256, 0, stream>>>(x3h, out, L, C);
}

// Round 7
// 792.173 us; speedup vs baseline: 1.2200x; 1.0518x over previous
//
#include <hip/hip_runtime.h>
#include <cstdint>
#include <cstddef>

// ---------------------------------------------------------------------------
// AutoformerEncodeBlock R12:
//  - LDS-staged GEMM epilogue (EPI 2/7/8/9): acc tile -> LDS (128KB, dead
//    after K-loop) -> row-linear half8 global stores (16 vec ops/thread vs
//    128 scalar). RMW/res reads coalesced on read-back side.
//  - fp16 residual path: attn out x1 fp16 (EPI=9), decomp1 fp16->fp16 (fp32
//    x2 eliminated), FFN2 pass0 res = x2h fp16 (EPI=8). ~160 MB saved.
//  - GEMM K-loop: R8 dual-barrier phase skeleton (structural plateau).
//  - corr_fft: register radix-8 FFT; Wvo fold; fused qk GEMM; fast GELU.
// ---------------------------------------------------------------------------

typedef _Float16 half8 __attribute__((ext_vector_type(8)));
typedef _Float16 half4 __attribute__((ext_vector_type(4)));
typedef float floatx4 __attribute__((ext_vector_type(4)));

#define PI_F 3.14159265358979323846f
#define ZP32(i) ((i) + ((i) >> 5))  // pad every 32 float2 elements

__device__ __forceinline__ void load_lds16(const void* g, void* l) {
  __builtin_amdgcn_global_load_lds((__attribute__((address_space(1))) void*)g,
                                   (__attribute__((address_space(3))) void*)l,
                                   16, 0, 0);
}

// exact-GELU via A&S 7.1.26 erf approximation (max abs err ~1.5e-7 on erf)
__device__ __forceinline__ float fast_gelu(float v) {
  float u = v * 0.70710678118654752f;
  float au = fabsf(u);
  float t = __builtin_amdgcn_rcpf(1.0f + 0.3275911f * au);
  float poly = t * (0.254829592f +
               t * (-0.284496736f +
               t * (1.421413741f +
               t * (-1.453152027f +
               t * 1.061405429f))));
  float e = __expf(-u * u);
  float erf_abs = 1.0f - poly * e;
  float erfv = copysignf(erf_abs, u);
  return 0.5f * v * (1.0f + erfv);
}

// ---------------------------- small utility kernels ------------------------

__global__ __launch_bounds__(256) void cvt_f16_kernel(const float* __restrict__ src,
                                                      _Float16* __restrict__ dst, int n4) {
  int i = blockIdx.x * 256 + threadIdx.x;
  if (i >= n4) return;
  float4 v = ((const float4*)src)[i];
  half4 h = {(_Float16)v.x, (_Float16)v.y, (_Float16)v.z, (_Float16)v.w};
  ((half4*)dst)[i] = h;
}

// dst[c, j] = src[j, c]  (n x n, fp32 -> fp16), 64x64 LDS tiles
__global__ __launch_bounds__(256) void transpose_f16_kernel(const float* __restrict__ src,
                                                            _Float16* __restrict__ dst, int n) {
  __shared__ float tile[64][65];
  int j0 = blockIdx.y * 64, c0 = blockIdx.x * 64;
  int tr = threadIdx.x >> 4;
  int tc = threadIdx.x & 15;
#pragma unroll
  for (int rr = 0; rr < 64; rr += 16) {
    float4 v = *(const float4*)(src + (size_t)(j0 + tr + rr) * n + c0 + tc * 4);
    tile[tr + rr][tc * 4 + 0] = v.x;
    tile[tr + rr][tc * 4 + 1] = v.y;
    tile[tr + rr][tc * 4 + 2] = v.z;
    tile[tr + rr][tc * 4 + 3] = v.w;
  }
  __syncthreads();
#pragma unroll
  for (int rr = 0; rr < 64; rr += 16) {
    int c = tr + rr;
    half4 h = {(_Float16)tile[tc * 4 + 0][c], (_Float16)tile[tc * 4 + 1][c],
               (_Float16)tile[tc * 4 + 2][c], (_Float16)tile[tc * 4 + 3][c]};
    *(half4*)(dst + (size_t)(c0 + c) * n + j0 + tc * 4) = h;
  }
}

// --------------------------------- LayerNorm -------------------------------
__global__ __launch_bounds__(256) void ln_kernel(const float* __restrict__ x,
                                                 const float* __restrict__ g,
                                                 const float* __restrict__ b,
                                                 _Float16* __restrict__ xn, int C) {
  int row = blockIdx.x;
  int t = threadIdx.x;
  const float4* xr = (const float4*)(x + (size_t)row * C);
  float4 v = xr[t];
  float s = v.x + v.y + v.z + v.w;
  float s2 = v.x * v.x + v.y * v.y + v.z * v.z + v.w * v.w;
  for (int o = 32; o > 0; o >>= 1) {
    s += __shfl_down(s, o, 64);
    s2 += __shfl_down(s2, o, 64);
  }
  __shared__ float red[8];
  int wave = t >> 6, lane = t & 63;
  if (lane == 0) { red[wave] = s; red[4 + wave] = s2; }
  __syncthreads();
  __shared__ float stats[2];
  if (t == 0) {
    float ts = red[0] + red[1] + red[2] + red[3];
    float ts2 = red[4] + red[5] + red[6] + red[7];
    float mu = ts / (float)C;
    float var = ts2 / (float)C - mu * mu;
    stats[0] = mu;
    stats[1] = 1.0f / sqrtf(var + 1e-5f);
  }
  __syncthreads();
  float mu = stats[0], rs = stats[1];
  float4 gv = ((const float4*)g)[t];
  float4 bv = ((const float4*)b)[t];
  half4 h = {(_Float16)((v.x - mu) * rs * gv.x + bv.x),
             (_Float16)((v.y - mu) * rs * gv.y + bv.y),
             (_Float16)((v.z - mu) * rs * gv.z + bv.z),
             (_Float16)((v.w - mu) * rs * gv.w + bv.w)};
  ((half4*)(xn + (size_t)row * C))[t] = h;
}

// ----------------------------------- GEMM ----------------------------------
// C[M,N] = A[M,K] * Bw[N,K]^T (fp16). 256x256 tile, BK=64, 8 waves (2x4),
// per-wave 128x64 output (acc[8][4]). R8 dual-barrier phase skeleton with
// counted vmcnt (see R8 comments). XOR-granule swizzle, 0 bank conflicts.
// EPI: 2 = fast GELU -> fp16 (staged), 4 = plain fp16 (scalar),
//      5 = fp16 transposed [B, N, L] (L=2048, scalar),
//      7 = fp16 RMW out += acc (staged, coalesced),
//      8 = fp16 out = acc + resh fp16 (staged),
//      9 = fp16 out = acc + bias + res fp32 (staged)
template <int EPI>
__global__ __launch_bounds__(512, 2) void gemm256_kernel(
    const _Float16* __restrict__ A, const _Float16* __restrict__ Bw,
    int M, int N, int K, int lda, int ldb,
    float* __restrict__ outf, _Float16* __restrict__ outh,
    const float* __restrict__ bias, const float* __restrict__ res,
    const _Float16* __restrict__ resh) {
  __shared__ _Float16 lds[2][2][256 * 64];  // [buf][A=0/B=1][256 rows x 64 halfs]

  int tid = threadIdx.x;
  int lane = tid & 63;
  int wave = tid >> 6;          // 0..7
  int wm = wave >> 2;           // 0..1  (M half)
  int wn = wave & 3;            // 0..3  (N quarter)
  int ln15 = lane & 15, q4 = lane >> 4;
  int l3 = lane >> 3, l7 = lane & 7;

  int nwg = gridDim.x, orig = blockIdx.x;
  int wg = ((nwg & 7) == 0) ? ((orig & 7) * (nwg >> 3) + (orig >> 3)) : orig;
  int nbn = N >> 8;
  size_t m0 = (size_t)(wg / nbn) << 8;
  size_t n0 = (size_t)(wg % nbn) << 8;

  // swizzled ds_read granule offsets (halfs)
  int sg0 = (q4 ^ l7) << 3;         // kk=0
  int sg1 = ((q4 + 4) ^ l7) << 3;   // kk=32

  floatx4 acc[8][4] = {};

  // staging: lane covers row (8*wave + l3) of each 64-row chunk, global
  // granule pre-swizzled to l7^l3 so linear LDS dest == swizzled layout.
  const _Float16* srcA = A + (m0 + 8 * wave + l3) * (size_t)lda + (size_t)((l7 ^ l3) * 8);
  const _Float16* srcB = Bw + (n0 + 8 * wave + l3) * (size_t)ldb + (size_t)((l7 ^ l3) * 8);
  char* ldsA0 = (char*)&lds[0][0][0] + wave * 1024;
  char* ldsB0 = (char*)&lds[0][1][0] + wave * 1024;

  // prologue: stage tile 0 (order B0,B1,B2,B3,A0,A2,A1,A3) into buf 0
  load_lds16(srcB, ldsB0);
  load_lds16(srcB + (size_t)64 * ldb, ldsB0 + 1 * 8192);
  load_lds16(srcB + (size_t)128 * ldb, ldsB0 + 2 * 8192);
  load_lds16(srcB + (size_t)192 * ldb, ldsB0 + 3 * 8192);
  load_lds16(srcA, ldsA0);
  load_lds16(srcA + (size_t)128 * lda, ldsA0 + 2 * 8192);
  load_lds16(srcA + (size_t)64 * lda, ldsA0 + 1 * 8192);
  load_lds16(srcA + (size_t)192 * lda, ldsA0 + 3 * 8192);
  // guard tile-0 reads (A1,A3 may stay outstanding)
  asm volatile("s_waitcnt vmcnt(2)" ::: "memory");
  __builtin_amdgcn_s_barrier();
  __builtin_amdgcn_sched_barrier(0);

  int nk = K >> 6;
  half8 bf[4][2], aA[2][2];

#define RD_B() _Pragma("unroll") for (int ni = 0; ni < 4; ++ni) {      \
    const _Float16* p_ = cB + ((wn * 64 + ni * 16 + ln15) << 6);       \
    bf[ni][0] = *(const half8*)(p_ + sg0);                             \
    bf[ni][1] = *(const half8*)(p_ + sg1); }
#define RD_A(mi) { const _Float16* p_ = cA + ((wm * 128 + (mi) * 16 + ln15) << 6); \
    aA[(mi) & 1][0] = *(const half8*)(p_ + sg0);                                   \
    aA[(mi) & 1][1] = *(const half8*)(p_ + sg1); }
#define MM(mi) _Pragma("unroll") for (int ni = 0; ni < 4; ++ni) {      \
    acc[mi][ni] = __builtin_amdgcn_mfma_f32_16x16x32_f16(aA[(mi) & 1][0], bf[ni][0], acc[mi][ni], 0, 0, 0); \
    acc[mi][ni] = __builtin_amdgcn_mfma_f32_16x16x32_f16(aA[(mi) & 1][1], bf[ni][1], acc[mi][ni], 0, 0, 0); }

#define PH_MID()                                            \
    __builtin_amdgcn_s_barrier();                           \
    asm volatile("s_waitcnt lgkmcnt(0)" ::: "memory");      \
    __builtin_amdgcn_sched_barrier(0);                      \
    __builtin_amdgcn_s_setprio(1);
#define PH_END()                                            \
    __builtin_amdgcn_s_setprio(0);                          \
    __builtin_amdgcn_s_barrier();                           \
    __builtin_amdgcn_sched_barrier(0);

  for (int t = 0; t < nk; ++t) {
    int cur = t & 1;
    const _Float16* cA = &lds[cur][0][0];
    const _Float16* cB = &lds[cur][1][0];
    const _Float16* As = srcA + (size_t)(t + 1) * 64;
    const _Float16* Bs = srcB + (size_t)(t + 1) * 64;
    char* stA = ldsA0 + (cur ^ 1) * 65536;
    char* stB = ldsB0 + (cur ^ 1) * 65536;
    bool pf = (t + 1 < nk);

    // ---- phase 0: MFMA mi=0,1 ----
    RD_B();
    RD_A(0); RD_A(1);
    if (pf) {
      load_lds16(Bs, stB);
      load_lds16(Bs + (size_t)64 * ldb, stB + 1 * 8192);
      load_lds16(Bs + (size_t)128 * ldb, stB + 2 * 8192);
    }
    PH_MID();
    MM(0); MM(1);
    PH_END();
    // ---- phase 1: MFMA mi=2,3; end-wait guards this tile's A1,A3 ----
    RD_A(2); RD_A(3);
    if (pf) {
      load_lds16(Bs + (size_t)192 * ldb, stB + 3 * 8192);
      load_lds16(As, stA);
      load_lds16(As + (size_t)128 * lda, stA + 2 * 8192);
    }
    PH_MID();
    MM(2); MM(3);
    __builtin_amdgcn_s_setprio(0);
    if (pf) {
      asm volatile("s_waitcnt vmcnt(6)" ::: "memory");
    } else {
      asm volatile("s_waitcnt vmcnt(0)" ::: "memory");
    }
    __builtin_amdgcn_s_barrier();
    __builtin_amdgcn_sched_barrier(0);
    // ---- phase 2: MFMA mi=4,5 ----
    RD_A(4); RD_A(5);
    if (pf) {
      load_lds16(As + (size_t)64 * lda, stA + 1 * 8192);
    }
    PH_MID();
    MM(4); MM(5);
    PH_END();
    // ---- phase 3: MFMA mi=6,7; end-wait guards next tile's B*,A0,A2 ----
    RD_A(6); RD_A(7);
    if (pf) {
      load_lds16(As + (size_t)192 * lda, stA + 3 * 8192);
    }
    PH_MID();
    MM(6); MM(7);
    __builtin_amdgcn_s_setprio(0);
    asm volatile("s_waitcnt vmcnt(2)" ::: "memory");
    __builtin_amdgcn_s_barrier();
    __builtin_amdgcn_sched_barrier(0);
  }
#undef RD_B
#undef RD_A
#undef MM
#undef PH_MID
#undef PH_END

  if (EPI == 2 || EPI == 7 || EPI == 8 || EPI == 9) {
    // ---- LDS-staged epilogue: acc tile -> LDS fp16 -> coalesced half8 ----
    _Float16* eb = (_Float16*)&lds[0][0][0];  // 256 x 256 fp16 = 128 KiB
#pragma unroll
    for (int mi = 0; mi < 8; ++mi) {
#pragma unroll
      for (int ni = 0; ni < 4; ++ni) {
        floatx4 a4 = acc[mi][ni];
        int erow = wm * 128 + mi * 16 + q4 * 4;
        int ecol = wn * 64 + ni * 16 + ln15;
#pragma unroll
        for (int r = 0; r < 4; ++r) {
          float v = a4[r];
          if (EPI == 2) v = fast_gelu(v);
          eb[(size_t)(erow + r) * 256 + ecol] = (_Float16)v;
        }
      }
    }
    __syncthreads();
    int baser = (tid >> 6) * 32 + (((tid & 63) >> 5) << 4);
    int ecol2 = (tid & 31) << 3;
    float4 bv0, bv1;
    if (EPI == 9) {
      bv0 = *(const float4*)(bias + n0 + ecol2);
      bv1 = *(const float4*)(bias + n0 + ecol2 + 4);
    }
#pragma unroll
    for (int jr = 0; jr < 16; ++jr) {
      int row = baser + jr;
      half8 hv = *(const half8*)(eb + (size_t)row * 256 + ecol2);
      size_t gidx = (m0 + row) * (size_t)N + n0 + ecol2;
      if (EPI == 7) {
        half8 pv = *(const half8*)(outh + gidx);
#pragma unroll
        for (int k = 0; k < 8; ++k) hv[k] = (_Float16)((float)hv[k] + (float)pv[k]);
      } else if (EPI == 8) {
        half8 pv = *(const half8*)(resh + gidx);
#pragma unroll
        for (int k = 0; k < 8; ++k) hv[k] = (_Float16)((float)hv[k] + (float)pv[k]);
      } else if (EPI == 9) {
        float4 rv0 = *(const float4*)(res + gidx);
        float4 rv1 = *(const float4*)(res + gidx + 4);
        hv[0] = (_Float16)((float)hv[0] + bv0.x + rv0.x);
        hv[1] = (_Float16)((float)hv[1] + bv0.y + rv0.y);
        hv[2] = (_Float16)((float)hv[2] + bv0.z + rv0.z);
        hv[3] = (_Float16)((float)hv[3] + bv0.w + rv0.w);
        hv[4] = (_Float16)((float)hv[4] + bv1.x + rv1.x);
        hv[5] = (_Float16)((float)hv[5] + bv1.y + rv1.y);
        hv[6] = (_Float16)((float)hv[6] + bv1.z + rv1.z);
        hv[7] = (_Float16)((float)hv[7] + bv1.w + rv1.w);
      }
      *(half8*)(outh + gidx) = hv;
    }
  } else {
    // ---- legacy per-fragment epilogue (EPI 4, 5) ----
#pragma unroll
    for (int mi = 0; mi < 8; ++mi) {
#pragma unroll
      for (int ni = 0; ni < 4; ++ni) {
        floatx4 a4 = acc[mi][ni];
        size_t rowb = m0 + wm * 128 + mi * 16 + q4 * 4;
        size_t col = n0 + wn * 64 + ni * 16 + ln15;
        if (EPI == 5) {
          size_t b = rowb >> 11, l0 = rowb & 2047;
          half4 h = {(_Float16)a4[0], (_Float16)a4[1], (_Float16)a4[2], (_Float16)a4[3]};
          *(half4*)(outh + (((size_t)b * N + col) << 11) + l0) = h;
        } else {
#pragma unroll
          for (int r = 0; r < 4; ++r) {
            size_t idx = (rowb + r) * (size_t)N + col;
            outh[idx] = (_Float16)a4[r];
          }
        }
      }
    }
  }
}

// --------------------- autocorrelation: register radix-8 FFT ---------------
// (unchanged from R6 — see earlier comments)

#define CBFLY(ch, ia, ib, wr, wi) {                      \
    float ax_ = z[ch][ia].x, ay_ = z[ch][ia].y;          \
    float bx_ = z[ch][ib].x, by_ = z[ch][ib].y;          \
    float dx_ = ax_ - bx_, dy_ = ay_ - by_;              \
    z[ch][ia].x = ax_ + bx_; z[ch][ia].y = ay_ + by_;    \
    z[ch][ib].x = dx_ * (wr) - dy_ * (wi);               \
    z[ch][ib].y = dx_ * (wi) + dy_ * (wr); }
#define BFLY2(ia, ib, m) { float2 w_ = twl[ZP32(m)];     \
    CBFLY(0, ia, ib, w_.x, w_.y) CBFLY(1, ia, ib, w_.x, w_.y) }

__global__ __launch_bounds__(256) void corr_fft_kernel(const _Float16* __restrict__ F,
                                                       float* __restrict__ S) {
  __shared__ float2 Zs[2][2112];   // 2048 + pad every 32
  __shared__ float2 twl[1056];     // 1024 twiddles, padded
  int tid = threadIdx.x;
  int b = blockIdx.x >> 9;
  int c0 = (blockIdx.x & 511) << 1;
  const _Float16* qb = F + ((size_t)(b * 2048 + c0) << 11);
  const _Float16* kb = F + ((size_t)(b * 2048 + 1024 + c0) << 11);

  float2 z[2][8];
#pragma unroll
  for (int j = 0; j < 8; ++j) {
    int p = tid + 256 * j;
    z[0][j] = make_float2((float)qb[p], (float)kb[p]);
    z[1][j] = make_float2((float)qb[2048 + p], (float)kb[2048 + p]);
  }
  for (int m = tid; m < 1024; m += 256) {
    float sn, cs;
    __sincosf(-PI_F * (float)m / 1024.0f, &sn, &cs);
    twl[ZP32(m)] = make_float2(cs, sn);
  }
  __syncthreads();

  BFLY2(0, 4, tid)
  BFLY2(1, 5, tid + 256)
  BFLY2(2, 6, tid + 512)
  BFLY2(3, 7, tid + 768)
  { float2 wA = twl[ZP32(tid << 1)], wB = twl[ZP32((tid + 256) << 1)];
    CBFLY(0, 0, 2, wA.x, wA.y) CBFLY(1, 0, 2, wA.x, wA.y)
    CBFLY(0, 1, 3, wB.x, wB.y) CBFLY(1, 1, 3, wB.x, wB.y)
    CBFLY(0, 4, 6, wA.x, wA.y) CBFLY(1, 4, 6, wA.x, wA.y)
    CBFLY(0, 5, 7, wB.x, wB.y) CBFLY(1, 5, 7, wB.x, wB.y) }
  { float2 wA = twl[ZP32(tid << 2)];
    CBFLY(0, 0, 1, wA.x, wA.y) CBFLY(1, 0, 1, wA.x, wA.y)
    CBFLY(0, 2, 3, wA.x, wA.y) CBFLY(1, 2, 3, wA.x, wA.y)
    CBFLY(0, 4, 5, wA.x, wA.y) CBFLY(1, 4, 5, wA.x, wA.y)
    CBFLY(0, 6, 7, wA.x, wA.y) CBFLY(1, 6, 7, wA.x, wA.y) }

#pragma unroll
  for (int j = 0; j < 8; ++j) {
    int p = tid + 256 * j;
    Zs[0][ZP32(p)] = z[0][j];
    Zs[1][ZP32(p)] = z[1][j];
  }
  __syncthreads();
  int t5 = tid & 31, hi1 = (tid >> 5) << 8;
#pragma unroll
  for (int j = 0; j < 8; ++j) {
    int p = hi1 + t5 + 32 * j;
    z[0][j] = Zs[0][ZP32(p)];
    z[1][j] = Zs[1][ZP32(p)];
  }

  BFLY2(0, 4, t5 << 3)
  BFLY2(1, 5, (t5 + 32) << 3)
  BFLY2(2, 6, (t5 + 64) << 3)
  BFLY2(3, 7, (t5 + 96) << 3)
  { float2 wA = twl[ZP32(t5 << 4)], wB = twl[ZP32((t5 + 32) << 4)];
    CBFLY(0, 0, 2, wA.x, wA.y) CBFLY(1, 0, 2, wA.x, wA.y)
    CBFLY(0, 1, 3, wB.x, wB.y) CBFLY(1, 1, 3, wB.x, wB.y)
    CBFLY(0, 4, 6, wA.x, wA.y) CBFLY(1, 4, 6, wA.x, wA.y)
    CBFLY(0, 5, 7, wB.x, wB.y) CBFLY(1, 5, 7, wB.x, wB.y) }
  { float2 wA = twl[ZP32(t5 << 5)];
    CBFLY(0, 0, 1, wA.x, wA.y) CBFLY(1, 0, 1, wA.x, wA.y)
    CBFLY(0, 2, 3, wA.x, wA.y) CBFLY(1, 2, 3, wA.x, wA.y)
    CBFLY(0, 4, 5, wA.x, wA.y) CBFLY(1, 4, 5, wA.x, wA.y)
    CBFLY(0, 6, 7, wA.x, wA.y) CBFLY(1, 6, 7, wA.x, wA.y) }

#pragma unroll
  for (int j = 0; j < 8; ++j) {
    int p = hi1 + t5 + 32 * j;
    Zs[0][ZP32(p)] = z[0][j];
    Zs[1][ZP32(p)] = z[1][j];
  }
  __syncthreads();
  int t3 = tid & 3, hi2 = (tid >> 2) << 5;
#pragma unroll
  for (int j = 0; j < 8; ++j) {
    int p = hi2 + t3 + 4 * j;
    z[0][j] = Zs[0][ZP32(p)];
    z[1][j] = Zs[1][ZP32(p)];
  }

  BFLY2(0, 4, t3 << 6)
  BFLY2(1, 5, (t3 + 4) << 6)
  BFLY2(2, 6, (t3 + 8) << 6)
  BFLY2(3, 7, (t3 + 12) << 6)
  { float2 wA = twl[ZP32(t3 << 7)], wB = twl[ZP32((t3 + 4) << 7)];
    CBFLY(0, 0, 2, wA.x, wA.y) CBFLY(1, 0, 2, wA.x, wA.y)
    CBFLY(0, 1, 3, wB.x, wB.y) CBFLY(1, 1, 3, wB.x, wB.y)
    CBFLY(0, 4, 6, wA.x, wA.y) CBFLY(1, 4, 6, wA.x, wA.y)
    CBFLY(0, 5, 7, wB.x, wB.y) CBFLY(1, 5, 7, wB.x, wB.y) }
  { float2 wA = twl[ZP32(t3 << 8)];
    CBFLY(0, 0, 1, wA.x, wA.y) CBFLY(1, 0, 1, wA.x, wA.y)
    CBFLY(0, 2, 3, wA.x, wA.y) CBFLY(1, 2, 3, wA.x, wA.y)
    CBFLY(0, 4, 5, wA.x, wA.y) CBFLY(1, 4, 5, wA.x, wA.y)
    CBFLY(0, 6, 7, wA.x, wA.y) CBFLY(1, 6, 7, wA.x, wA.y) }

#pragma unroll
  for (int j = 0; j < 8; ++j) {
    int p = hi2 + t3 + 4 * j;
    Zs[0][ZP32(p)] = z[0][j];
    Zs[1][ZP32(p)] = z[1][j];
  }
  __syncthreads();
#pragma unroll
  for (int j = 0; j < 8; ++j) {
    int p = (tid << 3) + j;
    z[0][j] = Zs[0][ZP32(p)];
    z[1][j] = Zs[1][ZP32(p)];
  }

  CBFLY(0, 0, 2, 1.0f, 0.0f) CBFLY(1, 0, 2, 1.0f, 0.0f)
  CBFLY(0, 1, 3, 0.0f, -1.0f) CBFLY(1, 1, 3, 0.0f, -1.0f)
  CBFLY(0, 4, 6, 1.0f, 0.0f) CBFLY(1, 4, 6, 1.0f, 0.0f)
  CBFLY(0, 5, 7, 0.0f, -1.0f) CBFLY(1, 5, 7, 0.0f, -1.0f)
  CBFLY(0, 0, 1, 1.0f, 0.0f) CBFLY(1, 0, 1, 1.0f, 0.0f)
  CBFLY(0, 2, 3, 1.0f, 0.0f) CBFLY(1, 2, 3, 1.0f, 0.0f)
  CBFLY(0, 4, 5, 1.0f, 0.0f) CBFLY(1, 4, 5, 1.0f, 0.0f)
  CBFLY(0, 6, 7, 1.0f, 0.0f) CBFLY(1, 6, 7, 1.0f, 0.0f)

#pragma unroll
  for (int j = 0; j < 8; ++j) {
    int p = (tid << 3) + j;
    Zs[0][ZP32(p)] = z[0][j];
    Zs[1][ZP32(p)] = z[1][j];
  }
  __syncthreads();
  float* Sb = S + (size_t)blockIdx.x * 2050;  // row = b*512 + channel-group
  for (int f = tid; f <= 1024; f += 256) {
    int rf = __brev((unsigned)f) >> 21;
    int rmf = __brev((unsigned)((2048 - f) & 2047)) >> 21;
    float pr = 0.f, pim = 0.f;
#pragma unroll
    for (int ch = 0; ch < 2; ++ch) {
      float2 zf = Zs[ch][ZP32(rf)], zm = Zs[ch][ZP32(rmf)];
      float Qr = 0.5f * (zf.x + zm.x), Qi = 0.5f * (zf.y - zm.y);
      float Kr = 0.5f * (zf.y + zm.y), Ki = -0.5f * (zf.x - zm.x);
      pr += Qr * Kr + Qi * Ki;
      pim += Qi * Kr - Qr * Ki;
    }
    Sb[2 * f] = pr;
    Sb[2 * f + 1] = pim;
  }
}

// ------------- reduce 512 partial spectrum rows -> 8-way S8 format ---------
__global__ __launch_bounds__(256) void spec_reduce_kernel(const float* __restrict__ Sbig,
                                                          float* __restrict__ S8) {
  int f = blockIdx.x * 256 + threadIdx.x;  // 0..2303, guard
  int sc = blockIdx.y;                     // 0..7 (64-row chunk)
  int b = blockIdx.z;                      // 0..7
  if (f >= 2050) return;
  const float* src = Sbig + ((size_t)b * 512 + (size_t)sc * 64) * 2050 + f;
  float s = 0.f;
  for (int i = 0; i < 64; ++i) s += src[(size_t)i * 2050];
  S8[((size_t)b * 8 + sc) * 2050 + f] = s;
}

// --------------- per-batch: inverse FFT -> mean_corr -> top-7 + softmax ----
__global__ __launch_bounds__(256) void corr_topk_kernel(const float* __restrict__ S,
                                                        int* __restrict__ delays,
                                                        float* __restrict__ alphas,
                                                        int C, int L) {
  __shared__ float2 W[2048];
  __shared__ float mc[2048];
  __shared__ float rv[4];
  __shared__ int ri[4];
  __shared__ float swv[7];
  __shared__ int sdi[7];
  int b = blockIdx.x, tid = threadIdx.x;
  const float* Sb = S + (size_t)b * 8 * 2050;
  for (int f = tid; f < 2048; f += 256) {
    int ff = f <= 1024 ? f : 2048 - f;
    float re = 0.f, im = 0.f;
    for (int s = 0; s < 8; ++s) {
      re += Sb[s * 2050 + 2 * ff];
      im += Sb[s * 2050 + 2 * ff + 1];
    }
    W[f] = make_float2(re, f <= 1024 ? -im : im);
  }
  __syncthreads();
  for (int sh = 10; sh >= 0; --sh) {
    int s = 1 << sh;
    for (int j = tid; j < 1024; j += 256) {
      int t = j & (s - 1);
      int i0 = ((j >> sh) << (sh + 1)) | t;
      int i1 = i0 + s;
      float2 a = W[i0], bb = W[i1];
      float ang = -PI_F * (float)t / (float)s;
      float sn, cs;
      __sincosf(ang, &sn, &cs);
      float2 d = make_float2(a.x - bb.x, a.y - bb.y);
      W[i0] = make_float2(a.x + bb.x, a.y + bb.y);
      W[i1] = make_float2(d.x * cs - d.y * sn, d.x * sn + d.y * cs);
    }
    __syncthreads();
  }
  float inv = 1.0f / ((float)C * (float)L);
  for (int t = tid; t < 2048; t += 256) mc[t] = W[__brev((unsigned)t) >> 21].x * inv;
  __syncthreads();
  int wv = tid >> 6, lane = tid & 63;
  for (int it = 0; it < 7; ++it) {
    float bvv = -1e30f;
    int bi = 0;
    for (int e = tid * 8; e < tid * 8 + 8; ++e) {
      float v = mc[e];
      if (v > bvv) { bvv = v; bi = e; }
    }
    for (int o = 32; o > 0; o >>= 1) {
      float ov = __shfl_down(bvv, o, 64);
      int oi = __shfl_down(bi, o, 64);
      if (ov > bvv || (ov == bvv && oi < bi)) { bvv = ov; bi = oi; }
    }
    if (lane == 0) { rv[wv] = bvv; ri[wv] = bi; }
    __syncthreads();
    if (tid == 0) {
      float fv = rv[0];
      int fi = ri[0];
      for (int w2 = 1; w2 < 4; ++w2)
        if (rv[w2] > fv || (rv[w2] == fv && ri[w2] < fi)) { fv = rv[w2]; fi = ri[w2]; }
      swv[it] = fv;
      sdi[it] = fi;
      mc[fi] = -1e30f;
    }
    __syncthreads();
  }
  if (tid == 0) {
    float mx = swv[0];
    for (int i = 1; i < 7; ++i) mx = fmaxf(mx, swv[i]);
    float e[7], s = 0.f;
    for (int i = 0; i < 7; ++i) { e[i] = expf(swv[i] - mx); s += e[i]; }
    for (int i = 0; i < 7; ++i) {
      alphas[b * 7 + i] = e[i] / s;
      delays[b * 7 + i] = sdi[i];
    }
  }
}

// ------------------- lag aggregation on xn (commuted past Wv) --------------
__global__ __launch_bounds__(256) void agg_kernel(const _Float16* __restrict__ v,
                                                  const int* __restrict__ delays,
                                                  const float* __restrict__ alphas,
                                                  _Float16* __restrict__ agg,
                                                  int L, int C) {
  int bt = blockIdx.x;
  int b = bt >> 11, t = bt & 2047;
  int tid = threadIdx.x;
  const _Float16* vb = v + (size_t)b * L * C;
  float ax = 0.f, ay = 0.f, az = 0.f, aw = 0.f;
#pragma unroll
  for (int i = 0; i < 7; ++i) {
    int d = delays[b * 7 + i];
    float a = alphas[b * 7 + i];
    int src = t + d;
    if (src >= L) src -= L;
    half4 x = ((const half4*)(vb + (size_t)src * C))[tid];
    ax += a * (float)x.x; ay += a * (float)x.y;
    az += a * (float)x.z; aw += a * (float)x.w;
  }
  half4 h = {(_Float16)ax, (_Float16)ay, (_Float16)az, (_Float16)aw};
  ((half4*)(agg + (size_t)bt * C))[tid] = h;
}

// ------- series decomposition fp16 -> fp16: out = x - movavg25(x) ----------
__global__ __launch_bounds__(256) void decomp_hh_kernel(const _Float16* __restrict__ xin,
                                                        _Float16* __restrict__ xout,
                                                        int L, int C) {
  int c = blockIdx.x * 256 + threadIdx.x;
  int t0 = blockIdx.y * 128;
  int b = blockIdx.z;
  const _Float16* xb = xin + (size_t)b * L * C + c;
  float sum = 0.f;
  for (int j = t0 - 12; j <= t0 + 12; ++j) {
    int jc = j < 0 ? 0 : (j > L - 1 ? L - 1 : j);
    sum += (float)xb[(size_t)jc * C];
  }
  for (int t = t0; t < t0 + 128; ++t) {
    float xv = (float)xb[(size_t)t * C];
    float o = xv - sum * (1.0f / 25.0f);
    xout[((size_t)b * L + t) * C + c] = (_Float16)o;
    int nj = t + 13; if (nj > L - 1) nj = L - 1;
    int oj = t - 12; if (oj < 0) oj = 0;
    sum += (float)xb[(size_t)nj * C] - (float)xb[(size_t)oj * C];
  }
}

// ------- series decomposition fp16 -> fp32: out = x - movavg25(x) ----------
__global__ __launch_bounds__(256) void decomp_h_kernel(const _Float16* __restrict__ xin,
                                                       float* __restrict__ xout,
                                                       int L, int C) {
  int c = blockIdx.x * 256 + threadIdx.x;
  int t0 = blockIdx.y * 128;
  int b = blockIdx.z;
  const _Float16* xb = xin + (size_t)b * L * C + c;
  float sum = 0.f;
  for (int j = t0 - 12; j <= t0 + 12; ++j) {
    int jc = j < 0 ? 0 : (j > L - 1 ? L - 1 : j);
    sum += (float)xb[(size_t)jc * C];
  }
  for (int t = t0; t < t0 + 128; ++t) {
    float xv = (float)xb[(size_t)t * C];
    float o = xv - sum * (1.0f / 25.0f);
    xout[((size_t)b * L + t) * C + c] = o;
    int nj = t + 13; if (nj > L - 1) nj = L - 1;
    int oj = t - 12; if (oj < 0) oj = 0;
    sum += (float)xb[(size_t)nj * C] - (float)xb[(size_t)oj * C];
  }
}

// ------------------------------- launcher ----------------------------------
extern "C" void kernel_launch(void* const* d_in, const int* in_sizes, int n_in,
                              void* d_out, int out_size, void* d_ws, size_t ws_size,
                              hipStream_t stream) {
  const float* x = (const float*)d_in[0];
  const float* Wq = (const float*)d_in[1];
  const float* Wk = (const float*)d_in[2];
  const float* Wv = (const float*)d_in[3];
  const float* Wo = (const float*)d_in[4];
  const float* bo = (const float*)d_in[5];
  const float* lng = (const float*)d_in[6];
  const float* lnb = (const float*)d_in[7];
  const float* W1 = (const float*)d_in[8];
  const float* W2 = (const float*)d_in[9];
  float* out = (float*)d_out;

  const int B = 8, L = 2048, C = 1024, HD = 4096;
  const int M = B * L;  // 16384

  char* ws = (char*)d_ws;
  size_t off = 0;
  auto alloc = [&](size_t bytes) -> void* {
    void* p = ws + off;
    off = (off + bytes + 255) & ~(size_t)255;
    return p;
  };
  // ~150.6 MiB total (under the 152.1 MiB proven previously)
  _Float16* wqkh = (_Float16*)alloc((size_t)2 * C * C * 2); // 4 MB (q rows, then k rows)
  _Float16* wvoh = (_Float16*)alloc((size_t)C * C * 2);     // 2 MB (Wo*Wv)
  _Float16* w1h = (_Float16*)alloc((size_t)HD * C * 2);     // 8 MB
  _Float16* w2h = (_Float16*)alloc((size_t)C * HD * 2);     // 8 MB
  float* S8 = (float*)alloc((size_t)B * 8 * 2050 * 4);      // 512 KB (reduced spectrum)
  int* dl = (int*)alloc(B * 7 * 4);
  float* al = (float*)alloc(B * 7 * 4);
  _Float16* xn = (_Float16*)alloc((size_t)M * C * 2);       // 32 MB; later x2h
  _Float16* qkh = (_Float16*)alloc((size_t)M * 2 * C * 2);  // 64 MB [B,2C,L]; later x1h/hid
  _Float16* vh = (_Float16*)alloc((size_t)4096 * 2050 * 4); // 33.6 MB: Sbig/wvT/woh, aggh, x3h
  (void)ws_size; (void)in_sizes; (void)n_in; (void)out_size;

  _Float16* wvT = vh;                        // setup-only (dead before corr_fft)
  _Float16* woh = vh + (size_t)C * C;        // setup-only (dead before corr_fft)
  float* Sbig = (float*)vh;       // partial spectra (steps 5-6), dead before agg
  _Float16* aggh = vh;            // agg of xn (from step 8)
  _Float16* x1h = qkh;            // attn out fp16 (32 MB); q,k dead after corr_fft
  _Float16* x2h = xn;             // xn dead after agg
  _Float16* hid2 = qkh;           // FFN hidden half (M x 2048 fp16 = 64 MB); x1h dead
  _Float16* x3h = vh;             // FFN output fp16 (32 MB); aggh dead after attn GEMM

  // 1. weights -> fp16 (+ Wv transpose)
  cvt_f16_kernel<<<(C * C / 4 + 255) / 256, 256, 0, stream>>>(Wq, wqkh, C * C / 4);
  cvt_f16_kernel<<<(C * C / 4 + 255) / 256, 256, 0, stream>>>(Wk, wqkh + (size_t)C * C, C * C / 4);
  cvt_f16_kernel<<<(C * C / 4 + 255) / 256, 256, 0, stream>>>(Wo, woh, C * C / 4);
  transpose_f16_kernel<<<dim3(16, 16), 256, 0, stream>>>(Wv, wvT, C);
  cvt_f16_kernel<<<(HD * C / 4 + 255) / 256, 256, 0, stream>>>(W1, w1h, HD * C / 4);
  cvt_f16_kernel<<<(HD * C / 4 + 255) / 256, 256, 0, stream>>>(W2, w2h, HD * C / 4);
  // 2. Wvo[o,c] = sum_j Wo[o,j]*Wv[j,c]
  gemm256_kernel<4><<<16, 512, 0, stream>>>(woh, wvT, C, C, C, C, C,
                                            nullptr, wvoh, nullptr, nullptr, nullptr);
  // 3. LayerNorm -> fp16
  ln_kernel<<<M, 256, 0, stream>>>(x, lng, lnb, xn, C);
  // 4. fused q,k GEMM -> transposed [B, 2C, L]
  gemm256_kernel<5><<<(M / 256) * (2 * C / 256), 512, 0, stream>>>(
      xn, wqkh, M, 2 * C, C, C, C, nullptr, qkh, nullptr, nullptr, nullptr);
  // 5. channel FFTs -> per-block partial spectrum rows (no atomics)
  corr_fft_kernel<<<B * (C / 2), 256, 0, stream>>>(qkh, Sbig);
  // 6. reduce 512 partial rows -> 8-way S8
  spec_reduce_kernel<<<dim3(9, 8, 8), 256, 0, stream>>>(Sbig, S8);
  // 7. inverse FFT + top-7 + softmax
  corr_topk_kernel<<<B, 256, 0, stream>>>(S8, dl, al, C, L);
  // 8. lag aggregation on xn (commuted) -> aggh
  agg_kernel<<<B * L, 256, 0, stream>>>(xn, dl, al, aggh, L, C);
  // 9. attn = aggh * Wvo^T + bo + x -> x1h fp16 (qkh region, staged epilogue)
  gemm256_kernel<9><<<(M / 256) * (C / 256), 512, 0, stream>>>(
      aggh, wvoh, M, C, C, C, C, nullptr, x1h, bo, x, nullptr);
  // 10. decomp1: x2h = x1h - movavg(x1h) (fp16 -> fp16, xn region)
  decomp_hh_kernel<<<dim3(C / 256, L / 128, B), 256, 0, stream>>>(x1h, x2h, L, C);
  // 11. FFN in 2 HD-halves: FFN1 -> hid2 (qkh region), FFN2 -> x3h fp16 (vh)
  //     pass0: x3h = acc + x2h (fp16 res); pass1: x3h += acc (coalesced RMW)
  for (int ci = 0; ci < 2; ++ci) {
    gemm256_kernel<2><<<(M / 256) * (2048 / 256), 512, 0, stream>>>(
        x2h, w1h + (size_t)ci * 2048 * C, M, 2048, C, C, C,
        nullptr, hid2, nullptr, nullptr, nullptr);
    if (ci == 0) {
      gemm256_kernel<8><<<(M / 256) * (C / 256), 512, 0, stream>>>(
          hid2, w2h, M, C, 2048, 2048, HD, nullptr, x3h, nullptr, nullptr, x2h);
    } else {
      gemm256_kernel<7><<<(M / 256) * (C / 256), 512, 0, stream>>>(
          hid2, w2h + 2048, M, C, 2048, 2048, HD, nullptr, x3h, nullptr, nullptr, nullptr);
    }
  }
  // 12. decomp2 (fp16 input) -> out
  decomp_h_kernel<<<dim3(C / 256, L / 128, B), 256, 0, stream>>>(x3h, out, L, C);
}

// Round 8
// 789.479 us; speedup vs baseline: 1.2241x; 1.0034x over previous
//
#include <hip/hip_runtime.h>
#include <cstdint>
#include <cstddef>

// ---------------------------------------------------------------------------
// AutoformerEncodeBlock R13:
//  - EPI=5 (qk transposed) now LDS-staged: col-major tile in LDS (XOR swizzle
//    erow^((ecol&7)<<3)), readback along l -> 512B contiguous global stores
//    (was 32 scalar half4 at 4KB stride).
//  - Row-major staged epilogues (EPI 2/8/9): ecol ^ (q4<<4) swizzle -> 64
//    lanes cover all 32 banks (was 8-way, 1.05e6 conflicts measured R12).
//  - FFN2 single pass: K=4096 with dual-A (hidA=qkh, hidB=d_out); x3h RMW
//    pass eliminated (-64MB traffic, -1 dispatch).
//  - Wvo fold K-split: grid 64 (16 tiles x 4 K-slices), fp32 partials +
//    combine kernel (was grid 16 = 94% of CUs idle).
//  - GEMM K-loop: R8 dual-barrier phase skeleton (structural plateau).
// ---------------------------------------------------------------------------

typedef _Float16 half8 __attribute__((ext_vector_type(8)));
typedef _Float16 half4 __attribute__((ext_vector_type(4)));
typedef float floatx4 __attribute__((ext_vector_type(4)));

#define PI_F 3.14159265358979323846f
#define ZP32(i) ((i) + ((i) >> 5))  // pad every 32 float2 elements

__device__ __forceinline__ void load_lds16(const void* g, void* l) {
  __builtin_amdgcn_global_load_lds((__attribute__((address_space(1))) void*)g,
                                   (__attribute__((address_space(3))) void*)l,
                                   16, 0, 0);
}

// exact-GELU via A&S 7.1.26 erf approximation (max abs err ~1.5e-7 on erf)
__device__ __forceinline__ float fast_gelu(float v) {
  float u = v * 0.70710678118654752f;
  float au = fabsf(u);
  float t = __builtin_amdgcn_rcpf(1.0f + 0.3275911f * au);
  float poly = t * (0.254829592f +
               t * (-0.284496736f +
               t * (1.421413741f +
               t * (-1.453152027f +
               t * 1.061405429f))));
  float e = __expf(-u * u);
  float erf_abs = 1.0f - poly * e;
  float erfv = copysignf(erf_abs, u);
  return 0.5f * v * (1.0f + erfv);
}

// ---------------------------- small utility kernels ------------------------

__global__ __launch_bounds__(256) void cvt_f16_kernel(const float* __restrict__ src,
                                                      _Float16* __restrict__ dst, int n4) {
  int i = blockIdx.x * 256 + threadIdx.x;
  if (i >= n4) return;
  float4 v = ((const float4*)src)[i];
  half4 h = {(_Float16)v.x, (_Float16)v.y, (_Float16)v.z, (_Float16)v.w};
  ((half4*)dst)[i] = h;
}

// dst[c, j] = src[j, c]  (n x n, fp32 -> fp16), 64x64 LDS tiles
__global__ __launch_bounds__(256) void transpose_f16_kernel(const float* __restrict__ src,
                                                            _Float16* __restrict__ dst, int n) {
  __shared__ float tile[64][65];
  int j0 = blockIdx.y * 64, c0 = blockIdx.x * 64;
  int tr = threadIdx.x >> 4;
  int tc = threadIdx.x & 15;
#pragma unroll
  for (int rr = 0; rr < 64; rr += 16) {
    float4 v = *(const float4*)(src + (size_t)(j0 + tr + rr) * n + c0 + tc * 4);
    tile[tr + rr][tc * 4 + 0] = v.x;
    tile[tr + rr][tc * 4 + 1] = v.y;
    tile[tr + rr][tc * 4 + 2] = v.z;
    tile[tr + rr][tc * 4 + 3] = v.w;
  }
  __syncthreads();
#pragma unroll
  for (int rr = 0; rr < 64; rr += 16) {
    int c = tr + rr;
    half4 h = {(_Float16)tile[tc * 4 + 0][c], (_Float16)tile[tc * 4 + 1][c],
               (_Float16)tile[tc * 4 + 2][c], (_Float16)tile[tc * 4 + 3][c]};
    *(half4*)(dst + (size_t)(c0 + c) * n + j0 + tc * 4) = h;
  }
}

// combine 4 fp32 K-slice partials of Wvo -> fp16 (n4 = C*C/4)
__global__ __launch_bounds__(256) void wvo_combine_kernel(const float* __restrict__ p,
                                                          _Float16* __restrict__ w, int n4) {
  int i = blockIdx.x * 256 + threadIdx.x;
  if (i >= n4) return;
  const size_t S = (size_t)1024 * 1024;
  float4 a = ((const float4*)p)[i];
  float4 b = ((const float4*)(p + S))[i];
  float4 c = ((const float4*)(p + 2 * S))[i];
  float4 d = ((const float4*)(p + 3 * S))[i];
  half4 h = {(_Float16)(a.x + b.x + c.x + d.x), (_Float16)(a.y + b.y + c.y + d.y),
             (_Float16)(a.z + b.z + c.z + d.z), (_Float16)(a.w + b.w + c.w + d.w)};
  ((half4*)w)[i] = h;
}

// --------------------------------- LayerNorm -------------------------------
__global__ __launch_bounds__(256) void ln_kernel(const float* __restrict__ x,
                                                 const float* __restrict__ g,
                                                 const float* __restrict__ b,
                                                 _Float16* __restrict__ xn, int C) {
  int row = blockIdx.x;
  int t = threadIdx.x;
  const float4* xr = (const float4*)(x + (size_t)row * C);
  float4 v = xr[t];
  float s = v.x + v.y + v.z + v.w;
  float s2 = v.x * v.x + v.y * v.y + v.z * v.z + v.w * v.w;
  for (int o = 32; o > 0; o >>= 1) {
    s += __shfl_down(s, o, 64);
    s2 += __shfl_down(s2, o, 64);
  }
  __shared__ float red[8];
  int wave = t >> 6, lane = t & 63;
  if (lane == 0) { red[wave] = s; red[4 + wave] = s2; }
  __syncthreads();
  __shared__ float stats[2];
  if (t == 0) {
    float ts = red[0] + red[1] + red[2] + red[3];
    float ts2 = red[4] + red[5] + red[6] + red[7];
    float mu = ts / (float)C;
    float var = ts2 / (float)C - mu * mu;
    stats[0] = mu;
    stats[1] = 1.0f / sqrtf(var + 1e-5f);
  }
  __syncthreads();
  float mu = stats[0], rs = stats[1];
  float4 gv = ((const float4*)g)[t];
  float4 bv = ((const float4*)b)[t];
  half4 h = {(_Float16)((v.x - mu) * rs * gv.x + bv.x),
             (_Float16)((v.y - mu) * rs * gv.y + bv.y),
             (_Float16)((v.z - mu) * rs * gv.z + bv.z),
             (_Float16)((v.w - mu) * rs * gv.w + bv.w)};
  ((half4*)(xn + (size_t)row * C))[t] = h;
}

// ----------------------------------- GEMM ----------------------------------
// C[M,N] = A[M,K] * Bw[N,K]^T (fp16). 256x256 tile, BK=64, 8 waves (2x4),
// per-wave 128x64 output (acc[8][4]). R8 dual-barrier phase skeleton with
// counted vmcnt. XOR-granule swizzle on K-loop LDS (0 bank conflicts).
// EPI: 2 = fast GELU -> fp16 (staged row-major),
//      5 = fp16 transposed [B, N, L] (L=2048; staged col-major),
//      8 = fp16 out = acc + resh fp16 (staged; supports dual-A via Ah2),
//      9 = fp16 out = acc + bias + res fp32 (staged),
//      10 = fp32 K-slice partials (grid 64: 16 tiles x 4 slices of K=256)
template <int EPI>
__global__ __launch_bounds__(512, 2) void gemm256_kernel(
    const _Float16* __restrict__ A, const _Float16* __restrict__ Bw,
    int M, int N, int K, int lda, int ldb,
    float* __restrict__ outf, _Float16* __restrict__ outh,
    const float* __restrict__ bias, const float* __restrict__ res,
    const _Float16* __restrict__ resh, const _Float16* __restrict__ Ah2) {
  __shared__ _Float16 lds[2][2][256 * 64];  // [buf][A=0/B=1][256 rows x 64 halfs]

  int tid = threadIdx.x;
  int lane = tid & 63;
  int wave = tid >> 6;          // 0..7
  int wm = wave >> 2;           // 0..1  (M half)
  int wn = wave & 3;            // 0..3  (N quarter)
  int ln15 = lane & 15, q4 = lane >> 4;
  int l3 = lane >> 3, l7 = lane & 7;

  int nwg = gridDim.x, orig = blockIdx.x;
  int wg, kslice = 0;
  if (EPI == 10) {
    kslice = orig >> 4;
    wg = orig & 15;
  } else {
    wg = ((nwg & 7) == 0) ? ((orig & 7) * (nwg >> 3) + (orig >> 3)) : orig;
  }
  int nbn = N >> 8;
  size_t m0 = (size_t)(wg / nbn) << 8;
  size_t n0 = (size_t)(wg % nbn) << 8;

  // swizzled ds_read granule offsets (halfs)
  int sg0 = (q4 ^ l7) << 3;         // kk=0
  int sg1 = ((q4 + 4) ^ l7) << 3;   // kk=32

  floatx4 acc[8][4] = {};

  // staging: lane covers row (8*wave + l3) of each 64-row chunk, global
  // granule pre-swizzled to l7^l3 so linear LDS dest == swizzled layout.
  size_t swzoff = (size_t)((l7 ^ l3) * 8);
  const _Float16* srcA = A + (m0 + 8 * wave + l3) * (size_t)lda + swzoff;
  const _Float16* srcB = Bw + (n0 + 8 * wave + l3) * (size_t)ldb + swzoff;
  const _Float16* srcA2 = (Ah2 ? Ah2 : A) + (m0 + 8 * wave + l3) * (size_t)lda + swzoff;
  if (EPI == 10) {
    srcA += (size_t)kslice * 256;
    srcB += (size_t)kslice * 256;
  }
  char* ldsA0 = (char*)&lds[0][0][0] + wave * 1024;
  char* ldsB0 = (char*)&lds[0][1][0] + wave * 1024;

  int nk = (EPI == 10) ? 4 : (K >> 6);
  int nswitch = Ah2 ? (nk >> 1) : nk;  // tiles >= nswitch read from Ah2

  // prologue: stage tile 0 (order B0,B1,B2,B3,A0,A2,A1,A3) into buf 0
  load_lds16(srcB, ldsB0);
  load_lds16(srcB + (size_t)64 * ldb, ldsB0 + 1 * 8192);
  load_lds16(srcB + (size_t)128 * ldb, ldsB0 + 2 * 8192);
  load_lds16(srcB + (size_t)192 * ldb, ldsB0 + 3 * 8192);
  load_lds16(srcA, ldsA0);
  load_lds16(srcA + (size_t)128 * lda, ldsA0 + 2 * 8192);
  load_lds16(srcA + (size_t)64 * lda, ldsA0 + 1 * 8192);
  load_lds16(srcA + (size_t)192 * lda, ldsA0 + 3 * 8192);
  // guard tile-0 reads (A1,A3 may stay outstanding)
  asm volatile("s_waitcnt vmcnt(2)" ::: "memory");
  __builtin_amdgcn_s_barrier();
  __builtin_amdgcn_sched_barrier(0);

  half8 bf[4][2], aA[2][2];

#define RD_B() _Pragma("unroll") for (int ni = 0; ni < 4; ++ni) {      \
    const _Float16* p_ = cB + ((wn * 64 + ni * 16 + ln15) << 6);       \
    bf[ni][0] = *(const half8*)(p_ + sg0);                             \
    bf[ni][1] = *(const half8*)(p_ + sg1); }
#define RD_A(mi) { const _Float16* p_ = cA + ((wm * 128 + (mi) * 16 + ln15) << 6); \
    aA[(mi) & 1][0] = *(const half8*)(p_ + sg0);                                   \
    aA[(mi) & 1][1] = *(const half8*)(p_ + sg1); }
#define MM(mi) _Pragma("unroll") for (int ni = 0; ni < 4; ++ni) {      \
    acc[mi][ni] = __builtin_amdgcn_mfma_f32_16x16x32_f16(aA[(mi) & 1][0], bf[ni][0], acc[mi][ni], 0, 0, 0); \
    acc[mi][ni] = __builtin_amdgcn_mfma_f32_16x16x32_f16(aA[(mi) & 1][1], bf[ni][1], acc[mi][ni], 0, 0, 0); }

#define PH_MID()                                            \
    __builtin_amdgcn_s_barrier();                           \
    asm volatile("s_waitcnt lgkmcnt(0)" ::: "memory");      \
    __builtin_amdgcn_sched_barrier(0);                      \
    __builtin_amdgcn_s_setprio(1);
#define PH_END()                                            \
    __builtin_amdgcn_s_setprio(0);                          \
    __builtin_amdgcn_s_barrier();                           \
    __builtin_amdgcn_sched_barrier(0);

  for (int t = 0; t < nk; ++t) {
    int cur = t & 1;
    const _Float16* cA = &lds[cur][0][0];
    const _Float16* cB = &lds[cur][1][0];
    int tt = t + 1;
    const _Float16* As;
    if (Ah2 != nullptr && tt >= nswitch) As = srcA2 + (size_t)(tt - nswitch) * 64;
    else As = srcA + (size_t)tt * 64;
    const _Float16* Bs = srcB + (size_t)tt * 64;
    char* stA = ldsA0 + (cur ^ 1) * 65536;
    char* stB = ldsB0 + (cur ^ 1) * 65536;
    bool pf = (tt < nk);

    // ---- phase 0: MFMA mi=0,1 ----
    RD_B();
    RD_A(0); RD_A(1);
    if (pf) {
      load_lds16(Bs, stB);
      load_lds16(Bs + (size_t)64 * ldb, stB + 1 * 8192);
      load_lds16(Bs + (size_t)128 * ldb, stB + 2 * 8192);
    }
    PH_MID();
    MM(0); MM(1);
    PH_END();
    // ---- phase 1: MFMA mi=2,3; end-wait guards this tile's A1,A3 ----
    RD_A(2); RD_A(3);
    if (pf) {
      load_lds16(Bs + (size_t)192 * ldb, stB + 3 * 8192);
      load_lds16(As, stA);
      load_lds16(As + (size_t)128 * lda, stA + 2 * 8192);
    }
    PH_MID();
    MM(2); MM(3);
    __builtin_amdgcn_s_setprio(0);
    if (pf) {
      asm volatile("s_waitcnt vmcnt(6)" ::: "memory");
    } else {
      asm volatile("s_waitcnt vmcnt(0)" ::: "memory");
    }
    __builtin_amdgcn_s_barrier();
    __builtin_amdgcn_sched_barrier(0);
    // ---- phase 2: MFMA mi=4,5 ----
    RD_A(4); RD_A(5);
    if (pf) {
      load_lds16(As + (size_t)64 * lda, stA + 1 * 8192);
    }
    PH_MID();
    MM(4); MM(5);
    PH_END();
    // ---- phase 3: MFMA mi=6,7; end-wait guards next tile's B*,A0,A2 ----
    RD_A(6); RD_A(7);
    if (pf) {
      load_lds16(As + (size_t)192 * lda, stA + 3 * 8192);
    }
    PH_MID();
    MM(6); MM(7);
    __builtin_amdgcn_s_setprio(0);
    asm volatile("s_waitcnt vmcnt(2)" ::: "memory");
    __builtin_amdgcn_s_barrier();
    __builtin_amdgcn_sched_barrier(0);
  }
#undef RD_B
#undef RD_A
#undef MM
#undef PH_MID
#undef PH_END

  if (EPI == 2 || EPI == 8 || EPI == 9) {
    // ---- LDS-staged row-major epilogue; ecol ^ (q4<<4) -> conflict-free ---
    _Float16* eb = (_Float16*)&lds[0][0][0];  // 256 x 256 fp16 = 128 KiB
    int xq = q4 << 4;  // ((erow>>2)&3)<<4 == q4<<4 (erow = ..+q4*4+r, r<4)
#pragma unroll
    for (int mi = 0; mi < 8; ++mi) {
#pragma unroll
      for (int ni = 0; ni < 4; ++ni) {
        floatx4 a4 = acc[mi][ni];
        int erow = wm * 128 + mi * 16 + q4 * 4;
        int ecolX = (wn * 64 + ni * 16 + ln15) ^ xq;
#pragma unroll
        for (int r = 0; r < 4; ++r) {
          float v = a4[r];
          if (EPI == 2) v = fast_gelu(v);
          eb[(size_t)(erow + r) * 256 + ecolX] = (_Float16)v;
        }
      }
    }
    __syncthreads();
    int baser = (tid >> 6) * 32 + (((tid & 63) >> 5) << 4);
    int ecol2 = (tid & 31) << 3;
    float4 bv0, bv1;
    if (EPI == 9) {
      bv0 = *(const float4*)(bias + n0 + ecol2);
      bv1 = *(const float4*)(bias + n0 + ecol2 + 4);
    }
#pragma unroll
    for (int jr = 0; jr < 16; ++jr) {
      int row = baser + jr;
      int xr = ((row >> 2) & 3) << 4;
      half8 hv = *(const half8*)(eb + (size_t)row * 256 + (ecol2 ^ xr));
      size_t gidx = (m0 + row) * (size_t)N + n0 + ecol2;
      if (EPI == 8) {
        half8 pv = *(const half8*)(resh + gidx);
#pragma unroll
        for (int k = 0; k < 8; ++k) hv[k] = (_Float16)((float)hv[k] + (float)pv[k]);
      } else if (EPI == 9) {
        float4 rv0 = *(const float4*)(res + gidx);
        float4 rv1 = *(const float4*)(res + gidx + 4);
        hv[0] = (_Float16)((float)hv[0] + bv0.x + rv0.x);
        hv[1] = (_Float16)((float)hv[1] + bv0.y + rv0.y);
        hv[2] = (_Float16)((float)hv[2] + bv0.z + rv0.z);
        hv[3] = (_Float16)((float)hv[3] + bv0.w + rv0.w);
        hv[4] = (_Float16)((float)hv[4] + bv1.x + rv1.x);
        hv[5] = (_Float16)((float)hv[5] + bv1.y + rv1.y);
        hv[6] = (_Float16)((float)hv[6] + bv1.z + rv1.z);
        hv[7] = (_Float16)((float)hv[7] + bv1.w + rv1.w);
      }
      *(half8*)(outh + gidx) = hv;
    }
  } else if (EPI == 5) {
    // ---- LDS-staged transposed epilogue: col-major tile, swizzled --------
    _Float16* eb = (_Float16*)&lds[0][0][0];  // [col][row] 256x256 fp16
#pragma unroll
    for (int mi = 0; mi < 8; ++mi) {
#pragma unroll
      for (int ni = 0; ni < 4; ++ni) {
        floatx4 a4 = acc[mi][ni];
        int erow = wm * 128 + mi * 16 + q4 * 4;
        int ecol = wn * 64 + ni * 16 + ln15;
        int xc = (ecol & 7) << 3;
#pragma unroll
        for (int r = 0; r < 4; ++r)
          eb[(size_t)ecol * 256 + ((erow + r) ^ xc)] = (_Float16)a4[r];
      }
    }
    __syncthreads();
    size_t bidx = m0 >> 11, l0 = m0 & 2047;
    int cbase = (tid >> 5) * 16;
    int l8 = (tid & 31) << 3;
#pragma unroll
    for (int jr = 0; jr < 16; ++jr) {
      int col = cbase + jr;
      int xc = (col & 7) << 3;
      half8 hv = *(const half8*)(eb + (size_t)col * 256 + (l8 ^ xc));
      *(half8*)(outh + ((bidx * N + n0 + col) << 11) + l0 + l8) = hv;
    }
  } else {
    // ---- EPI 10: fp32 K-slice partial (scalar; tiny grid) ----------------
#pragma unroll
    for (int mi = 0; mi < 8; ++mi) {
#pragma unroll
      for (int ni = 0; ni < 4; ++ni) {
        floatx4 a4 = acc[mi][ni];
        size_t rowb = m0 + wm * 128 + mi * 16 + q4 * 4;
        size_t col = n0 + wn * 64 + ni * 16 + ln15;
        float* po = outf + (size_t)kslice * M * N;
#pragma unroll
        for (int r = 0; r < 4; ++r)
          po[(rowb + r) * (size_t)N + col] = a4[r];
      }
    }
  }
}

// --------------------- autocorrelation: register radix-8 FFT ---------------
// (unchanged from R6 — see earlier comments)

#define CBFLY(ch, ia, ib, wr, wi) {                      \
    float ax_ = z[ch][ia].x, ay_ = z[ch][ia].y;          \
    float bx_ = z[ch][ib].x, by_ = z[ch][ib].y;          \
    float dx_ = ax_ - bx_, dy_ = ay_ - by_;              \
    z[ch][ia].x = ax_ + bx_; z[ch][ia].y = ay_ + by_;    \
    z[ch][ib].x = dx_ * (wr) - dy_ * (wi);               \
    z[ch][ib].y = dx_ * (wi) + dy_ * (wr); }
#define BFLY2(ia, ib, m) { float2 w_ = twl[ZP32(m)];     \
    CBFLY(0, ia, ib, w_.x, w_.y) CBFLY(1, ia, ib, w_.x, w_.y) }

__global__ __launch_bounds__(256) void corr_fft_kernel(const _Float16* __restrict__ F,
                                                       float* __restrict__ S) {
  __shared__ float2 Zs[2][2112];   // 2048 + pad every 32
  __shared__ float2 twl[1056];     // 1024 twiddles, padded
  int tid = threadIdx.x;
  int b = blockIdx.x >> 9;
  int c0 = (blockIdx.x & 511) << 1;
  const _Float16* qb = F + ((size_t)(b * 2048 + c0) << 11);
  const _Float16* kb = F + ((size_t)(b * 2048 + 1024 + c0) << 11);

  float2 z[2][8];
#pragma unroll
  for (int j = 0; j < 8; ++j) {
    int p = tid + 256 * j;
    z[0][j] = make_float2((float)qb[p], (float)kb[p]);
    z[1][j] = make_float2((float)qb[2048 + p], (float)kb[2048 + p]);
  }
  for (int m = tid; m < 1024; m += 256) {
    float sn, cs;
    __sincosf(-PI_F * (float)m / 1024.0f, &sn, &cs);
    twl[ZP32(m)] = make_float2(cs, sn);
  }
  __syncthreads();

  BFLY2(0, 4, tid)
  BFLY2(1, 5, tid + 256)
  BFLY2(2, 6, tid + 512)
  BFLY2(3, 7, tid + 768)
  { float2 wA = twl[ZP32(tid << 1)], wB = twl[ZP32((tid + 256) << 1)];
    CBFLY(0, 0, 2, wA.x, wA.y) CBFLY(1, 0, 2, wA.x, wA.y)
    CBFLY(0, 1, 3, wB.x, wB.y) CBFLY(1, 1, 3, wB.x, wB.y)
    CBFLY(0, 4, 6, wA.x, wA.y) CBFLY(1, 4, 6, wA.x, wA.y)
    CBFLY(0, 5, 7, wB.x, wB.y) CBFLY(1, 5, 7, wB.x, wB.y) }
  { float2 wA = twl[ZP32(tid << 2)];
    CBFLY(0, 0, 1, wA.x, wA.y) CBFLY(1, 0, 1, wA.x, wA.y)
    CBFLY(0, 2, 3, wA.x, wA.y) CBFLY(1, 2, 3, wA.x, wA.y)
    CBFLY(0, 4, 5, wA.x, wA.y) CBFLY(1, 4, 5, wA.x, wA.y)
    CBFLY(0, 6, 7, wA.x, wA.y) CBFLY(1, 6, 7, wA.x, wA.y) }

#pragma unroll
  for (int j = 0; j < 8; ++j) {
    int p = tid + 256 * j;
    Zs[0][ZP32(p)] = z[0][j];
    Zs[1][ZP32(p)] = z[1][j];
  }
  __syncthreads();
  int t5 = tid & 31, hi1 = (tid >> 5) << 8;
#pragma unroll
  for (int j = 0; j < 8; ++j) {
    int p = hi1 + t5 + 32 * j;
    z[0][j] = Zs[0][ZP32(p)];
    z[1][j] = Zs[1][ZP32(p)];
  }

  BFLY2(0, 4, t5 << 3)
  BFLY2(1, 5, (t5 + 32) << 3)
  BFLY2(2, 6, (t5 + 64) << 3)
  BFLY2(3, 7, (t5 + 96) << 3)
  { float2 wA = twl[ZP32(t5 << 4)], wB = twl[ZP32((t5 + 32) << 4)];
    CBFLY(0, 0, 2, wA.x, wA.y) CBFLY(1, 0, 2, wA.x, wA.y)
    CBFLY(0, 1, 3, wB.x, wB.y) CBFLY(1, 1, 3, wB.x, wB.y)
    CBFLY(0, 4, 6, wA.x, wA.y) CBFLY(1, 4, 6, wA.x, wA.y)
    CBFLY(0, 5, 7, wB.x, wB.y) CBFLY(1, 5, 7, wB.x, wB.y) }
  { float2 wA = twl[ZP32(t5 << 5)];
    CBFLY(0, 0, 1, wA.x, wA.y) CBFLY(1, 0, 1, wA.x, wA.y)
    CBFLY(0, 2, 3, wA.x, wA.y) CBFLY(1, 2, 3, wA.x, wA.y)
    CBFLY(0, 4, 5, wA.x, wA.y) CBFLY(1, 4, 5, wA.x, wA.y)
    CBFLY(0, 6, 7, wA.x, wA.y) CBFLY(1, 6, 7, wA.x, wA.y) }

#pragma unroll
  for (int j = 0; j < 8; ++j) {
    int p = hi1 + t5 + 32 * j;
    Zs[0][ZP32(p)] = z[0][j];
    Zs[1][ZP32(p)] = z[1][j];
  }
  __syncthreads();
  int t3 = tid & 3, hi2 = (tid >> 2) << 5;
#pragma unroll
  for (int j = 0; j < 8; ++j) {
    int p = hi2 + t3 + 4 * j;
    z[0][j] = Zs[0][ZP32(p)];
    z[1][j] = Zs[1][ZP32(p)];
  }

  BFLY2(0, 4, t3 << 6)
  BFLY2(1, 5, (t3 + 4) << 6)
  BFLY2(2, 6, (t3 + 8) << 6)
  BFLY2(3, 7, (t3 + 12) << 6)
  { float2 wA = twl[ZP32(t3 << 7)], wB = twl[ZP32((t3 + 4) << 7)];
    CBFLY(0, 0, 2, wA.x, wA.y) CBFLY(1, 0, 2, wA.x, wA.y)
    CBFLY(0, 1, 3, wB.x, wB.y) CBFLY(1, 1, 3, wB.x, wB.y)
    CBFLY(0, 4, 6, wA.x, wA.y) CBFLY(1, 4, 6, wA.x, wA.y)
    CBFLY(0, 5, 7, wB.x, wB.y) CBFLY(1, 5, 7, wB.x, wB.y) }
  { float2 wA = twl[ZP32(t3 << 8)];
    CBFLY(0, 0, 1, wA.x, wA.y) CBFLY(1, 0, 1, wA.x, wA.y)
    CBFLY(0, 2, 3, wA.x, wA.y) CBFLY(1, 2, 3, wA.x, wA.y)
    CBFLY(0, 4, 5, wA.x, wA.y) CBFLY(1, 4, 5, wA.x, wA.y)
    CBFLY(0, 6, 7, wA.x, wA.y) CBFLY(1, 6, 7, wA.x, wA.y) }

#pragma unroll
  for (int j = 0; j < 8; ++j) {
    int p = hi2 + t3 + 4 * j;
    Zs[0][ZP32(p)] = z[0][j];
    Zs[1][ZP32(p)] = z[1][j];
  }
  __syncthreads();
#pragma unroll
  for (int j = 0; j < 8; ++j) {
    int p = (tid << 3) + j;
    z[0][j] = Zs[0][ZP32(p)];
    z[1][j] = Zs[1][ZP32(p)];
  }

  CBFLY(0, 0, 2, 1.0f, 0.0f) CBFLY(1, 0, 2, 1.0f, 0.0f)
  CBFLY(0, 1, 3, 0.0f, -1.0f) CBFLY(1, 1, 3, 0.0f, -1.0f)
  CBFLY(0, 4, 6, 1.0f, 0.0f) CBFLY(1, 4, 6, 1.0f, 0.0f)
  CBFLY(0, 5, 7, 0.0f, -1.0f) CBFLY(1, 5, 7, 0.0f, -1.0f)
  CBFLY(0, 0, 1, 1.0f, 0.0f) CBFLY(1, 0, 1, 1.0f, 0.0f)
  CBFLY(0, 2, 3, 1.0f, 0.0f) CBFLY(1, 2, 3, 1.0f, 0.0f)
  CBFLY(0, 4, 5, 1.0f, 0.0f) CBFLY(1, 4, 5, 1.0f, 0.0f)
  CBFLY(0, 6, 7, 1.0f, 0.0f) CBFLY(1, 6, 7, 1.0f, 0.0f)

#pragma unroll
  for (int j = 0; j < 8; ++j) {
    int p = (tid << 3) + j;
    Zs[0][ZP32(p)] = z[0][j];
    Zs[1][ZP32(p)] = z[1][j];
  }
  __syncthreads();
  float* Sb = S + (size_t)blockIdx.x * 2050;  // row = b*512 + channel-group
  for (int f = tid; f <= 1024; f += 256) {
    int rf = __brev((unsigned)f) >> 21;
    int rmf = __brev((unsigned)((2048 - f) & 2047)) >> 21;
    float pr = 0.f, pim = 0.f;
#pragma unroll
    for (int ch = 0; ch < 2; ++ch) {
      float2 zf = Zs[ch][ZP32(rf)], zm = Zs[ch][ZP32(rmf)];
      float Qr = 0.5f * (zf.x + zm.x), Qi = 0.5f * (zf.y - zm.y);
      float Kr = 0.5f * (zf.y + zm.y), Ki = -0.5f * (zf.x - zm.x);
      pr += Qr * Kr + Qi * Ki;
      pim += Qi * Kr - Qr * Ki;
    }
    Sb[2 * f] = pr;
    Sb[2 * f + 1] = pim;
  }
}

// ------------- reduce 512 partial spectrum rows -> 8-way S8 format ---------
__global__ __launch_bounds__(256) void spec_reduce_kernel(const float* __restrict__ Sbig,
                                                          float* __restrict__ S8) {
  int f = blockIdx.x * 256 + threadIdx.x;  // 0..2303, guard
  int sc = blockIdx.y;                     // 0..7 (64-row chunk)
  int b = blockIdx.z;                      // 0..7
  if (f >= 2050) return;
  const float* src = Sbig + ((size_t)b * 512 + (size_t)sc * 64) * 2050 + f;
  float s = 0.f;
  for (int i = 0; i < 64; ++i) s += src[(size_t)i * 2050];
  S8[((size_t)b * 8 + sc) * 2050 + f] = s;
}

// --------------- per-batch: inverse FFT -> mean_corr -> top-7 + softmax ----
__global__ __launch_bounds__(256) void corr_topk_kernel(const float* __restrict__ S,
                                                        int* __restrict__ delays,
                                                        float* __restrict__ alphas,
                                                        int C, int L) {
  __shared__ float2 W[2048];
  __shared__ float mc[2048];
  __shared__ float rv[4];
  __shared__ int ri[4];
  __shared__ float swv[7];
  __shared__ int sdi[7];
  int b = blockIdx.x, tid = threadIdx.x;
  const float* Sb = S + (size_t)b * 8 * 2050;
  for (int f = tid; f < 2048; f += 256) {
    int ff = f <= 1024 ? f : 2048 - f;
    float re = 0.f, im = 0.f;
    for (int s = 0; s < 8; ++s) {
      re += Sb[s * 2050 + 2 * ff];
      im += Sb[s * 2050 + 2 * ff + 1];
    }
    W[f] = make_float2(re, f <= 1024 ? -im : im);
  }
  __syncthreads();
  for (int sh = 10; sh >= 0; --sh) {
    int s = 1 << sh;
    for (int j = tid; j < 1024; j += 256) {
      int t = j & (s - 1);
      int i0 = ((j >> sh) << (sh + 1)) | t;
      int i1 = i0 + s;
      float2 a = W[i0], bb = W[i1];
      float ang = -PI_F * (float)t / (float)s;
      float sn, cs;
      __sincosf(ang, &sn, &cs);
      float2 d = make_float2(a.x - bb.x, a.y - bb.y);
      W[i0] = make_float2(a.x + bb.x, a.y + bb.y);
      W[i1] = make_float2(d.x * cs - d.y * sn, d.x * sn + d.y * cs);
    }
    __syncthreads();
  }
  float inv = 1.0f / ((float)C * (float)L);
  for (int t = tid; t < 2048; t += 256) mc[t] = W[__brev((unsigned)t) >> 21].x * inv;
  __syncthreads();
  int wv = tid >> 6, lane = tid & 63;
  for (int it = 0; it < 7; ++it) {
    float bvv = -1e30f;
    int bi = 0;
    for (int e = tid * 8; e < tid * 8 + 8; ++e) {
      float v = mc[e];
      if (v > bvv) { bvv = v; bi = e; }
    }
    for (int o = 32; o > 0; o >>= 1) {
      float ov = __shfl_down(bvv, o, 64);
      int oi = __shfl_down(bi, o, 64);
      if (ov > bvv || (ov == bvv && oi < bi)) { bvv = ov; bi = oi; }
    }
    if (lane == 0) { rv[wv] = bvv; ri[wv] = bi; }
    __syncthreads();
    if (tid == 0) {
      float fv = rv[0];
      int fi = ri[0];
      for (int w2 = 1; w2 < 4; ++w2)
        if (rv[w2] > fv || (rv[w2] == fv && ri[w2] < fi)) { fv = rv[w2]; fi = ri[w2]; }
      swv[it] = fv;
      sdi[it] = fi;
      mc[fi] = -1e30f;
    }
    __syncthreads();
  }
  if (tid == 0) {
    float mx = swv[0];
    for (int i = 1; i < 7; ++i) mx = fmaxf(mx, swv[i]);
    float e[7], s = 0.f;
    for (int i = 0; i < 7; ++i) { e[i] = expf(swv[i] - mx); s += e[i]; }
    for (int i = 0; i < 7; ++i) {
      alphas[b * 7 + i] = e[i] / s;
      delays[b * 7 + i] = sdi[i];
    }
  }
}

// ------------------- lag aggregation on xn (commuted past Wv) --------------
__global__ __launch_bounds__(256) void agg_kernel(const _Float16* __restrict__ v,
                                                  const int* __restrict__ delays,
                                                  const float* __restrict__ alphas,
                                                  _Float16* __restrict__ agg,
                                                  int L, int C) {
  int bt = blockIdx.x;
  int b = bt >> 11, t = bt & 2047;
  int tid = threadIdx.x;
  const _Float16* vb = v + (size_t)b * L * C;
  float ax = 0.f, ay = 0.f, az = 0.f, aw = 0.f;
#pragma unroll
  for (int i = 0; i < 7; ++i) {
    int d = delays[b * 7 + i];
    float a = alphas[b * 7 + i];
    int src = t + d;
    if (src >= L) src -= L;
    half4 x = ((const half4*)(vb + (size_t)src * C))[tid];
    ax += a * (float)x.x; ay += a * (float)x.y;
    az += a * (float)x.z; aw += a * (float)x.w;
  }
  half4 h = {(_Float16)ax, (_Float16)ay, (_Float16)az, (_Float16)aw};
  ((half4*)(agg + (size_t)bt * C))[tid] = h;
}

// ------- series decomposition fp16 -> fp16: out = x - movavg25(x) ----------
__global__ __launch_bounds__(256) void decomp_hh_kernel(const _Float16* __restrict__ xin,
                                                        _Float16* __restrict__ xout,
                                                        int L, int C) {
  int c = blockIdx.x * 256 + threadIdx.x;
  int t0 = blockIdx.y * 128;
  int b = blockIdx.z;
  const _Float16* xb = xin + (size_t)b * L * C + c;
  float sum = 0.f;
  for (int j = t0 - 12; j <= t0 + 12; ++j) {
    int jc = j < 0 ? 0 : (j > L - 1 ? L - 1 : j);
    sum += (float)xb[(size_t)jc * C];
  }
  for (int t = t0; t < t0 + 128; ++t) {
    float xv = (float)xb[(size_t)t * C];
    float o = xv - sum * (1.0f / 25.0f);
    xout[((size_t)b * L + t) * C + c] = (_Float16)o;
    int nj = t + 13; if (nj > L - 1) nj = L - 1;
    int oj = t - 12; if (oj < 0) oj = 0;
    sum += (float)xb[(size_t)nj * C] - (float)xb[(size_t)oj * C];
  }
}

// ------- series decomposition fp16 -> fp32: out = x - movavg25(x) ----------
__global__ __launch_bounds__(256) void decomp_h_kernel(const _Float16* __restrict__ xin,
                                                       float* __restrict__ xout,
                                                       int L, int C) {
  int c = blockIdx.x * 256 + threadIdx.x;
  int t0 = blockIdx.y * 128;
  int b = blockIdx.z;
  const _Float16* xb = xin + (size_t)b * L * C + c;
  float sum = 0.f;
  for (int j = t0 - 12; j <= t0 + 12; ++j) {
    int jc = j < 0 ? 0 : (j > L - 1 ? L - 1 : j);
    sum += (float)xb[(size_t)jc * C];
  }
  for (int t = t0; t < t0 + 128; ++t) {
    float xv = (float)xb[(size_t)t * C];
    float o = xv - sum * (1.0f / 25.0f);
    xout[((size_t)b * L + t) * C + c] = o;
    int nj = t + 13; if (nj > L - 1) nj = L - 1;
    int oj = t - 12; if (oj < 0) oj = 0;
    sum += (float)xb[(size_t)nj * C] - (float)xb[(size_t)oj * C];
  }
}

// ------------------------------- launcher ----------------------------------
extern "C" void kernel_launch(void* const* d_in, const int* in_sizes, int n_in,
                              void* d_out, int out_size, void* d_ws, size_t ws_size,
                              hipStream_t stream) {
  const float* x = (const float*)d_in[0];
  const float* Wq = (const float*)d_in[1];
  const float* Wk = (const float*)d_in[2];
  const float* Wv = (const float*)d_in[3];
  const float* Wo = (const float*)d_in[4];
  const float* bo = (const float*)d_in[5];
  const float* lng = (const float*)d_in[6];
  const float* lnb = (const float*)d_in[7];
  const float* W1 = (const float*)d_in[8];
  const float* W2 = (const float*)d_in[9];
  float* out = (float*)d_out;

  const int B = 8, L = 2048, C = 1024, HD = 4096;
  const int M = B * L;  // 16384

  char* ws = (char*)d_ws;
  size_t off = 0;
  auto alloc = [&](size_t bytes) -> void* {
    void* p = ws + off;
    off = (off + bytes + 255) & ~(size_t)255;
    return p;
  };
  _Float16* wqkh = (_Float16*)alloc((size_t)2 * C * C * 2); // 4 MB (q rows, then k rows)
  _Float16* wvoh = (_Float16*)alloc((size_t)C * C * 2);     // 2 MB (Wo*Wv)
  _Float16* w1h = (_Float16*)alloc((size_t)HD * C * 2);     // 8 MB
  _Float16* w2h = (_Float16*)alloc((size_t)C * HD * 2);     // 8 MB
  float* S8 = (float*)alloc((size_t)B * 8 * 2050 * 4);      // 512 KB (reduced spectrum)
  int* dl = (int*)alloc(B * 7 * 4);
  float* al = (float*)alloc(B * 7 * 4);
  _Float16* xn = (_Float16*)alloc((size_t)M * C * 2);       // 32 MB; later x2h
  _Float16* qkh = (_Float16*)alloc((size_t)M * 2 * C * 2);  // 64 MB [B,2C,L]; later x1h/hidA
  _Float16* vh = (_Float16*)alloc((size_t)4096 * 2050 * 4); // 33.6 MB: setup/Sbig/aggh/x3h
  (void)ws_size; (void)in_sizes; (void)n_in; (void)out_size;

  _Float16* wvT = vh;                        // setup-only (dead before corr_fft)
  _Float16* woh = vh + (size_t)C * C;        // setup-only (dead before corr_fft)
  float* wvo32 = (float*)(vh + (size_t)2 * C * C);  // 16 MB K-slice partials (setup)
  float* Sbig = (float*)vh;       // partial spectra (steps 5-6), dead before agg
  _Float16* aggh = vh;            // agg of xn (from step 8)
  _Float16* x1h = qkh;            // attn out fp16 (32 MB); q,k dead after corr_fft
  _Float16* x2h = xn;             // xn dead after agg
  _Float16* hidA = qkh;           // FFN hidden half A (64 MB); x1h dead
  _Float16* hidB = (_Float16*)out;// FFN hidden half B (64 MB); d_out free till decomp2
  _Float16* x3h = vh;             // FFN output fp16 (32 MB); aggh dead after attn GEMM

  // 1. weights -> fp16 (+ Wv transpose)
  cvt_f16_kernel<<<(C * C / 4 + 255) / 256, 256, 0, stream>>>(Wq, wqkh, C * C / 4);
  cvt_f16_kernel<<<(C * C / 4 + 255) / 256, 256, 0, stream>>>(Wk, wqkh + (size_t)C * C, C * C / 4);
  cvt_f16_kernel<<<(C * C / 4 + 255) / 256, 256, 0, stream>>>(Wo, woh, C * C / 4);
  transpose_f16_kernel<<<dim3(16, 16), 256, 0, stream>>>(Wv, wvT, C);
  cvt_f16_kernel<<<(HD * C / 4 + 255) / 256, 256, 0, stream>>>(W1, w1h, HD * C / 4);
  cvt_f16_kernel<<<(HD * C / 4 + 255) / 256, 256, 0, stream>>>(W2, w2h, HD * C / 4);
  // 2. Wvo = Wo*Wv fold: K-split grid 64 -> fp32 partials -> combine fp16
  gemm256_kernel<10><<<64, 512, 0, stream>>>(woh, wvT, C, C, C, C, C,
                                             wvo32, nullptr, nullptr, nullptr, nullptr, nullptr);
  wvo_combine_kernel<<<(C * C / 4 + 255) / 256, 256, 0, stream>>>(wvo32, wvoh, C * C / 4);
  // 3. LayerNorm -> fp16
  ln_kernel<<<M, 256, 0, stream>>>(x, lng, lnb, xn, C);
  // 4. fused q,k GEMM -> transposed [B, 2C, L] (staged epilogue)
  gemm256_kernel<5><<<(M / 256) * (2 * C / 256), 512, 0, stream>>>(
      xn, wqkh, M, 2 * C, C, C, C, nullptr, qkh, nullptr, nullptr, nullptr, nullptr);
  // 5. channel FFTs -> per-block partial spectrum rows (no atomics)
  corr_fft_kernel<<<B * (C / 2), 256, 0, stream>>>(qkh, Sbig);
  // 6. reduce 512 partial rows -> 8-way S8
  spec_reduce_kernel<<<dim3(9, 8, 8), 256, 0, stream>>>(Sbig, S8);
  // 7. inverse FFT + top-7 + softmax
  corr_topk_kernel<<<B, 256, 0, stream>>>(S8, dl, al, C, L);
  // 8. lag aggregation on xn (commuted) -> aggh
  agg_kernel<<<B * L, 256, 0, stream>>>(xn, dl, al, aggh, L, C);
  // 9. attn = aggh * Wvo^T + bo + x -> x1h fp16 (qkh region, staged epilogue)
  gemm256_kernel<9><<<(M / 256) * (C / 256), 512, 0, stream>>>(
      aggh, wvoh, M, C, C, C, C, nullptr, x1h, bo, x, nullptr, nullptr);
  // 10. decomp1: x2h = x1h - movavg(x1h) (fp16 -> fp16, xn region)
  decomp_hh_kernel<<<dim3(C / 256, L / 128, B), 256, 0, stream>>>(x1h, x2h, L, C);
  // 11. FFN: two FFN1 halves -> hidA (qkh) / hidB (d_out), then ONE FFN2
  //     pass with K=4096 dual-A: x3h = acc + x2h (fp16 res)
  gemm256_kernel<2><<<(M / 256) * (2048 / 256), 512, 0, stream>>>(
      x2h, w1h, M, 2048, C, C, C, nullptr, hidA, nullptr, nullptr, nullptr, nullptr);
  gemm256_kernel<2><<<(M / 256) * (2048 / 256), 512, 0, stream>>>(
      x2h, w1h + (size_t)2048 * C, M, 2048, C, C, C,
      nullptr, hidB, nullptr, nullptr, nullptr, nullptr);
  gemm256_kernel<8><<<(M / 256) * (C / 256), 512, 0, stream>>>(
      hidA, w2h, M, C, HD, 2048, HD, nullptr, x3h, nullptr, nullptr, x2h, hidB);
  // 12. decomp2 (fp16 input) -> out (d_out; hidB dead)
  decomp_h_kernel<<<dim3(C / 256, L / 128, B), 256, 0, stream>>>(x3h, out, L, C);
}

// Round 9
// 779.817 us; speedup vs baseline: 1.2393x; 1.0124x over previous
//
#include <hip/hip_runtime.h>
#include <cstdint>
#include <cstddef>

// ---------------------------------------------------------------------------
// AutoformerEncodeBlock R14 (= R13 + dispatch-count reduction):
//  - 5 weight cvt dispatches -> 1 ranged cvt_all_kernel (-4 dispatches).
//  - 2 FFN1 halves -> 1 N=4096 dispatch with split-output epilogue
//    (n0<2048 -> hidA, else hidB; both ld=2048) (-1 dispatch).
//  - GEMM K-loop: R8 dual-barrier phase skeleton (established plateau).
//  - FFN2 single pass K=4096 dual-A; staged epilogues; fast GELU;
//    register radix-8 corr_fft; Wvo fold (K-split).
// ---------------------------------------------------------------------------

typedef _Float16 half8 __attribute__((ext_vector_type(8)));
typedef _Float16 half4 __attribute__((ext_vector_type(4)));
typedef float floatx4 __attribute__((ext_vector_type(4)));

#define PI_F 3.14159265358979323846f
#define ZP32(i) ((i) + ((i) >> 5))  // pad every 32 float2 elements

__device__ __forceinline__ void load_lds16(const void* g, void* l) {
  __builtin_amdgcn_global_load_lds((__attribute__((address_space(1))) void*)g,
                                   (__attribute__((address_space(3))) void*)l,
                                   16, 0, 0);
}

// exact-GELU via A&S 7.1.26 erf approximation (max abs err ~1.5e-7 on erf)
__device__ __forceinline__ float fast_gelu(float v) {
  float u = v * 0.70710678118654752f;
  float au = fabsf(u);
  float t = __builtin_amdgcn_rcpf(1.0f + 0.3275911f * au);
  float poly = t * (0.254829592f +
               t * (-0.284496736f +
               t * (1.421413741f +
               t * (-1.453152027f +
               t * 1.061405429f))));
  float e = __expf(-u * u);
  float erf_abs = 1.0f - poly * e;
  float erfv = copysignf(erf_abs, u);
  return 0.5f * v * (1.0f + erfv);
}

// ---------------------------- small utility kernels ------------------------

// all fp32->fp16 weight conversions in one dispatch (ranges over float4 idx)
__global__ __launch_bounds__(256) void cvt_all_kernel(
    const float* __restrict__ Wq, const float* __restrict__ Wk,
    const float* __restrict__ Wo, const float* __restrict__ W1,
    const float* __restrict__ W2, _Float16* __restrict__ wqkh,
    _Float16* __restrict__ woh, _Float16* __restrict__ w1h,
    _Float16* __restrict__ w2h) {
  int i = blockIdx.x * 256 + threadIdx.x;
  const int CC4 = 262144;    // 1024*1024/4
  const int HD4 = 1048576;   // 4096*1024/4
  const float* src;
  _Float16* dst;
  int o;
  if (i < CC4) { src = Wq; dst = wqkh; o = i; }
  else if (i < 2 * CC4) { src = Wk; dst = wqkh + (size_t)1048576; o = i - CC4; }
  else if (i < 3 * CC4) { src = Wo; dst = woh; o = i - 2 * CC4; }
  else if (i < 3 * CC4 + HD4) { src = W1; dst = w1h; o = i - 3 * CC4; }
  else if (i < 3 * CC4 + 2 * HD4) { src = W2; dst = w2h; o = i - 3 * CC4 - HD4; }
  else return;
  float4 v = ((const float4*)src)[o];
  half4 h = {(_Float16)v.x, (_Float16)v.y, (_Float16)v.z, (_Float16)v.w};
  ((half4*)dst)[o] = h;
}

// dst[c, j] = src[j, c]  (n x n, fp32 -> fp16), 64x64 LDS tiles
__global__ __launch_bounds__(256) void transpose_f16_kernel(const float* __restrict__ src,
                                                            _Float16* __restrict__ dst, int n) {
  __shared__ float tile[64][65];
  int j0 = blockIdx.y * 64, c0 = blockIdx.x * 64;
  int tr = threadIdx.x >> 4;
  int tc = threadIdx.x & 15;
#pragma unroll
  for (int rr = 0; rr < 64; rr += 16) {
    float4 v = *(const float4*)(src + (size_t)(j0 + tr + rr) * n + c0 + tc * 4);
    tile[tr + rr][tc * 4 + 0] = v.x;
    tile[tr + rr][tc * 4 + 1] = v.y;
    tile[tr + rr][tc * 4 + 2] = v.z;
    tile[tr + rr][tc * 4 + 3] = v.w;
  }
  __syncthreads();
#pragma unroll
  for (int rr = 0; rr < 64; rr += 16) {
    int c = tr + rr;
    half4 h = {(_Float16)tile[tc * 4 + 0][c], (_Float16)tile[tc * 4 + 1][c],
               (_Float16)tile[tc * 4 + 2][c], (_Float16)tile[tc * 4 + 3][c]};
    *(half4*)(dst + (size_t)(c0 + c) * n + j0 + tc * 4) = h;
  }
}

// combine 4 fp32 K-slice partials of Wvo -> fp16 (n4 = C*C/4)
__global__ __launch_bounds__(256) void wvo_combine_kernel(const float* __restrict__ p,
                                                          _Float16* __restrict__ w, int n4) {
  int i = blockIdx.x * 256 + threadIdx.x;
  if (i >= n4) return;
  const size_t S = (size_t)1024 * 1024;
  float4 a = ((const float4*)p)[i];
  float4 b = ((const float4*)(p + S))[i];
  float4 c = ((const float4*)(p + 2 * S))[i];
  float4 d = ((const float4*)(p + 3 * S))[i];
  half4 h = {(_Float16)(a.x + b.x + c.x + d.x), (_Float16)(a.y + b.y + c.y + d.y),
             (_Float16)(a.z + b.z + c.z + d.z), (_Float16)(a.w + b.w + c.w + d.w)};
  ((half4*)w)[i] = h;
}

// --------------------------------- LayerNorm -------------------------------
__global__ __launch_bounds__(256) void ln_kernel(const float* __restrict__ x,
                                                 const float* __restrict__ g,
                                                 const float* __restrict__ b,
                                                 _Float16* __restrict__ xn, int C) {
  int row = blockIdx.x;
  int t = threadIdx.x;
  const float4* xr = (const float4*)(x + (size_t)row * C);
  float4 v = xr[t];
  float s = v.x + v.y + v.z + v.w;
  float s2 = v.x * v.x + v.y * v.y + v.z * v.z + v.w * v.w;
  for (int o = 32; o > 0; o >>= 1) {
    s += __shfl_down(s, o, 64);
    s2 += __shfl_down(s2, o, 64);
  }
  __shared__ float red[8];
  int wave = t >> 6, lane = t & 63;
  if (lane == 0) { red[wave] = s; red[4 + wave] = s2; }
  __syncthreads();
  __shared__ float stats[2];
  if (t == 0) {
    float ts = red[0] + red[1] + red[2] + red[3];
    float ts2 = red[4] + red[5] + red[6] + red[7];
    float mu = ts / (float)C;
    float var = ts2 / (float)C - mu * mu;
    stats[0] = mu;
    stats[1] = 1.0f / sqrtf(var + 1e-5f);
  }
  __syncthreads();
  float mu = stats[0], rs = stats[1];
  float4 gv = ((const float4*)g)[t];
  float4 bv = ((const float4*)b)[t];
  half4 h = {(_Float16)((v.x - mu) * rs * gv.x + bv.x),
             (_Float16)((v.y - mu) * rs * gv.y + bv.y),
             (_Float16)((v.z - mu) * rs * gv.z + bv.z),
             (_Float16)((v.w - mu) * rs * gv.w + bv.w)};
  ((half4*)(xn + (size_t)row * C))[t] = h;
}

// ----------------------------------- GEMM ----------------------------------
// C[M,N] = A[M,K] * Bw[N,K]^T (fp16). 256x256 tile, BK=64, 8 waves (2x4),
// per-wave 128x64 output (acc[8][4]). R8 dual-barrier phase skeleton with
// counted vmcnt. XOR-granule swizzle on K-loop LDS (0 bank conflicts).
// EPI: 2 = fast GELU -> fp16 (staged row-major; dual-output: n0<2048 -> outh,
//          else resh (cast), both ld 2048 when resh != null),
//      5 = fp16 transposed [B, N, L] (L=2048; staged col-major),
//      8 = fp16 out = acc + resh fp16 (staged; dual-A via Ah2),
//      9 = fp16 out = acc + bias + res fp32 (staged),
//      10 = fp32 K-slice partials (grid 64: 16 tiles x 4 slices of K=256)
template <int EPI>
__global__ __launch_bounds__(512, 2) void gemm256_kernel(
    const _Float16* __restrict__ A, const _Float16* __restrict__ Bw,
    int M, int N, int K, int lda, int ldb,
    float* __restrict__ outf, _Float16* __restrict__ outh,
    const float* __restrict__ bias, const float* __restrict__ res,
    const _Float16* __restrict__ resh, const _Float16* __restrict__ Ah2) {
  __shared__ _Float16 lds[2][2][256 * 64];  // [buf][A=0/B=1][256 rows x 64 halfs]

  int tid = threadIdx.x;
  int lane = tid & 63;
  int wave = tid >> 6;          // 0..7
  int wm = wave >> 2;           // 0..1  (M half)
  int wn = wave & 3;            // 0..3  (N quarter)
  int ln15 = lane & 15, q4 = lane >> 4;
  int l3 = lane >> 3, l7 = lane & 7;

  int nwg = gridDim.x, orig = blockIdx.x;
  int wg, kslice = 0;
  if (EPI == 10) {
    kslice = orig >> 4;
    wg = orig & 15;
  } else {
    wg = ((nwg & 7) == 0) ? ((orig & 7) * (nwg >> 3) + (orig >> 3)) : orig;
  }
  int nbn = N >> 8;
  size_t m0 = (size_t)(wg / nbn) << 8;
  size_t n0 = (size_t)(wg % nbn) << 8;

  // swizzled ds_read granule offsets (halfs)
  int sg0 = (q4 ^ l7) << 3;         // kk=0
  int sg1 = ((q4 + 4) ^ l7) << 3;   // kk=32

  floatx4 acc[8][4] = {};

  // staging: lane covers row (8*wave + l3) of each 64-row chunk, global
  // granule pre-swizzled to l7^l3 so linear LDS dest == swizzled layout.
  size_t swzoff = (size_t)((l7 ^ l3) * 8);
  const _Float16* srcA = A + (m0 + 8 * wave + l3) * (size_t)lda + swzoff;
  const _Float16* srcB = Bw + (n0 + 8 * wave + l3) * (size_t)ldb + swzoff;
  const _Float16* srcA2 = ((EPI == 8 && Ah2) ? Ah2 : A) + (m0 + 8 * wave + l3) * (size_t)lda + swzoff;
  if (EPI == 10) {
    srcA += (size_t)kslice * 256;
    srcB += (size_t)kslice * 256;
  }
  char* ldsA0 = (char*)&lds[0][0][0] + wave * 1024;
  char* ldsB0 = (char*)&lds[0][1][0] + wave * 1024;

  int nk = (EPI == 10) ? 4 : (K >> 6);
  int nswitch = (EPI == 8 && Ah2) ? (nk >> 1) : nk;  // tiles >= nswitch read Ah2

  // prologue: stage tile 0 (order B0,B1,B2,B3,A0,A2,A1,A3) into buf 0
  load_lds16(srcB, ldsB0);
  load_lds16(srcB + (size_t)64 * ldb, ldsB0 + 1 * 8192);
  load_lds16(srcB + (size_t)128 * ldb, ldsB0 + 2 * 8192);
  load_lds16(srcB + (size_t)192 * ldb, ldsB0 + 3 * 8192);
  load_lds16(srcA, ldsA0);
  load_lds16(srcA + (size_t)128 * lda, ldsA0 + 2 * 8192);
  load_lds16(srcA + (size_t)64 * lda, ldsA0 + 1 * 8192);
  load_lds16(srcA + (size_t)192 * lda, ldsA0 + 3 * 8192);
  // guard tile-0 reads (A1,A3 may stay outstanding)
  asm volatile("s_waitcnt vmcnt(2)" ::: "memory");
  __builtin_amdgcn_s_barrier();
  __builtin_amdgcn_sched_barrier(0);

  half8 bf[4][2], aA[2][2];

#define RD_B() _Pragma("unroll") for (int ni = 0; ni < 4; ++ni) {      \
    const _Float16* p_ = cB + ((wn * 64 + ni * 16 + ln15) << 6);       \
    bf[ni][0] = *(const half8*)(p_ + sg0);                             \
    bf[ni][1] = *(const half8*)(p_ + sg1); }
#define RD_A(mi) { const _Float16* p_ = cA + ((wm * 128 + (mi) * 16 + ln15) << 6); \
    aA[(mi) & 1][0] = *(const half8*)(p_ + sg0);                                   \
    aA[(mi) & 1][1] = *(const half8*)(p_ + sg1); }
#define MM(mi) _Pragma("unroll") for (int ni = 0; ni < 4; ++ni) {      \
    acc[mi][ni] = __builtin_amdgcn_mfma_f32_16x16x32_f16(aA[(mi) & 1][0], bf[ni][0], acc[mi][ni], 0, 0, 0); \
    acc[mi][ni] = __builtin_amdgcn_mfma_f32_16x16x32_f16(aA[(mi) & 1][1], bf[ni][1], acc[mi][ni], 0, 0, 0); }

#define PH_MID()                                            \
    __builtin_amdgcn_s_barrier();                           \
    asm volatile("s_waitcnt lgkmcnt(0)" ::: "memory");      \
    __builtin_amdgcn_sched_barrier(0);                      \
    __builtin_amdgcn_s_setprio(1);
#define PH_END()                                            \
    __builtin_amdgcn_s_setprio(0);                          \
    __builtin_amdgcn_s_barrier();                           \
    __builtin_amdgcn_sched_barrier(0);

  for (int t = 0; t < nk; ++t) {
    int cur = t & 1;
    const _Float16* cA = &lds[cur][0][0];
    const _Float16* cB = &lds[cur][1][0];
    int tt = t + 1;
    const _Float16* As;
    if (EPI == 8 && Ah2 != nullptr && tt >= nswitch) As = srcA2 + (size_t)(tt - nswitch) * 64;
    else As = srcA + (size_t)tt * 64;
    const _Float16* Bs = srcB + (size_t)tt * 64;
    char* stA = ldsA0 + (cur ^ 1) * 65536;
    char* stB = ldsB0 + (cur ^ 1) * 65536;
    bool pf = (tt < nk);

    // ---- phase 0: MFMA mi=0,1 ----
    RD_B();
    RD_A(0); RD_A(1);
    if (pf) {
      load_lds16(Bs, stB);
      load_lds16(Bs + (size_t)64 * ldb, stB + 1 * 8192);
      load_lds16(Bs + (size_t)128 * ldb, stB + 2 * 8192);
    }
    PH_MID();
    MM(0); MM(1);
    PH_END();
    // ---- phase 1: MFMA mi=2,3; end-wait guards this tile's A1,A3 ----
    RD_A(2); RD_A(3);
    if (pf) {
      load_lds16(Bs + (size_t)192 * ldb, stB + 3 * 8192);
      load_lds16(As, stA);
      load_lds16(As + (size_t)128 * lda, stA + 2 * 8192);
    }
    PH_MID();
    MM(2); MM(3);
    __builtin_amdgcn_s_setprio(0);
    if (pf) {
      asm volatile("s_waitcnt vmcnt(6)" ::: "memory");
    } else {
      asm volatile("s_waitcnt vmcnt(0)" ::: "memory");
    }
    __builtin_amdgcn_s_barrier();
    __builtin_amdgcn_sched_barrier(0);
    // ---- phase 2: MFMA mi=4,5 ----
    RD_A(4); RD_A(5);
    if (pf) {
      load_lds16(As + (size_t)64 * lda, stA + 1 * 8192);
    }
    PH_MID();
    MM(4); MM(5);
    PH_END();
    // ---- phase 3: MFMA mi=6,7; end-wait guards next tile's B*,A0,A2 ----
    RD_A(6); RD_A(7);
    if (pf) {
      load_lds16(As + (size_t)192 * lda, stA + 3 * 8192);
    }
    PH_MID();
    MM(6); MM(7);
    __builtin_amdgcn_s_setprio(0);
    asm volatile("s_waitcnt vmcnt(2)" ::: "memory");
    __builtin_amdgcn_s_barrier();
    __builtin_amdgcn_sched_barrier(0);
  }
#undef RD_B
#undef RD_A
#undef MM
#undef PH_MID
#undef PH_END

  if (EPI == 2 || EPI == 8 || EPI == 9) {
    // ---- LDS-staged row-major epilogue; ecol ^ (q4<<4) -> conflict-free ---
    _Float16* eb = (_Float16*)&lds[0][0][0];  // 256 x 256 fp16 = 128 KiB
    int xq = q4 << 4;  // ((erow>>2)&3)<<4 == q4<<4 (erow = ..+q4*4+r, r<4)
#pragma unroll
    for (int mi = 0; mi < 8; ++mi) {
#pragma unroll
      for (int ni = 0; ni < 4; ++ni) {
        floatx4 a4 = acc[mi][ni];
        int erow = wm * 128 + mi * 16 + q4 * 4;
        int ecolX = (wn * 64 + ni * 16 + ln15) ^ xq;
#pragma unroll
        for (int r = 0; r < 4; ++r) {
          float v = a4[r];
          if (EPI == 2) v = fast_gelu(v);
          eb[(size_t)(erow + r) * 256 + ecolX] = (_Float16)v;
        }
      }
    }
    __syncthreads();
    int baser = (tid >> 6) * 32 + (((tid & 63) >> 5) << 4);
    int ecol2 = (tid & 31) << 3;
    float4 bv0, bv1;
    if (EPI == 9) {
      bv0 = *(const float4*)(bias + n0 + ecol2);
      bv1 = *(const float4*)(bias + n0 + ecol2 + 4);
    }
    // EPI=2 dual-output: n0<2048 -> outh, else resh (as output), ld 2048
    _Float16* ob = outh;
    size_t ldo = N, nc0 = n0;
    if (EPI == 2 && resh != nullptr) {
      ldo = 2048;
      if (n0 >= 2048) { ob = (_Float16*)resh; nc0 = n0 - 2048; }
    }
#pragma unroll
    for (int jr = 0; jr < 16; ++jr) {
      int row = baser + jr;
      int xr = ((row >> 2) & 3) << 4;
      half8 hv = *(const half8*)(eb + (size_t)row * 256 + (ecol2 ^ xr));
      size_t gidx = (m0 + row) * ldo + nc0 + ecol2;
      if (EPI == 8) {
        half8 pv = *(const half8*)(resh + gidx);
#pragma unroll
        for (int k = 0; k < 8; ++k) hv[k] = (_Float16)((float)hv[k] + (float)pv[k]);
      } else if (EPI == 9) {
        float4 rv0 = *(const float4*)(res + gidx);
        float4 rv1 = *(const float4*)(res + gidx + 4);
        hv[0] = (_Float16)((float)hv[0] + bv0.x + rv0.x);
        hv[1] = (_Float16)((float)hv[1] + bv0.y + rv0.y);
        hv[2] = (_Float16)((float)hv[2] + bv0.z + rv0.z);
        hv[3] = (_Float16)((float)hv[3] + bv0.w + rv0.w);
        hv[4] = (_Float16)((float)hv[4] + bv1.x + rv1.x);
        hv[5] = (_Float16)((float)hv[5] + bv1.y + rv1.y);
        hv[6] = (_Float16)((float)hv[6] + bv1.z + rv1.z);
        hv[7] = (_Float16)((float)hv[7] + bv1.w + rv1.w);
      }
      *(half8*)(ob + gidx) = hv;
    }
  } else if (EPI == 5) {
    // ---- LDS-staged transposed epilogue: col-major tile, swizzled --------
    _Float16* eb = (_Float16*)&lds[0][0][0];  // [col][row] 256x256 fp16
#pragma unroll
    for (int mi = 0; mi < 8; ++mi) {
#pragma unroll
      for (int ni = 0; ni < 4; ++ni) {
        floatx4 a4 = acc[mi][ni];
        int erow = wm * 128 + mi * 16 + q4 * 4;
        int ecol = wn * 64 + ni * 16 + ln15;
        int xc = (ecol & 7) << 3;
#pragma unroll
        for (int r = 0; r < 4; ++r)
          eb[(size_t)ecol * 256 + ((erow + r) ^ xc)] = (_Float16)a4[r];
      }
    }
    __syncthreads();
    size_t bidx = m0 >> 11, l0 = m0 & 2047;
    int cbase = (tid >> 5) * 16;
    int l8 = (tid & 31) << 3;
#pragma unroll
    for (int jr = 0; jr < 16; ++jr) {
      int col = cbase + jr;
      int xc = (col & 7) << 3;
      half8 hv = *(const half8*)(eb + (size_t)col * 256 + (l8 ^ xc));
      *(half8*)(outh + ((bidx * N + n0 + col) << 11) + l0 + l8) = hv;
    }
  } else {
    // ---- EPI 10: fp32 K-slice partial (scalar; tiny grid) ----------------
#pragma unroll
    for (int mi = 0; mi < 8; ++mi) {
#pragma unroll
      for (int ni = 0; ni < 4; ++ni) {
        floatx4 a4 = acc[mi][ni];
        size_t rowb = m0 + wm * 128 + mi * 16 + q4 * 4;
        size_t col = n0 + wn * 64 + ni * 16 + ln15;
        float* po = outf + (size_t)kslice * M * N;
#pragma unroll
        for (int r = 0; r < 4; ++r)
          po[(rowb + r) * (size_t)N + col] = a4[r];
      }
    }
  }
}

// --------------------- autocorrelation: register radix-8 FFT ---------------
// (unchanged from R6 — see earlier comments)

#define CBFLY(ch, ia, ib, wr, wi) {                      \
    float ax_ = z[ch][ia].x, ay_ = z[ch][ia].y;          \
    float bx_ = z[ch][ib].x, by_ = z[ch][ib].y;          \
    float dx_ = ax_ - bx_, dy_ = ay_ - by_;              \
    z[ch][ia].x = ax_ + bx_; z[ch][ia].y = ay_ + by_;    \
    z[ch][ib].x = dx_ * (wr) - dy_ * (wi);               \
    z[ch][ib].y = dx_ * (wi) + dy_ * (wr); }
#define BFLY2(ia, ib, m) { float2 w_ = twl[ZP32(m)];     \
    CBFLY(0, ia, ib, w_.x, w_.y) CBFLY(1, ia, ib, w_.x, w_.y) }

__global__ __launch_bounds__(256) void corr_fft_kernel(const _Float16* __restrict__ F,
                                                       float* __restrict__ S) {
  __shared__ float2 Zs[2][2112];   // 2048 + pad every 32
  __shared__ float2 twl[1056];     // 1024 twiddles, padded
  int tid = threadIdx.x;
  int b = blockIdx.x >> 9;
  int c0 = (blockIdx.x & 511) << 1;
  const _Float16* qb = F + ((size_t)(b * 2048 + c0) << 11);
  const _Float16* kb = F + ((size_t)(b * 2048 + 1024 + c0) << 11);

  float2 z[2][8];
#pragma unroll
  for (int j = 0; j < 8; ++j) {
    int p = tid + 256 * j;
    z[0][j] = make_float2((float)qb[p], (float)kb[p]);
    z[1][j] = make_float2((float)qb[2048 + p], (float)kb[2048 + p]);
  }
  for (int m = tid; m < 1024; m += 256) {
    float sn, cs;
    __sincosf(-PI_F * (float)m / 1024.0f, &sn, &cs);
    twl[ZP32(m)] = make_float2(cs, sn);
  }
  __syncthreads();

  BFLY2(0, 4, tid)
  BFLY2(1, 5, tid + 256)
  BFLY2(2, 6, tid + 512)
  BFLY2(3, 7, tid + 768)
  { float2 wA = twl[ZP32(tid << 1)], wB = twl[ZP32((tid + 256) << 1)];
    CBFLY(0, 0, 2, wA.x, wA.y) CBFLY(1, 0, 2, wA.x, wA.y)
    CBFLY(0, 1, 3, wB.x, wB.y) CBFLY(1, 1, 3, wB.x, wB.y)
    CBFLY(0, 4, 6, wA.x, wA.y) CBFLY(1, 4, 6, wA.x, wA.y)
    CBFLY(0, 5, 7, wB.x, wB.y) CBFLY(1, 5, 7, wB.x, wB.y) }
  { float2 wA = twl[ZP32(tid << 2)];
    CBFLY(0, 0, 1, wA.x, wA.y) CBFLY(1, 0, 1, wA.x, wA.y)
    CBFLY(0, 2, 3, wA.x, wA.y) CBFLY(1, 2, 3, wA.x, wA.y)
    CBFLY(0, 4, 5, wA.x, wA.y) CBFLY(1, 4, 5, wA.x, wA.y)
    CBFLY(0, 6, 7, wA.x, wA.y) CBFLY(1, 6, 7, wA.x, wA.y) }

#pragma unroll
  for (int j = 0; j < 8; ++j) {
    int p = tid + 256 * j;
    Zs[0][ZP32(p)] = z[0][j];
    Zs[1][ZP32(p)] = z[1][j];
  }
  __syncthreads();
  int t5 = tid & 31, hi1 = (tid >> 5) << 8;
#pragma unroll
  for (int j = 0; j < 8; ++j) {
    int p = hi1 + t5 + 32 * j;
    z[0][j] = Zs[0][ZP32(p)];
    z[1][j] = Zs[1][ZP32(p)];
  }

  BFLY2(0, 4, t5 << 3)
  BFLY2(1, 5, (t5 + 32) << 3)
  BFLY2(2, 6, (t5 + 64) << 3)
  BFLY2(3, 7, (t5 + 96) << 3)
  { float2 wA = twl[ZP32(t5 << 4)], wB = twl[ZP32((t5 + 32) << 4)];
    CBFLY(0, 0, 2, wA.x, wA.y) CBFLY(1, 0, 2, wA.x, wA.y)
    CBFLY(0, 1, 3, wB.x, wB.y) CBFLY(1, 1, 3, wB.x, wB.y)
    CBFLY(0, 4, 6, wA.x, wA.y) CBFLY(1, 4, 6, wA.x, wA.y)
    CBFLY(0, 5, 7, wB.x, wB.y) CBFLY(1, 5, 7, wB.x, wB.y) }
  { float2 wA = twl[ZP32(t5 << 5)];
    CBFLY(0, 0, 1, wA.x, wA.y) CBFLY(1, 0, 1, wA.x, wA.y)
    CBFLY(0, 2, 3, wA.x, wA.y) CBFLY(1, 2, 3, wA.x, wA.y)
    CBFLY(0, 4, 5, wA.x, wA.y) CBFLY(1, 4, 5, wA.x, wA.y)
    CBFLY(0, 6, 7, wA.x, wA.y) CBFLY(1, 6, 7, wA.x, wA.y) }

#pragma unroll
  for (int j = 0; j < 8; ++j) {
    int p = hi1 + t5 + 32 * j;
    Zs[0][ZP32(p)] = z[0][j];
    Zs[1][ZP32(p)] = z[1][j];
  }
  __syncthreads();
  int t3 = tid & 3, hi2 = (tid >> 2) << 5;
#pragma unroll
  for (int j = 0; j < 8; ++j) {
    int p = hi2 + t3 + 4 * j;
    z[0][j] = Zs[0][ZP32(p)];
    z[1][j] = Zs[1][ZP32(p)];
  }

  BFLY2(0, 4, t3 << 6)
  BFLY2(1, 5, (t3 + 4) << 6)
  BFLY2(2, 6, (t3 + 8) << 6)
  BFLY2(3, 7, (t3 + 12) << 6)
  { float2 wA = twl[ZP32(t3 << 7)], wB = twl[ZP32((t3 + 4) << 7)];
    CBFLY(0, 0, 2, wA.x, wA.y) CBFLY(1, 0, 2, wA.x, wA.y)
    CBFLY(0, 1, 3, wB.x, wB.y) CBFLY(1, 1, 3, wB.x, wB.y)
    CBFLY(0, 4, 6, wA.x, wA.y) CBFLY(1, 4, 6, wA.x, wA.y)
    CBFLY(0, 5, 7, wB.x, wB.y) CBFLY(1, 5, 7, wB.x, wB.y) }
  { float2 wA = twl[ZP32(t3 << 8)];
    CBFLY(0, 0, 1, wA.x, wA.y) CBFLY(1, 0, 1, wA.x, wA.y)
    CBFLY(0, 2, 3, wA.x, wA.y) CBFLY(1, 2, 3, wA.x, wA.y)
    CBFLY(0, 4, 5, wA.x, wA.y) CBFLY(1, 4, 5, wA.x, wA.y)
    CBFLY(0, 6, 7, wA.x, wA.y) CBFLY(1, 6, 7, wA.x, wA.y) }

#pragma unroll
  for (int j = 0; j < 8; ++j) {
    int p = hi2 + t3 + 4 * j;
    Zs[0][ZP32(p)] = z[0][j];
    Zs[1][ZP32(p)] = z[1][j];
  }
  __syncthreads();
#pragma unroll
  for (int j = 0; j < 8; ++j) {
    int p = (tid << 3) + j;
    z[0][j] = Zs[0][ZP32(p)];
    z[1][j] = Zs[1][ZP32(p)];
  }

  CBFLY(0, 0, 2, 1.0f, 0.0f) CBFLY(1, 0, 2, 1.0f, 0.0f)
  CBFLY(0, 1, 3, 0.0f, -1.0f) CBFLY(1, 1, 3, 0.0f, -1.0f)
  CBFLY(0, 4, 6, 1.0f, 0.0f) CBFLY(1, 4, 6, 1.0f, 0.0f)
  CBFLY(0, 5, 7, 0.0f, -1.0f) CBFLY(1, 5, 7, 0.0f, -1.0f)
  CBFLY(0, 0, 1, 1.0f, 0.0f) CBFLY(1, 0, 1, 1.0f, 0.0f)
  CBFLY(0, 2, 3, 1.0f, 0.0f) CBFLY(1, 2, 3, 1.0f, 0.0f)
  CBFLY(0, 4, 5, 1.0f, 0.0f) CBFLY(1, 4, 5, 1.0f, 0.0f)
  CBFLY(0, 6, 7, 1.0f, 0.0f) CBFLY(1, 6, 7, 1.0f, 0.0f)

#pragma unroll
  for (int j = 0; j < 8; ++j) {
    int p = (tid << 3) + j;
    Zs[0][ZP32(p)] = z[0][j];
    Zs[1][ZP32(p)] = z[1][j];
  }
  __syncthreads();
  float* Sb = S + (size_t)blockIdx.x * 2050;  // row = b*512 + channel-group
  for (int f = tid; f <= 1024; f += 256) {
    int rf = __brev((unsigned)f) >> 21;
    int rmf = __brev((unsigned)((2048 - f) & 2047)) >> 21;
    float pr = 0.f, pim = 0.f;
#pragma unroll
    for (int ch = 0; ch < 2; ++ch) {
      float2 zf = Zs[ch][ZP32(rf)], zm = Zs[ch][ZP32(rmf)];
      float Qr = 0.5f * (zf.x + zm.x), Qi = 0.5f * (zf.y - zm.y);
      float Kr = 0.5f * (zf.y + zm.y), Ki = -0.5f * (zf.x - zm.x);
      pr += Qr * Kr + Qi * Ki;
      pim += Qi * Kr - Qr * Ki;
    }
    Sb[2 * f] = pr;
    Sb[2 * f + 1] = pim;
  }
}

// ------------- reduce 512 partial spectrum rows -> 8-way S8 format ---------
__global__ __launch_bounds__(256) void spec_reduce_kernel(const float* __restrict__ Sbig,
                                                          float* __restrict__ S8) {
  int f = blockIdx.x * 256 + threadIdx.x;  // 0..2303, guard
  int sc = blockIdx.y;                     // 0..7 (64-row chunk)
  int b = blockIdx.z;                      // 0..7
  if (f >= 2050) return;
  const float* src = Sbig + ((size_t)b * 512 + (size_t)sc * 64) * 2050 + f;
  float s = 0.f;
  for (int i = 0; i < 64; ++i) s += src[(size_t)i * 2050];
  S8[((size_t)b * 8 + sc) * 2050 + f] = s;
}

// --------------- per-batch: inverse FFT -> mean_corr -> top-7 + softmax ----
__global__ __launch_bounds__(256) void corr_topk_kernel(const float* __restrict__ S,
                                                        int* __restrict__ delays,
                                                        float* __restrict__ alphas,
                                                        int C, int L) {
  __shared__ float2 W[2048];
  __shared__ float mc[2048];
  __shared__ float rv[4];
  __shared__ int ri[4];
  __shared__ float swv[7];
  __shared__ int sdi[7];
  int b = blockIdx.x, tid = threadIdx.x;
  const float* Sb = S + (size_t)b * 8 * 2050;
  for (int f = tid; f < 2048; f += 256) {
    int ff = f <= 1024 ? f : 2048 - f;
    float re = 0.f, im = 0.f;
    for (int s = 0; s < 8; ++s) {
      re += Sb[s * 2050 + 2 * ff];
      im += Sb[s * 2050 + 2 * ff + 1];
    }
    W[f] = make_float2(re, f <= 1024 ? -im : im);
  }
  __syncthreads();
  for (int sh = 10; sh >= 0; --sh) {
    int s = 1 << sh;
    for (int j = tid; j < 1024; j += 256) {
      int t = j & (s - 1);
      int i0 = ((j >> sh) << (sh + 1)) | t;
      int i1 = i0 + s;
      float2 a = W[i0], bb = W[i1];
      float ang = -PI_F * (float)t / (float)s;
      float sn, cs;
      __sincosf(ang, &sn, &cs);
      float2 d = make_float2(a.x - bb.x, a.y - bb.y);
      W[i0] = make_float2(a.x + bb.x, a.y + bb.y);
      W[i1] = make_float2(d.x * cs - d.y * sn, d.x * sn + d.y * cs);
    }
    __syncthreads();
  }
  float inv = 1.0f / ((float)C * (float)L);
  for (int t = tid; t < 2048; t += 256) mc[t] = W[__brev((unsigned)t) >> 21].x * inv;
  __syncthreads();
  int wv = tid >> 6, lane = tid & 63;
  for (int it = 0; it < 7; ++it) {
    float bvv = -1e30f;
    int bi = 0;
    for (int e = tid * 8; e < tid * 8 + 8; ++e) {
      float v = mc[e];
      if (v > bvv) { bvv = v; bi = e; }
    }
    for (int o = 32; o > 0; o >>= 1) {
      float ov = __shfl_down(bvv, o, 64);
      int oi = __shfl_down(bi, o, 64);
      if (ov > bvv || (ov == bvv && oi < bi)) { bvv = ov; bi = oi; }
    }
    if (lane == 0) { rv[wv] = bvv; ri[wv] = bi; }
    __syncthreads();
    if (tid == 0) {
      float fv = rv[0];
      int fi = ri[0];
      for (int w2 = 1; w2 < 4; ++w2)
        if (rv[w2] > fv || (rv[w2] == fv && ri[w2] < fi)) { fv = rv[w2]; fi = ri[w2]; }
      swv[it] = fv;
      sdi[it] = fi;
      mc[fi] = -1e30f;
    }
    __syncthreads();
  }
  if (tid == 0) {
    float mx = swv[0];
    for (int i = 1; i < 7; ++i) mx = fmaxf(mx, swv[i]);
    float e[7], s = 0.f;
    for (int i = 0; i < 7; ++i) { e[i] = expf(swv[i] - mx); s += e[i]; }
    for (int i = 0; i < 7; ++i) {
      alphas[b * 7 + i] = e[i] / s;
      delays[b * 7 + i] = sdi[i];
    }
  }
}

// ------------------- lag aggregation on xn (commuted past Wv) --------------
__global__ __launch_bounds__(256) void agg_kernel(const _Float16* __restrict__ v,
                                                  const int* __restrict__ delays,
                                                  const float* __restrict__ alphas,
                                                  _Float16* __restrict__ agg,
                                                  int L, int C) {
  int bt = blockIdx.x;
  int b = bt >> 11, t = bt & 2047;
  int tid = threadIdx.x;
  const _Float16* vb = v + (size_t)b * L * C;
  float ax = 0.f, ay = 0.f, az = 0.f, aw = 0.f;
#pragma unroll
  for (int i = 0; i < 7; ++i) {
    int d = delays[b * 7 + i];
    float a = alphas[b * 7 + i];
    int src = t + d;
    if (src >= L) src -= L;
    half4 x = ((const half4*)(vb + (size_t)src * C))[tid];
    ax += a * (float)x.x; ay += a * (float)x.y;
    az += a * (float)x.z; aw += a * (float)x.w;
  }
  half4 h = {(_Float16)ax, (_Float16)ay, (_Float16)az, (_Float16)aw};
  ((half4*)(agg + (size_t)bt * C))[tid] = h;
}

// ------- series decomposition fp16 -> fp16: out = x - movavg25(x) ----------
__global__ __launch_bounds__(256) void decomp_hh_kernel(const _Float16* __restrict__ xin,
                                                        _Float16* __restrict__ xout,
                                                        int L, int C) {
  int c = blockIdx.x * 256 + threadIdx.x;
  int t0 = blockIdx.y * 128;
  int b = blockIdx.z;
  const _Float16* xb = xin + (size_t)b * L * C + c;
  float sum = 0.f;
  for (int j = t0 - 12; j <= t0 + 12; ++j) {
    int jc = j < 0 ? 0 : (j > L - 1 ? L - 1 : j);
    sum += (float)xb[(size_t)jc * C];
  }
  for (int t = t0; t < t0 + 128; ++t) {
    float xv = (float)xb[(size_t)t * C];
    float o = xv - sum * (1.0f / 25.0f);
    xout[((size_t)b * L + t) * C + c] = (_Float16)o;
    int nj = t + 13; if (nj > L - 1) nj = L - 1;
    int oj = t - 12; if (oj < 0) oj = 0;
    sum += (float)xb[(size_t)nj * C] - (float)xb[(size_t)oj * C];
  }
}

// ------- series decomposition fp16 -> fp32: out = x - movavg25(x) ----------
__global__ __launch_bounds__(256) void decomp_h_kernel(const _Float16* __restrict__ xin,
                                                       float* __restrict__ xout,
                                                       int L, int C) {
  int c = blockIdx.x * 256 + threadIdx.x;
  int t0 = blockIdx.y * 128;
  int b = blockIdx.z;
  const _Float16* xb = xin + (size_t)b * L * C + c;
  float sum = 0.f;
  for (int j = t0 - 12; j <= t0 + 12; ++j) {
    int jc = j < 0 ? 0 : (j > L - 1 ? L - 1 : j);
    sum += (float)xb[(size_t)jc * C];
  }
  for (int t = t0; t < t0 + 128; ++t) {
    float xv = (float)xb[(size_t)t * C];
    float o = xv - sum * (1.0f / 25.0f);
    xout[((size_t)b * L + t) * C + c] = o;
    int nj = t + 13; if (nj > L - 1) nj = L - 1;
    int oj = t - 12; if (oj < 0) oj = 0;
    sum += (float)xb[(size_t)nj * C] - (float)xb[(size_t)oj * C];
  }
}

// ------------------------------- launcher ----------------------------------
extern "C" void kernel_launch(void* const* d_in, const int* in_sizes, int n_in,
                              void* d_out, int out_size, void* d_ws, size_t ws_size,
                              hipStream_t stream) {
  const float* x = (const float*)d_in[0];
  const float* Wq = (const float*)d_in[1];
  const float* Wk = (const float*)d_in[2];
  const float* Wv = (const float*)d_in[3];
  const float* Wo = (const float*)d_in[4];
  const float* bo = (const float*)d_in[5];
  const float* lng = (const float*)d_in[6];
  const float* lnb = (const float*)d_in[7];
  const float* W1 = (const float*)d_in[8];
  const float* W2 = (const float*)d_in[9];
  float* out = (float*)d_out;

  const int B = 8, L = 2048, C = 1024, HD = 4096;
  const int M = B * L;  // 16384

  char* ws = (char*)d_ws;
  size_t off = 0;
  auto alloc = [&](size_t bytes) -> void* {
    void* p = ws + off;
    off = (off + bytes + 255) & ~(size_t)255;
    return p;
  };
  _Float16* wqkh = (_Float16*)alloc((size_t)2 * C * C * 2); // 4 MB (q rows, then k rows)
  _Float16* wvoh = (_Float16*)alloc((size_t)C * C * 2);     // 2 MB (Wo*Wv)
  _Float16* w1h = (_Float16*)alloc((size_t)HD * C * 2);     // 8 MB
  _Float16* w2h = (_Float16*)alloc((size_t)C * HD * 2);     // 8 MB
  float* S8 = (float*)alloc((size_t)B * 8 * 2050 * 4);      // 512 KB (reduced spectrum)
  int* dl = (int*)alloc(B * 7 * 4);
  float* al = (float*)alloc(B * 7 * 4);
  _Float16* xn = (_Float16*)alloc((size_t)M * C * 2);       // 32 MB; later x2h
  _Float16* qkh = (_Float16*)alloc((size_t)M * 2 * C * 2);  // 64 MB [B,2C,L]; later x1h/hidA
  _Float16* vh = (_Float16*)alloc((size_t)4096 * 2050 * 4); // 33.6 MB: setup/Sbig/aggh/x3h
  (void)ws_size; (void)in_sizes; (void)n_in; (void)out_size;

  _Float16* wvT = vh;                        // setup-only (dead before corr_fft)
  _Float16* woh = vh + (size_t)C * C;        // setup-only (dead before corr_fft)
  float* wvo32 = (float*)(vh + (size_t)2 * C * C);  // 16 MB K-slice partials (setup)
  float* Sbig = (float*)vh;       // partial spectra (steps 5-6), dead before agg
  _Float16* aggh = vh;            // agg of xn (from step 8)
  _Float16* x1h = qkh;            // attn out fp16 (32 MB); q,k dead after corr_fft
  _Float16* x2h = xn;             // xn dead after agg
  _Float16* hidA = qkh;           // FFN hidden half A (64 MB); x1h dead
  _Float16* hidB = (_Float16*)out;// FFN hidden half B (64 MB); d_out free till decomp2
  _Float16* x3h = vh;             // FFN output fp16 (32 MB); aggh dead after attn GEMM

  // 1. all weight conversions in one dispatch (+ Wv transpose)
  cvt_all_kernel<<<(3 * 262144 + 2 * 1048576 + 255) / 256, 256, 0, stream>>>(
      Wq, Wk, Wo, W1, W2, wqkh, woh, w1h, w2h);
  transpose_f16_kernel<<<dim3(16, 16), 256, 0, stream>>>(Wv, wvT, C);
  // 2. Wvo = Wo*Wv fold: K-split grid 64 -> fp32 partials -> combine fp16
  gemm256_kernel<10><<<64, 512, 0, stream>>>(woh, wvT, C, C, C, C, C,
                                             wvo32, nullptr, nullptr, nullptr, nullptr, nullptr);
  wvo_combine_kernel<<<(C * C / 4 + 255) / 256, 256, 0, stream>>>(wvo32, wvoh, C * C / 4);
  // 3. LayerNorm -> fp16
  ln_kernel<<<M, 256, 0, stream>>>(x, lng, lnb, xn, C);
  // 4. fused q,k GEMM -> transposed [B, 2C, L] (staged epilogue)
  gemm256_kernel<5><<<(M / 256) * (2 * C / 256), 512, 0, stream>>>(
      xn, wqkh, M, 2 * C, C, C, C, nullptr, qkh, nullptr, nullptr, nullptr, nullptr);
  // 5. channel FFTs -> per-block partial spectrum rows (no atomics)
  corr_fft_kernel<<<B * (C / 2), 256, 0, stream>>>(qkh, Sbig);
  // 6. reduce 512 partial rows -> 8-way S8
  spec_reduce_kernel<<<dim3(9, 8, 8), 256, 0, stream>>>(Sbig, S8);
  // 7. inverse FFT + top-7 + softmax
  corr_topk_kernel<<<B, 256, 0, stream>>>(S8, dl, al, C, L);
  // 8. lag aggregation on xn (commuted) -> aggh
  agg_kernel<<<B * L, 256, 0, stream>>>(xn, dl, al, aggh, L, C);
  // 9. attn = aggh * Wvo^T + bo + x -> x1h fp16 (qkh region, staged epilogue)
  gemm256_kernel<9><<<(M / 256) * (C / 256), 512, 0, stream>>>(
      aggh, wvoh, M, C, C, C, C, nullptr, x1h, bo, x, nullptr, nullptr);
  // 10. decomp1: x2h = x1h - movavg(x1h) (fp16 -> fp16, xn region)
  decomp_hh_kernel<<<dim3(C / 256, L / 128, B), 256, 0, stream>>>(x1h, x2h, L, C);
  // 11. FFN: ONE FFN1 dispatch N=4096 (split output hidA | hidB, ld 2048),
  //     then ONE FFN2 pass K=4096 dual-A: x3h = acc + x2h (fp16 res)
  gemm256_kernel<2><<<(M / 256) * (HD / 256), 512, 0, stream>>>(
      x2h, w1h, M, HD, C, C, C, nullptr, hidA, nullptr, nullptr, hidB, nullptr);
  gemm256_kernel<8><<<(M / 256) * (C / 256), 512, 0, stream>>>(
      hidA, w2h, M, C, HD, 2048, HD, nullptr, x3h, nullptr, nullptr, x2h, hidB);
  // 12. decomp2 (fp16 input) -> out (d_out; hidB dead)
  decomp_h_kernel<<<dim3(C / 256, L / 128, B), 256, 0, stream>>>(x3h, out, L, C);
}